// Round 1
// baseline (1467.534 us; speedup 1.0000x reference)
//
#include <hip/hip_runtime.h>
#include <math.h>

#define DEV __device__ __forceinline__

static constexpr int S_LEN  = 2048;
static constexpr int IN_DIM = 1024;
static constexpr int P_DIM  = 512;
static constexpr int NHEAD  = 8;
static constexpr int HD     = 64;
static constexpr int KN     = 128;

DEV float gelu_exact(float x) {
    return 0.5f * x * (1.0f + erff(x * 0.70710678118654752440f));
}

// 256-thread block sum reduction. sm4 must be float[4] shared.
DEV float block_reduce_sum(float v, float* sm4) {
    #pragma unroll
    for (int off = 32; off; off >>= 1) v += __shfl_down(v, off, 64);
    int lane = threadIdx.x & 63, w = threadIdx.x >> 6;
    __syncthreads();
    if (lane == 0) sm4[w] = v;
    __syncthreads();
    return sm4[0] + sm4[1] + sm4[2] + sm4[3];
}

// ---------------- K1: pentachora centroids, L2-normalized -------------------
__global__ __launch_bounds__(256) void k_cent(const float* __restrict__ penta,
                                              float* __restrict__ cent) {
    int p = blockIdx.x, t = threadIdx.x;
    __shared__ float sm4[4];
    float c0 = 0.f, c1 = 0.f;
    #pragma unroll
    for (int v = 0; v < 5; v++) {
        const float* row = penta + ((long)p * 5 + v) * P_DIM;
        c0 += row[t];
        c1 += row[t + 256];
    }
    c0 /= 5.0f; c1 /= 5.0f;
    float tot = block_reduce_sum(c0 * c0 + c1 * c1, sm4);
    float n = fmaxf(sqrtf(tot), 1e-12f);
    cent[p * P_DIM + t]       = c0 / n;
    cent[p * P_DIM + t + 256] = c1 / n;
}

// ---------------- generic 8-row-tiled fp32 GEMM: C = A@W + bias -------------
// A: M x K (M = gridDim.x*8), W: K x N row-major, threads own COLS columns.
template <int K, int N, int COLS>
__global__ __launch_bounds__(256) void k_gemm(const float* __restrict__ A,
                                              const float* __restrict__ W,
                                              const float* __restrict__ bias,
                                              float* __restrict__ C) {
    __shared__ float As[8 * K];
    int r0 = blockIdx.x * 8, t = threadIdx.x;
    const float4* Ain = (const float4*)(A + (long)r0 * K);
    #pragma unroll
    for (int idx = t, u = 0; u < (8 * K / 4) / 256; u++, idx += 256)
        ((float4*)As)[idx] = Ain[idx];
    __syncthreads();

    float acc[8][COLS];
    #pragma unroll
    for (int r = 0; r < 8; r++)
        #pragma unroll
        for (int c = 0; c < COLS; c++) acc[r][c] = 0.f;

    for (int k = 0; k < K; k += 4) {
        float4 a4[8];
        #pragma unroll
        for (int r = 0; r < 8; r++) a4[r] = *(const float4*)(As + r * K + k);
        #pragma unroll
        for (int kk = 0; kk < 4; kk++) {
            float w[COLS];
            #pragma unroll
            for (int c = 0; c < COLS; c++) w[c] = W[(long)(k + kk) * N + t + c * 256];
            #pragma unroll
            for (int r = 0; r < 8; r++) {
                float a = ((const float*)&a4[r])[kk];
                #pragma unroll
                for (int c = 0; c < COLS; c++) acc[r][c] = fmaf(a, w[c], acc[r][c]);
            }
        }
    }
    #pragma unroll
    for (int r = 0; r < 8; r++)
        #pragma unroll
        for (int c = 0; c < COLS; c++) {
            int col = t + c * 256;
            C[(long)(r0 + r) * N + col] = acc[r][c] + bias[col];
        }
}

// ---------------- K3: per-row LayerNorm -> gelu -> L2 normalize (in place) --
__global__ __launch_bounds__(256) void k_ln_gelu_norm(const float* __restrict__ Zin,
                                                      const float* __restrict__ g,
                                                      const float* __restrict__ b,
                                                      float* __restrict__ Z) {
    long row = blockIdx.x;
    int t = threadIdx.x;
    __shared__ float sm4[4];
    float x0 = Zin[row * P_DIM + t], x1 = Zin[row * P_DIM + t + 256];
    float mu = block_reduce_sum(x0 + x1, sm4) * (1.0f / P_DIM);
    float d0 = x0 - mu, d1 = x1 - mu;
    float var = block_reduce_sum(d0 * d0 + d1 * d1, sm4) * (1.0f / P_DIM);
    float rs = 1.0f / sqrtf(var + 1e-5f);
    float y0 = gelu_exact(d0 * rs * g[t] + b[t]);
    float y1 = gelu_exact(d1 * rs * g[t + 256] + b[t + 256]);
    float nn = block_reduce_sum(y0 * y0 + y1 * y1, sm4);
    float n = fmaxf(sqrtf(nn), 1e-12f);
    Z[row * P_DIM + t]       = y0 / n;
    Z[row * P_DIM + t + 256] = y1 / n;
}

// ---------------- K4: anchor argmax over 1024 centroids, gather position ----
__global__ __launch_bounds__(256) void k_anchor(const float* __restrict__ Z,
                                                const float* __restrict__ cent,
                                                const float* __restrict__ spos,
                                                float* __restrict__ pos) {
    __shared__ float Zs[8 * P_DIM];
    __shared__ float sv[256];
    __shared__ int   si[256];
    int r0 = blockIdx.x * 8, t = threadIdx.x;
    const float4* Zin = (const float4*)(Z + (long)r0 * P_DIM);
    #pragma unroll
    for (int u = 0; u < 4; u++) ((float4*)Zs)[t + u * 256] = Zin[t + u * 256];
    __syncthreads();

    float best[8];
    int bidx[8];
    #pragma unroll
    for (int r = 0; r < 8; r++) { best[r] = -1e30f; bidx[r] = 0; }

    for (int m = 0; m < 4; m++) {
        int p = t + m * 256;  // ascending per thread -> strict > keeps lowest p
        float acc[8];
        #pragma unroll
        for (int r = 0; r < 8; r++) acc[r] = 0.f;
        const float4* cp = (const float4*)(cent + (long)p * P_DIM);
        for (int kk = 0; kk < P_DIM / 4; kk++) {
            float4 c4 = cp[kk];
            #pragma unroll
            for (int r = 0; r < 8; r++) {
                float4 z4 = ((const float4*)(Zs + r * P_DIM))[kk];
                acc[r] += z4.x * c4.x + z4.y * c4.y + z4.z * c4.z + z4.w * c4.w;
            }
        }
        #pragma unroll
        for (int r = 0; r < 8; r++)
            if (acc[r] > best[r]) { best[r] = acc[r]; bidx[r] = p; }
    }
    for (int r = 0; r < 8; r++) {
        sv[t] = best[r]; si[t] = bidx[r];
        __syncthreads();
        for (int off = 128; off; off >>= 1) {
            if (t < off) {
                if (sv[t + off] > sv[t] ||
                    (sv[t + off] == sv[t] && si[t + off] < si[t])) {
                    sv[t] = sv[t + off]; si[t] = si[t + off];
                }
            }
            __syncthreads();
        }
        if (t == 0) pos[r0 + r] = spos[si[0]];
        __syncthreads();
    }
}

// ---------------- K6: exact jax-tiebreak top-128 neighbor select ------------
// key = (float_bits(dist) << 11) | j  -> lexicographic (dist, j), all distinct.
__global__ __launch_bounds__(256) void k_routes(const float* __restrict__ pos,
                                                int* __restrict__ routes) {
    int bi = blockIdx.x;          // global query token
    int b = bi >> 11, i = bi & 2047;
    int t = threadIdx.x;
    __shared__ float ps[S_LEN];
    __shared__ unsigned int hist[256];
    __shared__ int sh_digit;
    __shared__ unsigned int sh_cum;
    __shared__ unsigned int cnt;

    #pragma unroll
    for (int u = 0; u < 8; u++) ps[t + u * 256] = pos[b * S_LEN + t + u * 256];
    __syncthreads();
    float pi = ps[i];

    unsigned long long key[8];
    #pragma unroll
    for (int u = 0; u < 8; u++) {
        int j = t + u * 256;
        float d = fabsf(pi - ps[j]);
        key[u] = (((unsigned long long)__float_as_uint(d)) << 11) | (unsigned)j;
    }

    unsigned long long prefix = 0;
    int want = KN;
    for (int pass = 0; pass < 6; pass++) {
        int shift = 40 - pass * 8;
        hist[t] = 0;
        __syncthreads();
        #pragma unroll
        for (int u = 0; u < 8; u++) {
            if ((key[u] >> (shift + 8)) == prefix)
                atomicAdd(&hist[(unsigned)((key[u] >> shift) & 0xFF)], 1u);
        }
        __syncthreads();
        if (t == 0) {
            unsigned int cum = 0;
            int d = 0;
            for (; d < 256; d++) {
                unsigned h = hist[d];
                if (cum + h >= (unsigned)want) break;
                cum += h;
            }
            if (d == 256) d = 255;  // unreachable guard
            sh_digit = d; sh_cum = cum;
        }
        __syncthreads();
        prefix = (prefix << 8) | (unsigned)sh_digit;
        want -= (int)sh_cum;
        __syncthreads();
    }
    unsigned long long KTH = prefix;  // exact 128th-smallest key
    if (t == 0) cnt = 0;
    __syncthreads();
    int out_base = bi * KN;
    #pragma unroll
    for (int u = 0; u < 8; u++) {
        if (key[u] <= KTH) {
            unsigned slot = atomicAdd(&cnt, 1u);
            routes[out_base + slot] = (int)(key[u] & 0x7FF);
        }
    }
}

// ---------------- K7: gathered attention per (b, query) ---------------------
__global__ __launch_bounds__(256) void k_attn(const float* __restrict__ qkv,
                                              const int* __restrict__ routes,
                                              float* __restrict__ attn_out) {
    int bi = blockIdx.x;
    int b = bi >> 11;
    int t = threadIdx.x;
    __shared__ float qs[P_DIM];
    __shared__ int rts[KN];
    __shared__ float sc[NHEAD * KN];

    const float* qrow = qkv + (long)bi * (3 * P_DIM);
    qs[t] = qrow[t]; qs[t + 256] = qrow[t + 256];
    if (t < KN) rts[t] = routes[bi * KN + t];
    __syncthreads();

    // phase 1: scores
    #pragma unroll
    for (int m = 0; m < 4; m++) {
        int pix = t + m * 256;
        int h = pix >> 7, jj = pix & 127;
        long gt = (long)(b * S_LEN + rts[jj]) * (3 * P_DIM);
        const float4* kp = (const float4*)(qkv + gt + P_DIM + h * HD);
        const float4* qp = (const float4*)(qs + h * HD);
        float s = 0.f;
        #pragma unroll
        for (int kk = 0; kk < HD / 4; kk++) {
            float4 kv = kp[kk], qv = qp[kk];
            s += qv.x * kv.x + qv.y * kv.y + qv.z * kv.z + qv.w * kv.w;
        }
        sc[pix] = s * 0.125f;
    }
    __syncthreads();

    // phase 2: softmax per head (8 groups of 32 lanes)
    {
        int g = t >> 5, lane = t & 31;
        float v0 = sc[g * KN + lane],      v1 = sc[g * KN + lane + 32];
        float v2 = sc[g * KN + lane + 64], v3 = sc[g * KN + lane + 96];
        float mx = fmaxf(fmaxf(v0, v1), fmaxf(v2, v3));
        #pragma unroll
        for (int off = 16; off; off >>= 1) mx = fmaxf(mx, __shfl_xor(mx, off, 32));
        float e0 = expf(v0 - mx), e1 = expf(v1 - mx);
        float e2 = expf(v2 - mx), e3 = expf(v3 - mx);
        float sum = e0 + e1 + e2 + e3;
        #pragma unroll
        for (int off = 16; off; off >>= 1) sum += __shfl_xor(sum, off, 32);
        float inv = 1.0f / sum;
        sc[g * KN + lane]      = e0 * inv; sc[g * KN + lane + 32] = e1 * inv;
        sc[g * KN + lane + 64] = e2 * inv; sc[g * KN + lane + 96] = e3 * inv;
    }
    __syncthreads();

    // phase 3: out[h,d] = sum_jj p * v
    #pragma unroll
    for (int m = 0; m < 2; m++) {
        int o = t + m * 256;
        int h = o >> 6, d = o & 63;
        float acc = 0.f;
        for (int jj = 0; jj < KN; jj++) {
            long gt = (long)(b * S_LEN + rts[jj]) * (3 * P_DIM);
            acc = fmaf(sc[h * KN + jj], qkv[gt + 2 * P_DIM + h * HD + d], acc);
        }
        attn_out[(long)bi * P_DIM + o] = acc;
    }
}

// ---------------- K9: pooled partial sums (atomic) --------------------------
__global__ __launch_bounds__(256) void k_pool(const float* __restrict__ zatt,
                                              float* __restrict__ pooled) {
    int b = blockIdx.y, chunk = blockIdx.x, t = threadIdx.x;
    float a0 = 0.f, a1 = 0.f;
    for (int s = 0; s < 128; s++) {
        long row = ((long)b * S_LEN + chunk * 128 + s) * P_DIM;
        a0 += zatt[row + t];
        a1 += zatt[row + t + 256];
    }
    atomicAdd(&pooled[b * P_DIM + t], a0);
    atomicAdd(&pooled[b * P_DIM + t + 256], a1);
}

// ---------------- K10: expert MLP (one block per batch row) -----------------
__global__ __launch_bounds__(256) void k_expert(const float* __restrict__ pooled,
                                                const float* __restrict__ w1,
                                                const float* __restrict__ b1,
                                                const float* __restrict__ g,
                                                const float* __restrict__ bb,
                                                const float* __restrict__ w2,
                                                const float* __restrict__ b2,
                                                float* __restrict__ out,
                                                int s2, int sN, int out_off) {
    int b = blockIdx.x, t = threadIdx.x;
    __shared__ float pl[P_DIM];
    __shared__ float h[1024];
    __shared__ float sm4[4];
    pl[t]       = pooled[b * P_DIM + t]       * (1.0f / S_LEN);
    pl[t + 256] = pooled[b * P_DIM + t + 256] * (1.0f / S_LEN);
    __syncthreads();
    for (int j = t; j < s2; j += 256) {
        float acc = 0.f;
        for (int k = 0; k < P_DIM; k++) acc = fmaf(pl[k], w1[(long)k * s2 + j], acc);
        h[j] = acc + b1[j];
    }
    __syncthreads();
    float loc = 0.f;
    for (int j = t; j < s2; j += 256) loc += h[j];
    float mu = block_reduce_sum(loc, sm4) / (float)s2;
    loc = 0.f;
    for (int j = t; j < s2; j += 256) { float d = h[j] - mu; loc += d * d; }
    float var = block_reduce_sum(loc, sm4) / (float)s2;
    float rs = 1.0f / sqrtf(var + 1e-5f);
    __syncthreads();
    for (int j = t; j < s2; j += 256)
        h[j] = gelu_exact((h[j] - mu) * rs * g[j] + bb[j]);
    __syncthreads();
    for (int j = t; j < sN; j += 256) {
        float acc = 0.f;
        for (int k = 0; k < s2; k++) acc = fmaf(h[k], w2[(long)k * sN + j], acc);
        out[b * 896 + out_off + j] = acc + b2[j];
    }
}

// ---------------------------------------------------------------------------
extern "C" void kernel_launch(void* const* d_in, const int* in_sizes, int n_in,
                              void* d_out, int out_size, void* d_ws, size_t ws_size,
                              hipStream_t stream) {
    const float* seq   = (const float*)d_in[0];
    const float* penta = (const float*)d_in[1];
    const float* spos  = (const float*)d_in[2];
    const float* projW = (const float*)d_in[3];
    const float* projb = (const float*)d_in[4];
    const float* lng   = (const float*)d_in[5];
    const float* lnb   = (const float*)d_in[6];
    const float* qkvW  = (const float*)d_in[7];
    const float* qkvb  = (const float*)d_in[8];
    const float* outW  = (const float*)d_in[9];
    const float* outb  = (const float*)d_in[10];

    float* ws     = (float*)d_ws;
    float* cent   = ws;                   // 1024*512            = 524288
    float* z      = cent + 524288;        // 4096*512            = 2097152
    float* qkv    = z + 2097152;          // 4096*1536           = 6291456
    float* pos    = qkv + 6291456;        // 4096
    float* attn   = pos + 4096;           // 4096*512            = 2097152
    float* zatt   = attn + 2097152;       // 4096*512            = 2097152
    float* pooled = zatt + 2097152;       // 1024
    int*   routes = (int*)(pooled + 1024);// 4096*128            = 524288

    k_cent<<<1024, 256, 0, stream>>>(penta, cent);
    k_gemm<IN_DIM, P_DIM, 2><<<512, 256, 0, stream>>>(seq, projW, projb, z);
    k_ln_gelu_norm<<<4096, 256, 0, stream>>>(z, lng, lnb, z);
    k_anchor<<<512, 256, 0, stream>>>(z, cent, spos, pos);
    k_gemm<P_DIM, 3 * P_DIM, 6><<<512, 256, 0, stream>>>(z, qkvW, qkvb, qkv);
    k_routes<<<4096, 256, 0, stream>>>(pos, routes);
    k_attn<<<4096, 256, 0, stream>>>(qkv, routes, attn);
    k_gemm<P_DIM, P_DIM, 2><<<512, 256, 0, stream>>>(attn, outW, outb, zatt);

    hipMemsetAsync(pooled, 0, 1024 * sizeof(float), stream);
    dim3 pg(16, 2);
    k_pool<<<pg, 256, 0, stream>>>(zatt, pooled);

    k_expert<<<2, 256, 0, stream>>>(pooled, (const float*)d_in[11], (const float*)d_in[12],
                                    (const float*)d_in[13], (const float*)d_in[14],
                                    (const float*)d_in[15], (const float*)d_in[16],
                                    (float*)d_out, 256, 128, 0);
    k_expert<<<2, 256, 0, stream>>>(pooled, (const float*)d_in[17], (const float*)d_in[18],
                                    (const float*)d_in[19], (const float*)d_in[20],
                                    (const float*)d_in[21], (const float*)d_in[22],
                                    (float*)d_out, 512, 256, 128);
    k_expert<<<2, 256, 0, stream>>>(pooled, (const float*)d_in[23], (const float*)d_in[24],
                                    (const float*)d_in[25], (const float*)d_in[26],
                                    (const float*)d_in[27], (const float*)d_in[28],
                                    (float*)d_out, 1024, 512, 384);
}

// Round 2
// 983.612 us; speedup vs baseline: 1.4920x; 1.4920x over previous
//
#include <hip/hip_runtime.h>
#include <math.h>

#define DEV __device__ __forceinline__

static constexpr int S_LEN  = 2048;
static constexpr int IN_DIM = 1024;
static constexpr int P_DIM  = 512;
static constexpr int NHEAD  = 8;
static constexpr int HD     = 64;
static constexpr int KN     = 128;

DEV float gelu_exact(float x) {
    return 0.5f * x * (1.0f + erff(x * 0.70710678118654752440f));
}

// 256-thread block sum reduction. sm4 must be float[4] shared.
DEV float block_reduce_sum(float v, float* sm4) {
    #pragma unroll
    for (int off = 32; off; off >>= 1) v += __shfl_down(v, off, 64);
    int lane = threadIdx.x & 63, w = threadIdx.x >> 6;
    __syncthreads();
    if (lane == 0) sm4[w] = v;
    __syncthreads();
    return sm4[0] + sm4[1] + sm4[2] + sm4[3];
}

// ---------------- K1: pentachora centroids, L2-normalized -------------------
__global__ __launch_bounds__(256) void k_cent(const float* __restrict__ penta,
                                              float* __restrict__ cent) {
    int p = blockIdx.x, t = threadIdx.x;
    __shared__ float sm4[4];
    float c0 = 0.f, c1 = 0.f;
    #pragma unroll
    for (int v = 0; v < 5; v++) {
        const float* row = penta + ((long)p * 5 + v) * P_DIM;
        c0 += row[t];
        c1 += row[t + 256];
    }
    c0 /= 5.0f; c1 /= 5.0f;
    float tot = block_reduce_sum(c0 * c0 + c1 * c1, sm4);
    float n = fmaxf(sqrtf(tot), 1e-12f);
    cent[p * P_DIM + t]       = c0 / n;
    cent[p * P_DIM + t + 256] = c1 / n;
}

// ---------------- generic 8-row-tiled fp32 GEMM: C = A@W + bias -------------
template <int K, int N, int COLS>
__global__ __launch_bounds__(256) void k_gemm(const float* __restrict__ A,
                                              const float* __restrict__ W,
                                              const float* __restrict__ bias,
                                              float* __restrict__ C) {
    __shared__ float As[8 * K];
    int r0 = blockIdx.x * 8, t = threadIdx.x;
    const float4* Ain = (const float4*)(A + (long)r0 * K);
    #pragma unroll
    for (int idx = t, u = 0; u < (8 * K / 4) / 256; u++, idx += 256)
        ((float4*)As)[idx] = Ain[idx];
    __syncthreads();

    float acc[8][COLS];
    #pragma unroll
    for (int r = 0; r < 8; r++)
        #pragma unroll
        for (int c = 0; c < COLS; c++) acc[r][c] = 0.f;

    for (int k = 0; k < K; k += 4) {
        float4 a4[8];
        #pragma unroll
        for (int r = 0; r < 8; r++) a4[r] = *(const float4*)(As + r * K + k);
        #pragma unroll
        for (int kk = 0; kk < 4; kk++) {
            float w[COLS];
            #pragma unroll
            for (int c = 0; c < COLS; c++) w[c] = W[(long)(k + kk) * N + t + c * 256];
            #pragma unroll
            for (int r = 0; r < 8; r++) {
                float a = ((const float*)&a4[r])[kk];
                #pragma unroll
                for (int c = 0; c < COLS; c++) acc[r][c] = fmaf(a, w[c], acc[r][c]);
            }
        }
    }
    #pragma unroll
    for (int r = 0; r < 8; r++)
        #pragma unroll
        for (int c = 0; c < COLS; c++) {
            int col = t + c * 256;
            C[(long)(r0 + r) * N + col] = acc[r][c] + bias[col];
        }
}

// ---------------- K3: per-row LayerNorm -> gelu -> L2 normalize (in place) --
__global__ __launch_bounds__(256) void k_ln_gelu_norm(const float* __restrict__ Zin,
                                                      const float* __restrict__ g,
                                                      const float* __restrict__ b,
                                                      float* __restrict__ Z) {
    long row = blockIdx.x;
    int t = threadIdx.x;
    __shared__ float sm4[4];
    float x0 = Zin[row * P_DIM + t], x1 = Zin[row * P_DIM + t + 256];
    float mu = block_reduce_sum(x0 + x1, sm4) * (1.0f / P_DIM);
    float d0 = x0 - mu, d1 = x1 - mu;
    float var = block_reduce_sum(d0 * d0 + d1 * d1, sm4) * (1.0f / P_DIM);
    float rs = 1.0f / sqrtf(var + 1e-5f);
    float y0 = gelu_exact(d0 * rs * g[t] + b[t]);
    float y1 = gelu_exact(d1 * rs * g[t + 256] + b[t + 256]);
    float nn = block_reduce_sum(y0 * y0 + y1 * y1, sm4);
    float n = fmaxf(sqrtf(nn), 1e-12f);
    Z[row * P_DIM + t]       = y0 / n;
    Z[row * P_DIM + t + 256] = y1 / n;
}

// ---------------- K4: anchor argmax over 1024 centroids, gather position ----
__global__ __launch_bounds__(256) void k_anchor(const float* __restrict__ Z,
                                                const float* __restrict__ cent,
                                                const float* __restrict__ spos,
                                                float* __restrict__ pos) {
    __shared__ float Zs[8 * P_DIM];
    __shared__ float sv[256];
    __shared__ int   si[256];
    int r0 = blockIdx.x * 8, t = threadIdx.x;
    const float4* Zin = (const float4*)(Z + (long)r0 * P_DIM);
    #pragma unroll
    for (int u = 0; u < 4; u++) ((float4*)Zs)[t + u * 256] = Zin[t + u * 256];
    __syncthreads();

    float best[8];
    int bidx[8];
    #pragma unroll
    for (int r = 0; r < 8; r++) { best[r] = -1e30f; bidx[r] = 0; }

    for (int m = 0; m < 4; m++) {
        int p = t + m * 256;  // ascending per thread -> strict > keeps lowest p
        float acc[8];
        #pragma unroll
        for (int r = 0; r < 8; r++) acc[r] = 0.f;
        const float4* cp = (const float4*)(cent + (long)p * P_DIM);
        for (int kk = 0; kk < P_DIM / 4; kk++) {
            float4 c4 = cp[kk];
            #pragma unroll
            for (int r = 0; r < 8; r++) {
                float4 z4 = ((const float4*)(Zs + r * P_DIM))[kk];
                acc[r] += z4.x * c4.x + z4.y * c4.y + z4.z * c4.z + z4.w * c4.w;
            }
        }
        #pragma unroll
        for (int r = 0; r < 8; r++)
            if (acc[r] > best[r]) { best[r] = acc[r]; bidx[r] = p; }
    }
    for (int r = 0; r < 8; r++) {
        sv[t] = best[r]; si[t] = bidx[r];
        __syncthreads();
        for (int off = 128; off; off >>= 1) {
            if (t < off) {
                if (sv[t + off] > sv[t] ||
                    (sv[t + off] == sv[t] && si[t + off] < si[t])) {
                    sv[t] = sv[t + off]; si[t] = si[t + off];
                }
            }
            __syncthreads();
        }
        if (t == 0) pos[r0 + r] = spos[si[0]];
        __syncthreads();
    }
}

// ---------------- K6: exact jax-tiebreak top-128 neighbor select ------------
__global__ __launch_bounds__(256) void k_routes(const float* __restrict__ pos,
                                                int* __restrict__ routes) {
    int bi = blockIdx.x;          // global query token
    int b = bi >> 11, i = bi & 2047;
    int t = threadIdx.x;
    __shared__ float ps[S_LEN];
    __shared__ unsigned int hist[256];
    __shared__ int sh_digit;
    __shared__ unsigned int sh_cum;
    __shared__ unsigned int cnt;

    #pragma unroll
    for (int u = 0; u < 8; u++) ps[t + u * 256] = pos[b * S_LEN + t + u * 256];
    __syncthreads();
    float pi = ps[i];

    unsigned long long key[8];
    #pragma unroll
    for (int u = 0; u < 8; u++) {
        int j = t + u * 256;
        float d = fabsf(pi - ps[j]);
        key[u] = (((unsigned long long)__float_as_uint(d)) << 11) | (unsigned)j;
    }

    unsigned long long prefix = 0;
    int want = KN;
    for (int pass = 0; pass < 6; pass++) {
        int shift = 40 - pass * 8;
        hist[t] = 0;
        __syncthreads();
        #pragma unroll
        for (int u = 0; u < 8; u++) {
            if ((key[u] >> (shift + 8)) == prefix)
                atomicAdd(&hist[(unsigned)((key[u] >> shift) & 0xFF)], 1u);
        }
        __syncthreads();
        if (t == 0) {
            unsigned int cum = 0;
            int d = 0;
            for (; d < 256; d++) {
                unsigned h = hist[d];
                if (cum + h >= (unsigned)want) break;
                cum += h;
            }
            if (d == 256) d = 255;  // unreachable guard
            sh_digit = d; sh_cum = cum;
        }
        __syncthreads();
        prefix = (prefix << 8) | (unsigned)sh_digit;
        want -= (int)sh_cum;
        __syncthreads();
    }
    unsigned long long KTH = prefix;  // exact 128th-smallest key
    if (t == 0) cnt = 0;
    __syncthreads();
    int out_base = bi * KN;
    #pragma unroll
    for (int u = 0; u < 8; u++) {
        if (key[u] <= KTH) {
            unsigned slot = atomicAdd(&cnt, 1u);
            routes[out_base + slot] = (int)(key[u] & 0x7FF);
        }
    }
}

// ---------------- K7: gathered attention per (b, query) ---------------------
__global__ __launch_bounds__(256) void k_attn(const float* __restrict__ qkv,
                                              const int* __restrict__ routes,
                                              float* __restrict__ attn_out) {
    int bi = blockIdx.x;
    int b = bi >> 11;
    int t = threadIdx.x;
    __shared__ float qs[P_DIM];
    __shared__ int rts[KN];
    __shared__ float sc[NHEAD * KN];

    const float* qrow = qkv + (long)bi * (3 * P_DIM);
    qs[t] = qrow[t]; qs[t + 256] = qrow[t + 256];
    if (t < KN) rts[t] = routes[bi * KN + t];
    __syncthreads();

    // phase 1: scores
    #pragma unroll
    for (int m = 0; m < 4; m++) {
        int pix = t + m * 256;
        int h = pix >> 7, jj = pix & 127;
        long gt = (long)(b * S_LEN + rts[jj]) * (3 * P_DIM);
        const float4* kp = (const float4*)(qkv + gt + P_DIM + h * HD);
        const float4* qp = (const float4*)(qs + h * HD);
        float s = 0.f;
        #pragma unroll
        for (int kk = 0; kk < HD / 4; kk++) {
            float4 kv = kp[kk], qv = qp[kk];
            s += qv.x * kv.x + qv.y * kv.y + qv.z * kv.z + qv.w * kv.w;
        }
        sc[pix] = s * 0.125f;
    }
    __syncthreads();

    // phase 2: softmax per head (8 groups of 32 lanes)
    {
        int g = t >> 5, lane = t & 31;
        float v0 = sc[g * KN + lane],      v1 = sc[g * KN + lane + 32];
        float v2 = sc[g * KN + lane + 64], v3 = sc[g * KN + lane + 96];
        float mx = fmaxf(fmaxf(v0, v1), fmaxf(v2, v3));
        #pragma unroll
        for (int off = 16; off; off >>= 1) mx = fmaxf(mx, __shfl_xor(mx, off, 32));
        float e0 = expf(v0 - mx), e1 = expf(v1 - mx);
        float e2 = expf(v2 - mx), e3 = expf(v3 - mx);
        float sum = e0 + e1 + e2 + e3;
        #pragma unroll
        for (int off = 16; off; off >>= 1) sum += __shfl_xor(sum, off, 32);
        float inv = 1.0f / sum;
        sc[g * KN + lane]      = e0 * inv; sc[g * KN + lane + 32] = e1 * inv;
        sc[g * KN + lane + 64] = e2 * inv; sc[g * KN + lane + 96] = e3 * inv;
    }
    __syncthreads();

    // phase 3: out[h,d] = sum_jj p * v
    #pragma unroll
    for (int m = 0; m < 2; m++) {
        int o = t + m * 256;
        int h = o >> 6, d = o & 63;
        float acc = 0.f;
        for (int jj = 0; jj < KN; jj++) {
            long gt = (long)(b * S_LEN + rts[jj]) * (3 * P_DIM);
            acc = fmaf(sc[h * KN + jj], qkv[gt + 2 * P_DIM + h * HD + d], acc);
        }
        attn_out[(long)bi * P_DIM + o] = acc;
    }
}

// ---------------- K9: pooled partial sums (atomic) --------------------------
__global__ __launch_bounds__(256) void k_pool(const float* __restrict__ zatt,
                                              float* __restrict__ pooled) {
    int b = blockIdx.y, chunk = blockIdx.x, t = threadIdx.x;
    float a0 = 0.f, a1 = 0.f;
    for (int s = 0; s < 128; s++) {
        long row = ((long)b * S_LEN + chunk * 128 + s) * P_DIM;
        a0 += zatt[row + t];
        a1 += zatt[row + t + 256];
    }
    atomicAdd(&pooled[b * P_DIM + t], a0);
    atomicAdd(&pooled[b * P_DIM + t + 256], a1);
}

// ---------------- Expert stage 1: h = pooled/S @ w1 + b1 (all 3 experts) ----
// h layout per batch row: [0,256) e0 | [256,768) e1 | [768,1792) e2
__global__ __launch_bounds__(256) void k_exp_fc1(const float* __restrict__ pooled,
                                                 const float* __restrict__ w1_0, const float* __restrict__ b1_0,
                                                 const float* __restrict__ w1_1, const float* __restrict__ b1_1,
                                                 const float* __restrict__ w1_2, const float* __restrict__ b1_2,
                                                 float* __restrict__ h) {
    int t = threadIdx.x, b = blockIdx.y;
    int c = blockIdx.x * 256 + t;  // [0, 1792)
    __shared__ float pl[P_DIM];
    pl[t]       = pooled[b * P_DIM + t]       * (1.0f / S_LEN);
    pl[t + 256] = pooled[b * P_DIM + t + 256] * (1.0f / S_LEN);
    __syncthreads();

    const float* wp; const float* bp; int s2, j;
    if (c < 256)      { wp = w1_0; bp = b1_0; s2 = 256;  j = c; }
    else if (c < 768) { wp = w1_1; bp = b1_1; s2 = 512;  j = c - 256; }
    else              { wp = w1_2; bp = b1_2; s2 = 1024; j = c - 768; }

    const float* p = wp + j;
    float acc = 0.f;
    #pragma unroll 16
    for (int k = 0; k < P_DIM; k++) {
        acc = fmaf(pl[k], *p, acc);
        p += s2;
    }
    h[(long)b * 1792 + c] = acc + bp[j];
}

// ---------------- Expert stage 2: LN + gelu per (expert, batch) -------------
__global__ __launch_bounds__(256) void k_exp_ln(float* __restrict__ h,
                                                const float* __restrict__ g0, const float* __restrict__ bb0,
                                                const float* __restrict__ g1, const float* __restrict__ bb1,
                                                const float* __restrict__ g2, const float* __restrict__ bb2) {
    int e = blockIdx.x, b = blockIdx.y, t = threadIdx.x;
    __shared__ float sm4[4];
    const int offs[3] = {0, 256, 768};
    const int ns[3]   = {256, 512, 1024};
    const float* gs[3]  = {g0, g1, g2};
    const float* bbs[3] = {bb0, bb1, bb2};
    int n = ns[e];
    float* hp = h + (long)b * 1792 + offs[e];
    const float* g = gs[e]; const float* bb = bbs[e];

    float x[4];
    float loc = 0.f;
    for (int u = 0; u < 4; u++) {
        int j = t + u * 256;
        x[u] = (j < n) ? hp[j] : 0.f;
        loc += x[u];
    }
    float mu = block_reduce_sum(loc, sm4) / (float)n;
    loc = 0.f;
    for (int u = 0; u < 4; u++) {
        int j = t + u * 256;
        if (j < n) { float d = x[u] - mu; loc += d * d; }
    }
    float var = block_reduce_sum(loc, sm4) / (float)n;
    float rs = 1.0f / sqrtf(var + 1e-5f);
    for (int u = 0; u < 4; u++) {
        int j = t + u * 256;
        if (j < n) hp[j] = gelu_exact((x[u] - mu) * rs * g[j] + bb[j]);
    }
}

// ---------------- Expert stage 3: out = h @ w2 + b2 (all 3 experts) ---------
// out layout per batch row: [0,128) e0 | [128,384) e1 | [384,896) e2
__global__ __launch_bounds__(256) void k_exp_fc2(const float* __restrict__ h,
                                                 const float* __restrict__ w2_0, const float* __restrict__ b2_0,
                                                 const float* __restrict__ w2_1, const float* __restrict__ b2_1,
                                                 const float* __restrict__ w2_2, const float* __restrict__ b2_2,
                                                 float* __restrict__ out) {
    int t = threadIdx.x, b = blockIdx.y;
    int c = blockIdx.x * 256 + t;  // [0, 1024), valid < 896
    __shared__ float hs[1792];
    for (int u = 0; u < 7; u++) hs[t + u * 256] = h[(long)b * 1792 + t + u * 256];
    __syncthreads();
    if (c >= 896) return;

    const float* wp; const float* bp; int s2, sN, j, off_h;
    if (c < 128)      { wp = w2_0; bp = b2_0; s2 = 256;  sN = 128; j = c;       off_h = 0; }
    else if (c < 384) { wp = w2_1; bp = b2_1; s2 = 512;  sN = 256; j = c - 128; off_h = 256; }
    else              { wp = w2_2; bp = b2_2; s2 = 1024; sN = 512; j = c - 384; off_h = 768; }

    const float* p = wp + j;
    const float* hh = hs + off_h;
    float acc = 0.f;
    #pragma unroll 16
    for (int k = 0; k < s2; k++) {
        acc = fmaf(hh[k], *p, acc);
        p += sN;
    }
    out[b * 896 + c] = acc + bp[j];
}

// ---------------------------------------------------------------------------
extern "C" void kernel_launch(void* const* d_in, const int* in_sizes, int n_in,
                              void* d_out, int out_size, void* d_ws, size_t ws_size,
                              hipStream_t stream) {
    const float* seq   = (const float*)d_in[0];
    const float* penta = (const float*)d_in[1];
    const float* spos  = (const float*)d_in[2];
    const float* projW = (const float*)d_in[3];
    const float* projb = (const float*)d_in[4];
    const float* lng   = (const float*)d_in[5];
    const float* lnb   = (const float*)d_in[6];
    const float* qkvW  = (const float*)d_in[7];
    const float* qkvb  = (const float*)d_in[8];
    const float* outW  = (const float*)d_in[9];
    const float* outb  = (const float*)d_in[10];

    float* ws     = (float*)d_ws;
    float* cent   = ws;                   // 1024*512
    float* z      = cent + 524288;        // 4096*512
    float* qkv    = z + 2097152;          // 4096*1536
    float* pos    = qkv + 6291456;        // 4096
    float* attn   = pos + 4096;           // 4096*512
    float* zatt   = attn + 2097152;       // 4096*512
    float* pooled = zatt + 2097152;       // 1024
    int*   routes = (int*)(pooled + 1024);// 4096*128
    float* hbuf   = (float*)(routes + 524288); // 2*1792

    k_cent<<<1024, 256, 0, stream>>>(penta, cent);
    k_gemm<IN_DIM, P_DIM, 2><<<512, 256, 0, stream>>>(seq, projW, projb, z);
    k_ln_gelu_norm<<<4096, 256, 0, stream>>>(z, lng, lnb, z);
    k_anchor<<<512, 256, 0, stream>>>(z, cent, spos, pos);
    k_gemm<P_DIM, 3 * P_DIM, 6><<<512, 256, 0, stream>>>(z, qkvW, qkvb, qkv);
    k_routes<<<4096, 256, 0, stream>>>(pos, routes);
    k_attn<<<4096, 256, 0, stream>>>(qkv, routes, attn);
    k_gemm<P_DIM, P_DIM, 2><<<512, 256, 0, stream>>>(attn, outW, outb, zatt);

    hipMemsetAsync(pooled, 0, 1024 * sizeof(float), stream);
    dim3 pg(16, 2);
    k_pool<<<pg, 256, 0, stream>>>(zatt, pooled);

    dim3 g1(7, 2);
    k_exp_fc1<<<g1, 256, 0, stream>>>(pooled,
        (const float*)d_in[11], (const float*)d_in[12],
        (const float*)d_in[17], (const float*)d_in[18],
        (const float*)d_in[23], (const float*)d_in[24], hbuf);
    dim3 g2(3, 2);
    k_exp_ln<<<g2, 256, 0, stream>>>(hbuf,
        (const float*)d_in[13], (const float*)d_in[14],
        (const float*)d_in[19], (const float*)d_in[20],
        (const float*)d_in[25], (const float*)d_in[26]);
    dim3 g3(4, 2);
    k_exp_fc2<<<g3, 256, 0, stream>>>(hbuf,
        (const float*)d_in[15], (const float*)d_in[16],
        (const float*)d_in[21], (const float*)d_in[22],
        (const float*)d_in[27], (const float*)d_in[28], (float*)d_out);
}

// Round 3
// 983.387 us; speedup vs baseline: 1.4923x; 1.0002x over previous
//
#include <hip/hip_runtime.h>
#include <math.h>

#define DEV __device__ __forceinline__

static constexpr int S_LEN  = 2048;
static constexpr int IN_DIM = 1024;
static constexpr int P_DIM  = 512;
static constexpr int NHEAD  = 8;
static constexpr int HD     = 64;
static constexpr int KN     = 128;

DEV float gelu_exact(float x) {
    return 0.5f * x * (1.0f + erff(x * 0.70710678118654752440f));
}

// 256-thread block sum reduction. sm4 must be float[4] shared.
DEV float block_reduce_sum(float v, float* sm4) {
    #pragma unroll
    for (int off = 32; off; off >>= 1) v += __shfl_down(v, off, 64);
    int lane = threadIdx.x & 63, w = threadIdx.x >> 6;
    __syncthreads();
    if (lane == 0) sm4[w] = v;
    __syncthreads();
    return sm4[0] + sm4[1] + sm4[2] + sm4[3];
}

// ---------------- K1: centroids, L2-normalized, stored TRANSPOSED -----------
// centT[d][p] : 512 x 1024, so the anchor GEMM reads it coalesced.
__global__ __launch_bounds__(256) void k_cent(const float* __restrict__ penta,
                                              float* __restrict__ centT) {
    int p = blockIdx.x, t = threadIdx.x;
    __shared__ float sm4[4];
    float c0 = 0.f, c1 = 0.f;
    #pragma unroll
    for (int v = 0; v < 5; v++) {
        const float* row = penta + ((long)p * 5 + v) * P_DIM;
        c0 += row[t];
        c1 += row[t + 256];
    }
    c0 /= 5.0f; c1 /= 5.0f;
    float tot = block_reduce_sum(c0 * c0 + c1 * c1, sm4);
    float n = fmaxf(sqrtf(tot), 1e-12f);
    centT[(long)t * 1024 + p]         = c0 / n;
    centT[(long)(t + 256) * 1024 + p] = c1 / n;
}

// ---------------- 16-row-tiled fp32 GEMM: C = A@W + bias, N-split on grid.y -
template <int K, int N, int COLS>
__global__ __launch_bounds__(256) void k_gemm(const float* __restrict__ A,
                                              const float* __restrict__ W,
                                              const float* __restrict__ bias,
                                              float* __restrict__ C) {
    __shared__ float As[16 * 512];
    int r0 = blockIdx.x * 16, t = threadIdx.x;
    int col_base = blockIdx.y * COLS * 256;

    float acc[16][COLS];
    #pragma unroll
    for (int r = 0; r < 16; r++)
        #pragma unroll
        for (int c = 0; c < COLS; c++) acc[r][c] = 0.f;

    for (int k0 = 0; k0 < K; k0 += 512) {
        __syncthreads();
        #pragma unroll
        for (int idx = t, u = 0; u < 8; u++, idx += 256) {
            int rr = idx >> 7, cc = idx & 127;
            ((float4*)As)[idx] =
                *((const float4*)(A + ((long)(r0 + rr)) * K + k0) + cc);
        }
        __syncthreads();
        for (int k = 0; k < 512; k += 4) {
            float w[4][COLS];
            #pragma unroll
            for (int kk = 0; kk < 4; kk++)
                #pragma unroll
                for (int c = 0; c < COLS; c++)
                    w[kk][c] = W[(long)(k0 + k + kk) * N + col_base + t + c * 256];
            #pragma unroll
            for (int r = 0; r < 16; r++) {
                float4 a4 = *(const float4*)(As + r * 512 + k);
                #pragma unroll
                for (int kk = 0; kk < 4; kk++) {
                    float av = ((const float*)&a4)[kk];
                    #pragma unroll
                    for (int c = 0; c < COLS; c++)
                        acc[r][c] = fmaf(av, w[kk][c], acc[r][c]);
                }
            }
        }
    }
    #pragma unroll
    for (int r = 0; r < 16; r++)
        #pragma unroll
        for (int c = 0; c < COLS; c++) {
            int col = col_base + t + c * 256;
            C[(long)(r0 + r) * N + col] = acc[r][c] + bias[col];
        }
}

// ---------------- K3: per-row LayerNorm -> gelu -> L2 normalize (in place) --
__global__ __launch_bounds__(256) void k_ln_gelu_norm(const float* __restrict__ Zin,
                                                      const float* __restrict__ g,
                                                      const float* __restrict__ b,
                                                      float* __restrict__ Z) {
    long row = blockIdx.x;
    int t = threadIdx.x;
    __shared__ float sm4[4];
    float x0 = Zin[row * P_DIM + t], x1 = Zin[row * P_DIM + t + 256];
    float mu = block_reduce_sum(x0 + x1, sm4) * (1.0f / P_DIM);
    float d0 = x0 - mu, d1 = x1 - mu;
    float var = block_reduce_sum(d0 * d0 + d1 * d1, sm4) * (1.0f / P_DIM);
    float rs = 1.0f / sqrtf(var + 1e-5f);
    float y0 = gelu_exact(d0 * rs * g[t] + b[t]);
    float y1 = gelu_exact(d1 * rs * g[t + 256] + b[t + 256]);
    float nn = block_reduce_sum(y0 * y0 + y1 * y1, sm4);
    float n = fmaxf(sqrtf(nn), 1e-12f);
    Z[row * P_DIM + t]       = y0 / n;
    Z[row * P_DIM + t + 256] = y1 / n;
}

// ---------------- K4: anchor argmax (GEMM vs centT + argmax epilogue) -------
__global__ __launch_bounds__(256) void k_anchor(const float* __restrict__ Z,
                                                const float* __restrict__ centT,
                                                const float* __restrict__ spos,
                                                float* __restrict__ pos) {
    __shared__ float Zs[16 * 512];
    __shared__ float sv[256];
    __shared__ int   si[256];
    int r0 = blockIdx.x * 16, t = threadIdx.x;
    #pragma unroll
    for (int idx = t, u = 0; u < 8; u++, idx += 256)
        ((float4*)Zs)[idx] = ((const float4*)(Z + (long)r0 * P_DIM))[idx];
    __syncthreads();

    float acc[16][4];
    #pragma unroll
    for (int r = 0; r < 16; r++)
        #pragma unroll
        for (int m = 0; m < 4; m++) acc[r][m] = 0.f;

    for (int k = 0; k < 512; k += 4) {
        float c[4][4];
        #pragma unroll
        for (int kk = 0; kk < 4; kk++)
            #pragma unroll
            for (int m = 0; m < 4; m++)
                c[kk][m] = centT[(long)(k + kk) * 1024 + t + m * 256];
        #pragma unroll
        for (int r = 0; r < 16; r++) {
            float4 z4 = *(const float4*)(Zs + r * 512 + k);
            #pragma unroll
            for (int kk = 0; kk < 4; kk++) {
                float zv = ((const float*)&z4)[kk];
                #pragma unroll
                for (int m = 0; m < 4; m++)
                    acc[r][m] = fmaf(zv, c[kk][m], acc[r][m]);
            }
        }
    }
    // per-thread argmax over its 4 p's (ascending p, strict > keeps lowest)
    for (int r = 0; r < 16; r++) {
        float best = -1e30f; int bidx = 0;
        #pragma unroll
        for (int m = 0; m < 4; m++) {
            if (acc[r][m] > best) { best = acc[r][m]; bidx = t + m * 256; }
        }
        sv[t] = best; si[t] = bidx;
        __syncthreads();
        for (int off = 128; off; off >>= 1) {
            if (t < off) {
                if (sv[t + off] > sv[t] ||
                    (sv[t + off] == sv[t] && si[t + off] < si[t])) {
                    sv[t] = sv[t + off]; si[t] = si[t + off];
                }
            }
            __syncthreads();
        }
        if (t == 0) pos[r0 + r] = spos[si[0]];
        __syncthreads();
    }
}

// ---------------- K5: per-batch bitonic argsort of positions ----------------
// key = (pos_bits << 32) | idx  (pos >= 0 so float-bit order == value order)
__global__ __launch_bounds__(256) void k_sort(const float* __restrict__ pos,
                                              int* __restrict__ order,
                                              int* __restrict__ rank_of) {
    int b = blockIdx.x, t = threadIdx.x;
    __shared__ unsigned long long key[2048];
    for (int u = 0; u < 8; u++) {
        int i = t + u * 256;
        key[i] = (((unsigned long long)__float_as_uint(pos[b * 2048 + i])) << 32)
                 | (unsigned)i;
    }
    __syncthreads();
    for (int k = 2; k <= 2048; k <<= 1) {
        for (int j = k >> 1; j > 0; j >>= 1) {
            for (int u = 0; u < 8; u++) {
                int i = t + u * 256;
                int l = i ^ j;
                if (l > i) {
                    bool up = ((i & k) == 0);
                    unsigned long long a = key[i], c = key[l];
                    if ((a > c) == up) { key[i] = c; key[l] = a; }
                }
            }
            __syncthreads();
        }
    }
    for (int u = 0; u < 8; u++) {
        int r = t + u * 256;
        int tok = (int)(key[r] & 0xffffffffu);
        order[b * 2048 + r] = tok;
        rank_of[b * 2048 + tok] = r;
    }
}

// ---------------- K6: exact jax-tiebreak top-128 -> emits RANKS -------------
__global__ __launch_bounds__(256) void k_routes(const float* __restrict__ pos,
                                                const int* __restrict__ rank_of,
                                                int* __restrict__ routes) {
    int bi = blockIdx.x;          // global query token
    int b = bi >> 11, i = bi & 2047;
    int t = threadIdx.x;
    __shared__ float ps[S_LEN];
    __shared__ unsigned int hist[256];
    __shared__ int sh_digit;
    __shared__ unsigned int sh_cum;
    __shared__ unsigned int cnt;

    #pragma unroll
    for (int u = 0; u < 8; u++) ps[t + u * 256] = pos[b * S_LEN + t + u * 256];
    __syncthreads();
    float pi = ps[i];

    unsigned long long key[8];
    #pragma unroll
    for (int u = 0; u < 8; u++) {
        int j = t + u * 256;
        float d = fabsf(pi - ps[j]);
        key[u] = (((unsigned long long)__float_as_uint(d)) << 11) | (unsigned)j;
    }

    unsigned long long prefix = 0;
    int want = KN;
    for (int pass = 0; pass < 6; pass++) {
        int shift = 40 - pass * 8;
        hist[t] = 0;
        __syncthreads();
        #pragma unroll
        for (int u = 0; u < 8; u++) {
            if ((key[u] >> (shift + 8)) == prefix)
                atomicAdd(&hist[(unsigned)((key[u] >> shift) & 0xFF)], 1u);
        }
        __syncthreads();
        if (t == 0) {
            unsigned int cum = 0;
            int d = 0;
            for (; d < 256; d++) {
                unsigned h = hist[d];
                if (cum + h >= (unsigned)want) break;
                cum += h;
            }
            if (d == 256) d = 255;  // unreachable guard
            sh_digit = d; sh_cum = cum;
        }
        __syncthreads();
        prefix = (prefix << 8) | (unsigned)sh_digit;
        want -= (int)sh_cum;
        __syncthreads();
    }
    unsigned long long KTH = prefix;  // exact 128th-smallest key
    if (t == 0) cnt = 0;
    __syncthreads();
    int out_base = bi * KN;
    #pragma unroll
    for (int u = 0; u < 8; u++) {
        if (key[u] <= KTH) {
            unsigned slot = atomicAdd(&cnt, 1u);
            routes[out_base + slot] = rank_of[b * 2048 + (int)(key[u] & 0x7FF)];
        }
    }
}

// ---------------- K7: flash-style gathered attention ------------------------
// Block = 8 rank-adjacent queries. 4 threads per (q,h), 16 dims each.
// Exact membership via per-query bitmap over ranks; online softmax.
__global__ __launch_bounds__(256) void k_attn(const float* __restrict__ qkv,
                                              const int* __restrict__ order,
                                              const int* __restrict__ routes,
                                              float* __restrict__ attn_out) {
    int gb = blockIdx.x;            // 512 blocks
    int b = gb >> 8;
    int r0 = (gb & 255) * 8;
    int t = threadIdx.x;
    int qh = t >> 2;                // 0..63
    int q  = qh >> 3;               // 0..7
    int h  = qh & 7;
    int quarter = t & 3;

    __shared__ float Kch[8 * 512];
    __shared__ float Vch[8 * 512];
    __shared__ unsigned long long bm[8][32];
    __shared__ int sh_tok[8];
    __shared__ int sh_lo, sh_hi;

    if (t < 8) sh_tok[t] = order[b * 2048 + r0 + t];
    if (t == 0) { sh_lo = 1 << 30; sh_hi = 0; }
    ((unsigned long long*)bm)[t] = 0ull;   // 256 words
    __syncthreads();

    int lmin = 1 << 30, lmax = 0;
    #pragma unroll
    for (int u = 0; u < 4; u++) {
        int e = t + u * 256;        // 0..1023
        int qq = e >> 7, kk = e & 127;
        int rk = routes[((long)(b * 2048 + sh_tok[qq])) * KN + kk];
        atomicOr(&bm[qq][rk >> 6], 1ull << (rk & 63));
        lmin = min(lmin, rk); lmax = max(lmax, rk);
    }
    atomicMin(&sh_lo, lmin);
    atomicMax(&sh_hi, lmax);

    // q fragment (16 dims) in registers
    float qreg[16];
    {
        const float* qp = qkv + ((long)(b * 2048 + sh_tok[q])) * 1536
                          + h * HD + quarter * 16;
        #pragma unroll
        for (int i = 0; i < 4; i++) {
            float4 v = ((const float4*)qp)[i];
            qreg[i*4+0]=v.x; qreg[i*4+1]=v.y; qreg[i*4+2]=v.z; qreg[i*4+3]=v.w;
        }
    }
    float O[16];
    #pragma unroll
    for (int i = 0; i < 16; i++) O[i] = 0.f;
    float m = -1e30f, l = 0.f;
    __syncthreads();
    int lo = sh_lo & ~7, hi = sh_hi + 1;

    for (int c0 = lo; c0 < hi; c0 += 8) {
        __syncthreads();   // previous chunk fully consumed
        {
            int nrow4 = min(8, 2048 - c0) * 128;
            #pragma unroll
            for (int u = 0; u < 4; u++) {
                int idx = t + u * 256;          // 0..1023
                if (idx < nrow4) {
                    int rr = idx >> 7, cc = idx & 127;
                    int tok = order[b * 2048 + c0 + rr];
                    const float4* src =
                        (const float4*)(qkv + ((long)(b * 2048 + tok)) * 1536);
                    ((float4*)Kch)[idx] = src[128 + cc];
                    ((float4*)Vch)[idx] = src[256 + cc];
                } else {
                    float4 zz = {0.f, 0.f, 0.f, 0.f};
                    ((float4*)Kch)[idx] = zz;
                    ((float4*)Vch)[idx] = zz;
                }
            }
        }
        __syncthreads();

        float s[8];
        #pragma unroll
        for (int rr = 0; rr < 8; rr++) {
            int rank = c0 + rr;
            bool mem = (rank < 2048) && ((bm[q][rank >> 6] >> (rank & 63)) & 1);
            float sv = -3e38f;
            if (mem) {  // uniform across the 4-lane quad (same q, same rank)
                const float* kp = Kch + rr * 512 + h * HD + quarter * 16;
                float part = 0.f;
                #pragma unroll
                for (int i2 = 0; i2 < 16; i2++) part = fmaf(qreg[i2], kp[i2], part);
                part += __shfl_xor(part, 1, 64);
                part += __shfl_xor(part, 2, 64);
                sv = part * 0.125f;
            }
            s[rr] = sv;
        }
        // online softmax update
        float mx = s[0];
        #pragma unroll
        for (int rr = 1; rr < 8; rr++) mx = fmaxf(mx, s[rr]);
        float mnew = fmaxf(m, mx);
        float alpha = __expf(m - mnew);
        float p[8], psum = 0.f;
        #pragma unroll
        for (int rr = 0; rr < 8; rr++) { p[rr] = __expf(s[rr] - mnew); psum += p[rr]; }
        l = l * alpha + psum;
        m = mnew;
        #pragma unroll
        for (int i2 = 0; i2 < 16; i2++) O[i2] *= alpha;
        #pragma unroll
        for (int rr = 0; rr < 8; rr++) {
            const float* vp = Vch + rr * 512 + h * HD + quarter * 16;
            float pv = p[rr];
            #pragma unroll
            for (int i2 = 0; i2 < 16; i2++) O[i2] = fmaf(pv, vp[i2], O[i2]);
        }
    }

    float inv = 1.0f / l;
    float* op = attn_out + ((long)(b * 2048 + sh_tok[q])) * P_DIM
                + h * HD + quarter * 16;
    #pragma unroll
    for (int i2 = 0; i2 < 4; i2++) {
        float4 v;
        v.x = O[i2*4+0]*inv; v.y = O[i2*4+1]*inv;
        v.z = O[i2*4+2]*inv; v.w = O[i2*4+3]*inv;
        ((float4*)op)[i2] = v;
    }
}

// ---------------- K9: pooled partial sums (atomic) --------------------------
__global__ __launch_bounds__(256) void k_pool(const float* __restrict__ zatt,
                                              float* __restrict__ pooled) {
    int b = blockIdx.y, chunk = blockIdx.x, t = threadIdx.x;
    float a0 = 0.f, a1 = 0.f;
    for (int s = 0; s < 128; s++) {
        long row = ((long)b * S_LEN + chunk * 128 + s) * P_DIM;
        a0 += zatt[row + t];
        a1 += zatt[row + t + 256];
    }
    atomicAdd(&pooled[b * P_DIM + t], a0);
    atomicAdd(&pooled[b * P_DIM + t + 256], a1);
}

// ---------------- Expert stage 1: h = pooled/S @ w1 + b1 (all 3 experts) ----
__global__ __launch_bounds__(256) void k_exp_fc1(const float* __restrict__ pooled,
                                                 const float* __restrict__ w1_0, const float* __restrict__ b1_0,
                                                 const float* __restrict__ w1_1, const float* __restrict__ b1_1,
                                                 const float* __restrict__ w1_2, const float* __restrict__ b1_2,
                                                 float* __restrict__ h) {
    int t = threadIdx.x, b = blockIdx.y;
    int c = blockIdx.x * 256 + t;  // [0, 1792)
    __shared__ float pl[P_DIM];
    pl[t]       = pooled[b * P_DIM + t]       * (1.0f / S_LEN);
    pl[t + 256] = pooled[b * P_DIM + t + 256] * (1.0f / S_LEN);
    __syncthreads();

    const float* wp; const float* bp; int s2, j;
    if (c < 256)      { wp = w1_0; bp = b1_0; s2 = 256;  j = c; }
    else if (c < 768) { wp = w1_1; bp = b1_1; s2 = 512;  j = c - 256; }
    else              { wp = w1_2; bp = b1_2; s2 = 1024; j = c - 768; }

    const float* p = wp + j;
    float acc = 0.f;
    #pragma unroll 16
    for (int k = 0; k < P_DIM; k++) {
        acc = fmaf(pl[k], *p, acc);
        p += s2;
    }
    h[(long)b * 1792 + c] = acc + bp[j];
}

// ---------------- Expert stage 2: LN + gelu per (expert, batch) -------------
__global__ __launch_bounds__(256) void k_exp_ln(float* __restrict__ h,
                                                const float* __restrict__ g0, const float* __restrict__ bb0,
                                                const float* __restrict__ g1, const float* __restrict__ bb1,
                                                const float* __restrict__ g2, const float* __restrict__ bb2) {
    int e = blockIdx.x, b = blockIdx.y, t = threadIdx.x;
    __shared__ float sm4[4];
    const int offs[3] = {0, 256, 768};
    const int ns[3]   = {256, 512, 1024};
    const float* gs[3]  = {g0, g1, g2};
    const float* bbs[3] = {bb0, bb1, bb2};
    int n = ns[e];
    float* hp = h + (long)b * 1792 + offs[e];
    const float* g = gs[e]; const float* bb = bbs[e];

    float x[4];
    float loc = 0.f;
    for (int u = 0; u < 4; u++) {
        int j = t + u * 256;
        x[u] = (j < n) ? hp[j] : 0.f;
        loc += x[u];
    }
    float mu = block_reduce_sum(loc, sm4) / (float)n;
    loc = 0.f;
    for (int u = 0; u < 4; u++) {
        int j = t + u * 256;
        if (j < n) { float d = x[u] - mu; loc += d * d; }
    }
    float var = block_reduce_sum(loc, sm4) / (float)n;
    float rs = 1.0f / sqrtf(var + 1e-5f);
    for (int u = 0; u < 4; u++) {
        int j = t + u * 256;
        if (j < n) hp[j] = gelu_exact((x[u] - mu) * rs * g[j] + bb[j]);
    }
}

// ---------------- Expert stage 3: out = h @ w2 + b2 (all 3 experts) ---------
__global__ __launch_bounds__(256) void k_exp_fc2(const float* __restrict__ h,
                                                 const float* __restrict__ w2_0, const float* __restrict__ b2_0,
                                                 const float* __restrict__ w2_1, const float* __restrict__ b2_1,
                                                 const float* __restrict__ w2_2, const float* __restrict__ b2_2,
                                                 float* __restrict__ out) {
    int t = threadIdx.x, b = blockIdx.y;
    int c = blockIdx.x * 256 + t;  // [0, 1024), valid < 896
    __shared__ float hs[1792];
    for (int u = 0; u < 7; u++) hs[t + u * 256] = h[(long)b * 1792 + t + u * 256];
    __syncthreads();
    if (c >= 896) return;

    const float* wp; const float* bp; int s2, sN, j, off_h;
    if (c < 128)      { wp = w2_0; bp = b2_0; s2 = 256;  sN = 128; j = c;       off_h = 0; }
    else if (c < 384) { wp = w2_1; bp = b2_1; s2 = 512;  sN = 256; j = c - 128; off_h = 256; }
    else              { wp = w2_2; bp = b2_2; s2 = 1024; sN = 512; j = c - 384; off_h = 768; }

    const float* p = wp + j;
    const float* hh = hs + off_h;
    float acc = 0.f;
    #pragma unroll 16
    for (int k = 0; k < s2; k++) {
        acc = fmaf(hh[k], *p, acc);
        p += sN;
    }
    out[b * 896 + c] = acc + bp[j];
}

// ---------------------------------------------------------------------------
extern "C" void kernel_launch(void* const* d_in, const int* in_sizes, int n_in,
                              void* d_out, int out_size, void* d_ws, size_t ws_size,
                              hipStream_t stream) {
    const float* seq   = (const float*)d_in[0];
    const float* penta = (const float*)d_in[1];
    const float* spos  = (const float*)d_in[2];
    const float* projW = (const float*)d_in[3];
    const float* projb = (const float*)d_in[4];
    const float* lng   = (const float*)d_in[5];
    const float* lnb   = (const float*)d_in[6];
    const float* qkvW  = (const float*)d_in[7];
    const float* qkvb  = (const float*)d_in[8];
    const float* outW  = (const float*)d_in[9];
    const float* outb  = (const float*)d_in[10];

    float* ws     = (float*)d_ws;
    float* centT  = ws;                    // 512*1024          = 524288
    float* z      = centT + 524288;        // 4096*512 (also zatt alias)
    float* qkv    = z + 2097152;           // 4096*1536
    float* pos    = qkv + 6291456;         // 4096
    float* attn   = pos + 4096;            // 4096*512
    float* pooled = attn + 2097152;        // 1024
    float* hbuf   = pooled + 1024;         // 2*1792 (pad 4096)
    int*   routes = (int*)(hbuf + 4096);   // 4096*128
    int*   order  = routes + 524288;       // 4096
    int*   rank_of= order + 4096;          // 4096
    float* zatt   = z;                     // alias: z dead after qkv GEMM

    k_cent<<<1024, 256, 0, stream>>>(penta, centT);
    {
        dim3 g(256, 2);
        k_gemm<IN_DIM, P_DIM, 1><<<g, 256, 0, stream>>>(seq, projW, projb, z);
    }
    k_ln_gelu_norm<<<4096, 256, 0, stream>>>(z, lng, lnb, z);
    k_anchor<<<256, 256, 0, stream>>>(z, centT, spos, pos);
    k_sort<<<2, 256, 0, stream>>>(pos, order, rank_of);
    {
        dim3 g(256, 2);
        k_gemm<P_DIM, 3 * P_DIM, 3><<<g, 256, 0, stream>>>(z, qkvW, qkvb, qkv);
    }
    k_routes<<<4096, 256, 0, stream>>>(pos, rank_of, routes);
    k_attn<<<512, 256, 0, stream>>>(qkv, order, routes, attn);
    {
        dim3 g(256, 2);
        k_gemm<P_DIM, P_DIM, 1><<<g, 256, 0, stream>>>(attn, outW, outb, zatt);
    }

    hipMemsetAsync(pooled, 0, 1024 * sizeof(float), stream);
    dim3 pg(16, 2);
    k_pool<<<pg, 256, 0, stream>>>(zatt, pooled);

    dim3 g1(7, 2);
    k_exp_fc1<<<g1, 256, 0, stream>>>(pooled,
        (const float*)d_in[11], (const float*)d_in[12],
        (const float*)d_in[17], (const float*)d_in[18],
        (const float*)d_in[23], (const float*)d_in[24], hbuf);
    dim3 g2(3, 2);
    k_exp_ln<<<g2, 256, 0, stream>>>(hbuf,
        (const float*)d_in[13], (const float*)d_in[14],
        (const float*)d_in[19], (const float*)d_in[20],
        (const float*)d_in[25], (const float*)d_in[26]);
    dim3 g3(4, 2);
    k_exp_fc2<<<g3, 256, 0, stream>>>(hbuf,
        (const float*)d_in[15], (const float*)d_in[16],
        (const float*)d_in[21], (const float*)d_in[22],
        (const float*)d_in[27], (const float*)d_in[28], (float*)d_out);
}

// Round 4
// 660.794 us; speedup vs baseline: 2.2209x; 1.4882x over previous
//
#include <hip/hip_runtime.h>
#include <math.h>

#define DEV __device__ __forceinline__

static constexpr int S_LEN  = 2048;
static constexpr int IN_DIM = 1024;
static constexpr int P_DIM  = 512;
static constexpr int NHEAD  = 8;
static constexpr int HD     = 64;
static constexpr int KN     = 128;

typedef __attribute__((ext_vector_type(8))) short bf16x8;
typedef __attribute__((ext_vector_type(4))) float f32x4;

DEV float gelu_exact(float x) {
    return 0.5f * x * (1.0f + erff(x * 0.70710678118654752440f));
}

// float -> bf16 (RNE), and the split residual helpers
DEV short bf_hi(float x) {
    unsigned u = __float_as_uint(x);
    unsigned r = (u + 0x7fffu + ((u >> 16) & 1u)) >> 16;
    return (short)r;
}
DEV float bf_f(short h) { return __uint_as_float(((unsigned)(unsigned short)h) << 16); }

// 256-thread block sum reduction. sm4 must be float[4] shared.
DEV float block_reduce_sum(float v, float* sm4) {
    #pragma unroll
    for (int off = 32; off; off >>= 1) v += __shfl_down(v, off, 64);
    int lane = threadIdx.x & 63, w = threadIdx.x >> 6;
    __syncthreads();
    if (lane == 0) sm4[w] = v;
    __syncthreads();
    return sm4[0] + sm4[1] + sm4[2] + sm4[3];
}

// ---------------- K1: centroids, L2-normalized, split-bf16 [p][d] -----------
__global__ __launch_bounds__(256) void k_cent(const float* __restrict__ penta,
                                              short* __restrict__ ch,
                                              short* __restrict__ cl) {
    int p = blockIdx.x, t = threadIdx.x;
    __shared__ float sm4[4];
    float c0 = 0.f, c1 = 0.f;
    #pragma unroll
    for (int v = 0; v < 5; v++) {
        const float* row = penta + ((long)p * 5 + v) * P_DIM;
        c0 += row[t];
        c1 += row[t + 256];
    }
    c0 /= 5.0f; c1 /= 5.0f;
    float tot = block_reduce_sum(c0 * c0 + c1 * c1, sm4);
    float n = fmaxf(sqrtf(tot), 1e-12f);
    float v0 = c0 / n, v1 = c1 / n;
    short h0 = bf_hi(v0), h1 = bf_hi(v1);
    ch[p * P_DIM + t]       = h0;
    ch[p * P_DIM + t + 256] = h1;
    cl[p * P_DIM + t]       = bf_hi(v0 - bf_f(h0));
    cl[p * P_DIM + t + 256] = bf_hi(v1 - bf_f(h1));
}

// ---------------- weight transpose + split: W (K x N) -> WT_hi/lo (N x K) ---
template <int K, int N>
__global__ __launch_bounds__(256) void k_wt(const float* __restrict__ W,
                                            short* __restrict__ WTh,
                                            short* __restrict__ WTl) {
    __shared__ float tile[64][65];
    int bk = blockIdx.x, bn = blockIdx.y;
    int t = threadIdx.x;
    int c = t & 63, r4 = t >> 6;
    #pragma unroll
    for (int i = 0; i < 16; i++) {
        int row = r4 + i * 4;
        tile[row][c] = W[(long)(bk * 64 + row) * N + bn * 64 + c];
    }
    __syncthreads();
    #pragma unroll
    for (int i = 0; i < 16; i++) {
        int n = r4 + i * 4;
        float v = tile[c][n];
        short h = bf_hi(v);
        long o = (long)(bn * 64 + n) * K + bk * 64 + c;
        WTh[o] = h;
        WTl[o] = bf_hi(v - bf_f(h));
    }
}

// ---------------- MFMA split-bf16 GEMM: C = A@W + bias ----------------------
// A: fp32 M x K (split on the fly). BT_hi/lo: bf16 N x K (pre-transposed).
// 128x128 block tile, 4 waves in 2x2, each wave 64x64 via 4x4 MFMA 16x16x32.
// EPI 0: C[row][col] = acc + bias[col].
// EPI 1: per-row argmax over cols (first-index ties) -> atomicMax rowkey.
template <int K, int N, int EPI>
__global__ __launch_bounds__(256) void k_mm(const float* __restrict__ A,
                                            const short* __restrict__ BTh,
                                            const short* __restrict__ BTl,
                                            const float* __restrict__ bias,
                                            float* __restrict__ C,
                                            unsigned long long* __restrict__ rowkey) {
    __shared__ short Ah[128 * 40], Al[128 * 40], Bh[128 * 40], Bl[128 * 40];
    int t = threadIdx.x;
    int lane = t & 63, wave = t >> 6;
    int wr = (wave >> 1) * 64, wc = (wave & 1) * 64;
    int m = lane & 15, quad = lane >> 4;
    int rb = blockIdx.x * 128, cb = blockIdx.y * 128;

    f32x4 acc[4][4];
    #pragma unroll
    for (int i = 0; i < 4; i++)
        #pragma unroll
        for (int j = 0; j < 4; j++) acc[i][j] = (f32x4){0.f, 0.f, 0.f, 0.f};

    for (int k0 = 0; k0 < K; k0 += 32) {
        __syncthreads();
        // stage A tile (fp32 -> hi/lo bf16), rows padded to 40 halfwords
        #pragma unroll
        for (int ps = 0; ps < 4; ps++) {
            int row = (t >> 3) + ps * 32;
            int seg = t & 7;
            float4 v = *(const float4*)(A + (long)(rb + row) * K + k0 + seg * 4);
            short h0 = bf_hi(v.x), h1 = bf_hi(v.y), h2 = bf_hi(v.z), h3 = bf_hi(v.w);
            short l0 = bf_hi(v.x - bf_f(h0)), l1 = bf_hi(v.y - bf_f(h1));
            short l2 = bf_hi(v.z - bf_f(h2)), l3 = bf_hi(v.w - bf_f(h3));
            *(short4*)(Ah + row * 40 + seg * 4) = make_short4(h0, h1, h2, h3);
            *(short4*)(Al + row * 40 + seg * 4) = make_short4(l0, l1, l2, l3);
        }
        // stage B tile (pre-split bf16, straight copy of WT rows)
        #pragma unroll
        for (int ps = 0; ps < 2; ps++) {
            int row = (t >> 2) + ps * 64;
            int seg = t & 3;
            *(float4*)(Bh + row * 40 + seg * 8) =
                *(const float4*)(BTh + (long)(cb + row) * K + k0 + seg * 8);
            *(float4*)(Bl + row * 40 + seg * 8) =
                *(const float4*)(BTl + (long)(cb + row) * K + k0 + seg * 8);
        }
        __syncthreads();

        bf16x8 ah[4], al[4], bh[4], bl[4];
        #pragma unroll
        for (int i = 0; i < 4; i++) {
            ah[i] = *(const bf16x8*)(Ah + (wr + i * 16 + m) * 40 + quad * 8);
            al[i] = *(const bf16x8*)(Al + (wr + i * 16 + m) * 40 + quad * 8);
            bh[i] = *(const bf16x8*)(Bh + (wc + i * 16 + m) * 40 + quad * 8);
            bl[i] = *(const bf16x8*)(Bl + (wc + i * 16 + m) * 40 + quad * 8);
        }
        #pragma unroll
        for (int i = 0; i < 4; i++)
            #pragma unroll
            for (int j = 0; j < 4; j++) {
                acc[i][j] = __builtin_amdgcn_mfma_f32_16x16x32_bf16(ah[i], bh[j], acc[i][j], 0, 0, 0);
                acc[i][j] = __builtin_amdgcn_mfma_f32_16x16x32_bf16(ah[i], bl[j], acc[i][j], 0, 0, 0);
                acc[i][j] = __builtin_amdgcn_mfma_f32_16x16x32_bf16(al[i], bh[j], acc[i][j], 0, 0, 0);
            }
    }

    if (EPI == 0) {
        #pragma unroll
        for (int i = 0; i < 4; i++) {
            int gr0 = rb + wr + i * 16 + quad * 4;
            #pragma unroll
            for (int j = 0; j < 4; j++) {
                int gc = cb + wc + j * 16 + m;
                float bv = bias[gc];
                #pragma unroll
                for (int r = 0; r < 4; r++)
                    C[(long)(gr0 + r) * N + gc] = acc[i][j][r] + bv;
            }
        }
    } else {
        #pragma unroll
        for (int i = 0; i < 4; i++) {
            #pragma unroll
            for (int r = 0; r < 4; r++) {
                int gr = rb + wr + i * 16 + quad * 4 + r;
                float bv = acc[i][0][r];
                int bp = cb + wc + m;
                #pragma unroll
                for (int j = 1; j < 4; j++) {
                    float v = acc[i][j][r];
                    int p = cb + wc + j * 16 + m;   // ascending; > keeps lowest p
                    if (v > bv) { bv = v; bp = p; }
                }
                // reduce across the 16 lanes of this quad (they share rows)
                #pragma unroll
                for (int off = 1; off < 16; off <<= 1) {
                    float ov = __shfl_xor(bv, off, 64);
                    int op = __shfl_xor(bp, off, 64);
                    if (ov > bv || (ov == bv && op < bp)) { bv = ov; bp = op; }
                }
                if (m == 0) {
                    unsigned u = __float_as_uint(bv);
                    u = (u & 0x80000000u) ? ~u : (u | 0x80000000u);
                    unsigned long long key =
                        ((unsigned long long)u << 32) | (unsigned)(0xFFFFFFFFu - (unsigned)bp);
                    atomicMax(&rowkey[gr], key);
                }
            }
        }
    }
}

// ---------------- rowkey -> cantor position ---------------------------------
__global__ __launch_bounds__(256) void k_pos(const unsigned long long* __restrict__ rowkey,
                                             const float* __restrict__ spos,
                                             float* __restrict__ pos) {
    int i = blockIdx.x * 256 + threadIdx.x;
    unsigned p = 0xFFFFFFFFu - (unsigned)(rowkey[i] & 0xFFFFFFFFull);
    pos[i] = spos[p];
}

// ---------------- K3: per-row LayerNorm -> gelu -> L2 normalize -------------
__global__ __launch_bounds__(256) void k_ln_gelu_norm(const float* __restrict__ Zin,
                                                      const float* __restrict__ g,
                                                      const float* __restrict__ b,
                                                      float* __restrict__ Z) {
    long row = blockIdx.x;
    int t = threadIdx.x;
    __shared__ float sm4[4];
    float x0 = Zin[row * P_DIM + t], x1 = Zin[row * P_DIM + t + 256];
    float mu = block_reduce_sum(x0 + x1, sm4) * (1.0f / P_DIM);
    float d0 = x0 - mu, d1 = x1 - mu;
    float var = block_reduce_sum(d0 * d0 + d1 * d1, sm4) * (1.0f / P_DIM);
    float rs = 1.0f / sqrtf(var + 1e-5f);
    float y0 = gelu_exact(d0 * rs * g[t] + b[t]);
    float y1 = gelu_exact(d1 * rs * g[t + 256] + b[t + 256]);
    float nn = block_reduce_sum(y0 * y0 + y1 * y1, sm4);
    float n = fmaxf(sqrtf(nn), 1e-12f);
    Z[row * P_DIM + t]       = y0 / n;
    Z[row * P_DIM + t + 256] = y1 / n;
}

// ---------------- K5: per-batch bitonic argsort of positions ----------------
__global__ __launch_bounds__(256) void k_sort(const float* __restrict__ pos,
                                              int* __restrict__ order,
                                              int* __restrict__ rank_of) {
    int b = blockIdx.x, t = threadIdx.x;
    __shared__ unsigned long long key[2048];
    for (int u = 0; u < 8; u++) {
        int i = t + u * 256;
        key[i] = (((unsigned long long)__float_as_uint(pos[b * 2048 + i])) << 32)
                 | (unsigned)i;
    }
    __syncthreads();
    for (int k = 2; k <= 2048; k <<= 1) {
        for (int j = k >> 1; j > 0; j >>= 1) {
            for (int u = 0; u < 8; u++) {
                int i = t + u * 256;
                int l = i ^ j;
                if (l > i) {
                    bool up = ((i & k) == 0);
                    unsigned long long a = key[i], c = key[l];
                    if ((a > c) == up) { key[i] = c; key[l] = a; }
                }
            }
            __syncthreads();
        }
    }
    for (int u = 0; u < 8; u++) {
        int r = t + u * 256;
        int tok = (int)(key[r] & 0xffffffffu);
        order[b * 2048 + r] = tok;
        rank_of[b * 2048 + tok] = r;
    }
}

// ---------------- K6: exact jax-tiebreak top-128 -> emits RANKS -------------
__global__ __launch_bounds__(256) void k_routes(const float* __restrict__ pos,
                                                const int* __restrict__ rank_of,
                                                int* __restrict__ routes) {
    int bi = blockIdx.x;          // global query token
    int b = bi >> 11, i = bi & 2047;
    int t = threadIdx.x;
    __shared__ float ps[S_LEN];
    __shared__ unsigned int hist[256];
    __shared__ int sh_digit;
    __shared__ unsigned int sh_cum;
    __shared__ unsigned int cnt;

    #pragma unroll
    for (int u = 0; u < 8; u++) ps[t + u * 256] = pos[b * S_LEN + t + u * 256];
    __syncthreads();
    float pi = ps[i];

    unsigned long long key[8];
    #pragma unroll
    for (int u = 0; u < 8; u++) {
        int j = t + u * 256;
        float d = fabsf(pi - ps[j]);
        key[u] = (((unsigned long long)__float_as_uint(d)) << 11) | (unsigned)j;
    }

    unsigned long long prefix = 0;
    int want = KN;
    for (int pass = 0; pass < 6; pass++) {
        int shift = 40 - pass * 8;
        hist[t] = 0;
        __syncthreads();
        #pragma unroll
        for (int u = 0; u < 8; u++) {
            if ((key[u] >> (shift + 8)) == prefix)
                atomicAdd(&hist[(unsigned)((key[u] >> shift) & 0xFF)], 1u);
        }
        __syncthreads();
        if (t == 0) {
            unsigned int cum = 0;
            int d = 0;
            for (; d < 256; d++) {
                unsigned h = hist[d];
                if (cum + h >= (unsigned)want) break;
                cum += h;
            }
            if (d == 256) d = 255;  // unreachable guard
            sh_digit = d; sh_cum = cum;
        }
        __syncthreads();
        prefix = (prefix << 8) | (unsigned)sh_digit;
        want -= (int)sh_cum;
        __syncthreads();
    }
    unsigned long long KTH = prefix;  // exact 128th-smallest key
    if (t == 0) cnt = 0;
    __syncthreads();
    int out_base = bi * KN;
    #pragma unroll
    for (int u = 0; u < 8; u++) {
        if (key[u] <= KTH) {
            unsigned slot = atomicAdd(&cnt, 1u);
            routes[out_base + slot] = rank_of[b * 2048 + (int)(key[u] & 0x7FF)];
        }
    }
}

// ---------------- K7: flash-style gathered attention ------------------------
__global__ __launch_bounds__(256) void k_attn(const float* __restrict__ qkv,
                                              const int* __restrict__ order,
                                              const int* __restrict__ routes,
                                              float* __restrict__ attn_out) {
    int gb = blockIdx.x;            // 512 blocks
    int b = gb >> 8;
    int r0 = (gb & 255) * 8;
    int t = threadIdx.x;
    int qh = t >> 2;                // 0..63
    int q  = qh >> 3;               // 0..7
    int h  = qh & 7;
    int quarter = t & 3;

    __shared__ float Kch[8 * 512];
    __shared__ float Vch[8 * 512];
    __shared__ unsigned long long bm[8][32];
    __shared__ int sh_tok[8];
    __shared__ int sh_lo, sh_hi;

    if (t < 8) sh_tok[t] = order[b * 2048 + r0 + t];
    if (t == 0) { sh_lo = 1 << 30; sh_hi = 0; }
    ((unsigned long long*)bm)[t] = 0ull;   // 256 words
    __syncthreads();

    int lmin = 1 << 30, lmax = 0;
    #pragma unroll
    for (int u = 0; u < 4; u++) {
        int e = t + u * 256;        // 0..1023
        int qq = e >> 7, kk = e & 127;
        int rk = routes[((long)(b * 2048 + sh_tok[qq])) * KN + kk];
        atomicOr(&bm[qq][rk >> 6], 1ull << (rk & 63));
        lmin = min(lmin, rk); lmax = max(lmax, rk);
    }
    atomicMin(&sh_lo, lmin);
    atomicMax(&sh_hi, lmax);

    float qreg[16];
    {
        const float* qp = qkv + ((long)(b * 2048 + sh_tok[q])) * 1536
                          + h * HD + quarter * 16;
        #pragma unroll
        for (int i = 0; i < 4; i++) {
            float4 v = ((const float4*)qp)[i];
            qreg[i*4+0]=v.x; qreg[i*4+1]=v.y; qreg[i*4+2]=v.z; qreg[i*4+3]=v.w;
        }
    }
    float O[16];
    #pragma unroll
    for (int i = 0; i < 16; i++) O[i] = 0.f;
    float m = -1e30f, l = 0.f;
    __syncthreads();
    int lo = sh_lo & ~7, hi = sh_hi + 1;

    for (int c0 = lo; c0 < hi; c0 += 8) {
        __syncthreads();   // previous chunk fully consumed
        {
            int nrow4 = min(8, 2048 - c0) * 128;
            #pragma unroll
            for (int u = 0; u < 4; u++) {
                int idx = t + u * 256;          // 0..1023
                if (idx < nrow4) {
                    int rr = idx >> 7, cc = idx & 127;
                    int tok = order[b * 2048 + c0 + rr];
                    const float4* src =
                        (const float4*)(qkv + ((long)(b * 2048 + tok)) * 1536);
                    ((float4*)Kch)[idx] = src[128 + cc];
                    ((float4*)Vch)[idx] = src[256 + cc];
                } else {
                    float4 zz = {0.f, 0.f, 0.f, 0.f};
                    ((float4*)Kch)[idx] = zz;
                    ((float4*)Vch)[idx] = zz;
                }
            }
        }
        __syncthreads();

        float s[8];
        #pragma unroll
        for (int rr = 0; rr < 8; rr++) {
            int rank = c0 + rr;
            bool mem = (rank < 2048) && ((bm[q][rank >> 6] >> (rank & 63)) & 1);
            float sv = -3e38f;
            if (mem) {  // uniform across the 4-lane quad (same q, same rank)
                const float* kp = Kch + rr * 512 + h * HD + quarter * 16;
                float part = 0.f;
                #pragma unroll
                for (int i2 = 0; i2 < 16; i2++) part = fmaf(qreg[i2], kp[i2], part);
                part += __shfl_xor(part, 1, 64);
                part += __shfl_xor(part, 2, 64);
                sv = part * 0.125f;
            }
            s[rr] = sv;
        }
        float mx = s[0];
        #pragma unroll
        for (int rr = 1; rr < 8; rr++) mx = fmaxf(mx, s[rr]);
        float mnew = fmaxf(m, mx);
        float alpha = __expf(m - mnew);
        float p[8], psum = 0.f;
        #pragma unroll
        for (int rr = 0; rr < 8; rr++) { p[rr] = __expf(s[rr] - mnew); psum += p[rr]; }
        l = l * alpha + psum;
        m = mnew;
        #pragma unroll
        for (int i2 = 0; i2 < 16; i2++) O[i2] *= alpha;
        #pragma unroll
        for (int rr = 0; rr < 8; rr++) {
            const float* vp = Vch + rr * 512 + h * HD + quarter * 16;
            float pv = p[rr];
            #pragma unroll
            for (int i2 = 0; i2 < 16; i2++) O[i2] = fmaf(pv, vp[i2], O[i2]);
        }
    }

    float inv = 1.0f / l;
    float* op = attn_out + ((long)(b * 2048 + sh_tok[q])) * P_DIM
                + h * HD + quarter * 16;
    #pragma unroll
    for (int i2 = 0; i2 < 4; i2++) {
        float4 v;
        v.x = O[i2*4+0]*inv; v.y = O[i2*4+1]*inv;
        v.z = O[i2*4+2]*inv; v.w = O[i2*4+3]*inv;
        ((float4*)op)[i2] = v;
    }
}

// ---------------- K9: pooled partial sums (atomic) --------------------------
__global__ __launch_bounds__(256) void k_pool(const float* __restrict__ zatt,
                                              float* __restrict__ pooled) {
    int b = blockIdx.y, chunk = blockIdx.x, t = threadIdx.x;
    float a0 = 0.f, a1 = 0.f;
    for (int s = 0; s < 128; s++) {
        long row = ((long)b * S_LEN + chunk * 128 + s) * P_DIM;
        a0 += zatt[row + t];
        a1 += zatt[row + t + 256];
    }
    atomicAdd(&pooled[b * P_DIM + t], a0);
    atomicAdd(&pooled[b * P_DIM + t + 256], a1);
}

// ---------------- Expert stage 1: h = pooled/S @ w1 + b1 (all 3 experts) ----
__global__ __launch_bounds__(256) void k_exp_fc1(const float* __restrict__ pooled,
                                                 const float* __restrict__ w1_0, const float* __restrict__ b1_0,
                                                 const float* __restrict__ w1_1, const float* __restrict__ b1_1,
                                                 const float* __restrict__ w1_2, const float* __restrict__ b1_2,
                                                 float* __restrict__ h) {
    int t = threadIdx.x, b = blockIdx.y;
    int c = blockIdx.x * 256 + t;  // [0, 1792)
    __shared__ float pl[P_DIM];
    pl[t]       = pooled[b * P_DIM + t]       * (1.0f / S_LEN);
    pl[t + 256] = pooled[b * P_DIM + t + 256] * (1.0f / S_LEN);
    __syncthreads();

    const float* wp; const float* bp; int s2, j;
    if (c < 256)      { wp = w1_0; bp = b1_0; s2 = 256;  j = c; }
    else if (c < 768) { wp = w1_1; bp = b1_1; s2 = 512;  j = c - 256; }
    else              { wp = w1_2; bp = b1_2; s2 = 1024; j = c - 768; }

    const float* p = wp + j;
    float acc = 0.f;
    #pragma unroll 16
    for (int k = 0; k < P_DIM; k++) {
        acc = fmaf(pl[k], *p, acc);
        p += s2;
    }
    h[(long)b * 1792 + c] = acc + bp[j];
}

// ---------------- Expert stage 2: LN + gelu per (expert, batch) -------------
__global__ __launch_bounds__(256) void k_exp_ln(float* __restrict__ h,
                                                const float* __restrict__ g0, const float* __restrict__ bb0,
                                                const float* __restrict__ g1, const float* __restrict__ bb1,
                                                const float* __restrict__ g2, const float* __restrict__ bb2) {
    int e = blockIdx.x, b = blockIdx.y, t = threadIdx.x;
    __shared__ float sm4[4];
    const int offs[3] = {0, 256, 768};
    const int ns[3]   = {256, 512, 1024};
    const float* gs[3]  = {g0, g1, g2};
    const float* bbs[3] = {bb0, bb1, bb2};
    int n = ns[e];
    float* hp = h + (long)b * 1792 + offs[e];
    const float* g = gs[e]; const float* bb = bbs[e];

    float x[4];
    float loc = 0.f;
    for (int u = 0; u < 4; u++) {
        int j = t + u * 256;
        x[u] = (j < n) ? hp[j] : 0.f;
        loc += x[u];
    }
    float mu = block_reduce_sum(loc, sm4) / (float)n;
    loc = 0.f;
    for (int u = 0; u < 4; u++) {
        int j = t + u * 256;
        if (j < n) { float d = x[u] - mu; loc += d * d; }
    }
    float var = block_reduce_sum(loc, sm4) / (float)n;
    float rs = 1.0f / sqrtf(var + 1e-5f);
    for (int u = 0; u < 4; u++) {
        int j = t + u * 256;
        if (j < n) hp[j] = gelu_exact((x[u] - mu) * rs * g[j] + bb[j]);
    }
}

// ---------------- Expert stage 3: out = h @ w2 + b2 (all 3 experts) ---------
__global__ __launch_bounds__(256) void k_exp_fc2(const float* __restrict__ h,
                                                 const float* __restrict__ w2_0, const float* __restrict__ b2_0,
                                                 const float* __restrict__ w2_1, const float* __restrict__ b2_1,
                                                 const float* __restrict__ w2_2, const float* __restrict__ b2_2,
                                                 float* __restrict__ out) {
    int t = threadIdx.x, b = blockIdx.y;
    int c = blockIdx.x * 256 + t;  // [0, 1024), valid < 896
    __shared__ float hs[1792];
    for (int u = 0; u < 7; u++) hs[t + u * 256] = h[(long)b * 1792 + t + u * 256];
    __syncthreads();
    if (c >= 896) return;

    const float* wp; const float* bp; int s2, sN, j, off_h;
    if (c < 128)      { wp = w2_0; bp = b2_0; s2 = 256;  sN = 128; j = c;       off_h = 0; }
    else if (c < 384) { wp = w2_1; bp = b2_1; s2 = 512;  sN = 256; j = c - 128; off_h = 256; }
    else              { wp = w2_2; bp = b2_2; s2 = 1024; sN = 512; j = c - 384; off_h = 768; }

    const float* p = wp + j;
    const float* hh = hs + off_h;
    float acc = 0.f;
    #pragma unroll 16
    for (int k = 0; k < s2; k++) {
        acc = fmaf(hh[k], *p, acc);
        p += sN;
    }
    out[b * 896 + c] = acc + bp[j];
}

// ---------------------------------------------------------------------------
extern "C" void kernel_launch(void* const* d_in, const int* in_sizes, int n_in,
                              void* d_out, int out_size, void* d_ws, size_t ws_size,
                              hipStream_t stream) {
    const float* seq   = (const float*)d_in[0];
    const float* penta = (const float*)d_in[1];
    const float* spos  = (const float*)d_in[2];
    const float* projW = (const float*)d_in[3];
    const float* projb = (const float*)d_in[4];
    const float* lng   = (const float*)d_in[5];
    const float* lnb   = (const float*)d_in[6];
    const float* qkvW  = (const float*)d_in[7];
    const float* qkvb  = (const float*)d_in[8];
    const float* outW  = (const float*)d_in[9];
    const float* outb  = (const float*)d_in[10];

    float* ws      = (float*)d_ws;
    float* z_pre   = ws;                      // 2097152 (zatt alias)
    float* z       = z_pre + 2097152;         // 2097152 (attn alias)
    float* qkv     = z + 2097152;             // 6291456
    float* pos     = qkv + 6291456;           // 4096
    float* pooled  = pos + 4096;              // 1024
    float* hbuf    = pooled + 1024;           // 4096
    unsigned long long* rowkey = (unsigned long long*)(hbuf + 4096);  // 4096 ull
    int*   routes  = (int*)(hbuf + 4096 + 8192);  // 524288
    int*   order   = routes + 524288;         // 4096
    int*   rank_of = order + 4096;            // 4096
    short* cent_h  = (short*)(rank_of + 4096);// 524288 shorts
    short* cent_l  = cent_h + 524288;
    short* pjWT_h  = cent_l + 524288;         // 512x1024
    short* pjWT_l  = pjWT_h + 524288;
    short* qkWT_h  = pjWT_l + 524288;         // 1536x512
    short* qkWT_l  = qkWT_h + 786432;
    short* owWT_h  = qkWT_l + 786432;         // 512x512
    short* owWT_l  = owWT_h + 262144;
    float* attn    = z;       // z dead after qkv GEMM
    float* zatt    = z_pre;   // z_pre dead after ln_gelu

    // weight prep
    k_cent<<<1024, 256, 0, stream>>>(penta, cent_h, cent_l);
    { dim3 g(16, 8);  k_wt<IN_DIM, P_DIM><<<g, 256, 0, stream>>>(projW, pjWT_h, pjWT_l); }
    { dim3 g(8, 24);  k_wt<P_DIM, 3 * P_DIM><<<g, 256, 0, stream>>>(qkvW, qkWT_h, qkWT_l); }
    { dim3 g(8, 8);   k_wt<P_DIM, P_DIM><<<g, 256, 0, stream>>>(outW, owWT_h, owWT_l); }

    // proj -> ln/gelu/norm
    { dim3 g(32, 4);  k_mm<IN_DIM, P_DIM, 0><<<g, 256, 0, stream>>>(seq, pjWT_h, pjWT_l, projb, z_pre, nullptr); }
    k_ln_gelu_norm<<<4096, 256, 0, stream>>>(z_pre, lng, lnb, z);

    // anchor argmax -> positions -> sort
    hipMemsetAsync(rowkey, 0, 4096 * sizeof(unsigned long long), stream);
    { dim3 g(32, 8);  k_mm<P_DIM, 1024, 1><<<g, 256, 0, stream>>>(z, cent_h, cent_l, nullptr, nullptr, rowkey); }
    k_pos<<<16, 256, 0, stream>>>(rowkey, spos, pos);
    k_sort<<<2, 256, 0, stream>>>(pos, order, rank_of);

    // qkv -> routes -> attention -> out-proj
    { dim3 g(32, 12); k_mm<P_DIM, 3 * P_DIM, 0><<<g, 256, 0, stream>>>(z, qkWT_h, qkWT_l, qkvb, qkv, nullptr); }
    k_routes<<<4096, 256, 0, stream>>>(pos, rank_of, routes);
    k_attn<<<512, 256, 0, stream>>>(qkv, order, routes, attn);
    { dim3 g(32, 4);  k_mm<P_DIM, P_DIM, 0><<<g, 256, 0, stream>>>(attn, owWT_h, owWT_l, outb, zatt, nullptr); }

    // pool + experts
    hipMemsetAsync(pooled, 0, 1024 * sizeof(float), stream);
    { dim3 pg(16, 2); k_pool<<<pg, 256, 0, stream>>>(zatt, pooled); }

    dim3 g1(7, 2);
    k_exp_fc1<<<g1, 256, 0, stream>>>(pooled,
        (const float*)d_in[11], (const float*)d_in[12],
        (const float*)d_in[17], (const float*)d_in[18],
        (const float*)d_in[23], (const float*)d_in[24], hbuf);
    dim3 g2(3, 2);
    k_exp_ln<<<g2, 256, 0, stream>>>(hbuf,
        (const float*)d_in[13], (const float*)d_in[14],
        (const float*)d_in[19], (const float*)d_in[20],
        (const float*)d_in[25], (const float*)d_in[26]);
    dim3 g3(4, 2);
    k_exp_fc2<<<g3, 256, 0, stream>>>(hbuf,
        (const float*)d_in[15], (const float*)d_in[16],
        (const float*)d_in[21], (const float*)d_in[22],
        (const float*)d_in[27], (const float*)d_in[28], (float*)d_out);
}

// Round 5
// 651.883 us; speedup vs baseline: 2.2512x; 1.0137x over previous
//
#include <hip/hip_runtime.h>
#include <math.h>

#define DEV __device__ __forceinline__

static constexpr int S_LEN  = 2048;
static constexpr int IN_DIM = 1024;
static constexpr int P_DIM  = 512;
static constexpr int NHEAD  = 8;
static constexpr int HD     = 64;
static constexpr int KN     = 128;

typedef __attribute__((ext_vector_type(8))) short bf16x8;
typedef __attribute__((ext_vector_type(4))) float f32x4;

DEV float gelu_exact(float x) {
    return 0.5f * x * (1.0f + erff(x * 0.70710678118654752440f));
}

// float -> bf16 (RNE), and the split residual helpers
DEV short bf_hi(float x) {
    unsigned u = __float_as_uint(x);
    unsigned r = (u + 0x7fffu + ((u >> 16) & 1u)) >> 16;
    return (short)r;
}
DEV float bf_f(short h) { return __uint_as_float(((unsigned)(unsigned short)h) << 16); }

// 256-thread block sum reduction. sm4 must be float[4] shared.
DEV float block_reduce_sum(float v, float* sm4) {
    #pragma unroll
    for (int off = 32; off; off >>= 1) v += __shfl_down(v, off, 64);
    int lane = threadIdx.x & 63, w = threadIdx.x >> 6;
    __syncthreads();
    if (lane == 0) sm4[w] = v;
    __syncthreads();
    return sm4[0] + sm4[1] + sm4[2] + sm4[3];
}

// ---------------- K1: centroids, L2-normalized, split-bf16 [p][d] -----------
__global__ __launch_bounds__(256) void k_cent(const float* __restrict__ penta,
                                              short* __restrict__ ch,
                                              short* __restrict__ cl) {
    int p = blockIdx.x, t = threadIdx.x;
    __shared__ float sm4[4];
    float c0 = 0.f, c1 = 0.f;
    #pragma unroll
    for (int v = 0; v < 5; v++) {
        const float* row = penta + ((long)p * 5 + v) * P_DIM;
        c0 += row[t];
        c1 += row[t + 256];
    }
    c0 /= 5.0f; c1 /= 5.0f;
    float tot = block_reduce_sum(c0 * c0 + c1 * c1, sm4);
    float n = fmaxf(sqrtf(tot), 1e-12f);
    float v0 = c0 / n, v1 = c1 / n;
    short h0 = bf_hi(v0), h1 = bf_hi(v1);
    ch[p * P_DIM + t]       = h0;
    ch[p * P_DIM + t + 256] = h1;
    cl[p * P_DIM + t]       = bf_hi(v0 - bf_f(h0));
    cl[p * P_DIM + t + 256] = bf_hi(v1 - bf_f(h1));
}

// ---------------- weight transpose + split: W (K x N) -> WT_hi/lo (N x K) ---
template <int K, int N>
__global__ __launch_bounds__(256) void k_wt(const float* __restrict__ W,
                                            short* __restrict__ WTh,
                                            short* __restrict__ WTl) {
    __shared__ float tile[64][65];
    int bk = blockIdx.x, bn = blockIdx.y;
    int t = threadIdx.x;
    int c = t & 63, r4 = t >> 6;
    #pragma unroll
    for (int i = 0; i < 16; i++) {
        int row = r4 + i * 4;
        tile[row][c] = W[(long)(bk * 64 + row) * N + bn * 64 + c];
    }
    __syncthreads();
    #pragma unroll
    for (int i = 0; i < 16; i++) {
        int n = r4 + i * 4;
        float v = tile[c][n];
        short h = bf_hi(v);
        long o = (long)(bn * 64 + n) * K + bk * 64 + c;
        WTh[o] = h;
        WTl[o] = bf_hi(v - bf_f(h));
    }
}

// ---------------- MFMA split-bf16 GEMM: C = A@W + bias ----------------------
// A: fp32 M x K (split on the fly). BT_hi/lo: bf16 N x K (pre-transposed).
// 128x128 block tile, 4 waves in 2x2, each wave 64x64 via 4x4 MFMA 16x16x32.
// EPI 0: C[row][col] = acc + bias[col].
// EPI 1: per-row argmax over cols (first-index ties) -> atomicMax rowkey.
template <int K, int N, int EPI>
__global__ __launch_bounds__(256) void k_mm(const float* __restrict__ A,
                                            const short* __restrict__ BTh,
                                            const short* __restrict__ BTl,
                                            const float* __restrict__ bias,
                                            float* __restrict__ C,
                                            unsigned long long* __restrict__ rowkey) {
    __shared__ short Ah[128 * 40], Al[128 * 40], Bh[128 * 40], Bl[128 * 40];
    int t = threadIdx.x;
    int lane = t & 63, wave = t >> 6;
    int wr = (wave >> 1) * 64, wc = (wave & 1) * 64;
    int m = lane & 15, quad = lane >> 4;
    int rb = blockIdx.x * 128, cb = blockIdx.y * 128;

    f32x4 acc[4][4];
    #pragma unroll
    for (int i = 0; i < 4; i++)
        #pragma unroll
        for (int j = 0; j < 4; j++) acc[i][j] = (f32x4){0.f, 0.f, 0.f, 0.f};

    for (int k0 = 0; k0 < K; k0 += 32) {
        __syncthreads();
        // stage A tile (fp32 -> hi/lo bf16), rows padded to 40 halfwords
        #pragma unroll
        for (int ps = 0; ps < 4; ps++) {
            int row = (t >> 3) + ps * 32;
            int seg = t & 7;
            float4 v = *(const float4*)(A + (long)(rb + row) * K + k0 + seg * 4);
            short h0 = bf_hi(v.x), h1 = bf_hi(v.y), h2 = bf_hi(v.z), h3 = bf_hi(v.w);
            short l0 = bf_hi(v.x - bf_f(h0)), l1 = bf_hi(v.y - bf_f(h1));
            short l2 = bf_hi(v.z - bf_f(h2)), l3 = bf_hi(v.w - bf_f(h3));
            *(short4*)(Ah + row * 40 + seg * 4) = make_short4(h0, h1, h2, h3);
            *(short4*)(Al + row * 40 + seg * 4) = make_short4(l0, l1, l2, l3);
        }
        // stage B tile (pre-split bf16, straight copy of WT rows)
        #pragma unroll
        for (int ps = 0; ps < 2; ps++) {
            int row = (t >> 2) + ps * 64;
            int seg = t & 3;
            *(float4*)(Bh + row * 40 + seg * 8) =
                *(const float4*)(BTh + (long)(cb + row) * K + k0 + seg * 8);
            *(float4*)(Bl + row * 40 + seg * 8) =
                *(const float4*)(BTl + (long)(cb + row) * K + k0 + seg * 8);
        }
        __syncthreads();

        bf16x8 ah[4], al[4], bh[4], bl[4];
        #pragma unroll
        for (int i = 0; i < 4; i++) {
            ah[i] = *(const bf16x8*)(Ah + (wr + i * 16 + m) * 40 + quad * 8);
            al[i] = *(const bf16x8*)(Al + (wr + i * 16 + m) * 40 + quad * 8);
            bh[i] = *(const bf16x8*)(Bh + (wc + i * 16 + m) * 40 + quad * 8);
            bl[i] = *(const bf16x8*)(Bl + (wc + i * 16 + m) * 40 + quad * 8);
        }
        #pragma unroll
        for (int i = 0; i < 4; i++)
            #pragma unroll
            for (int j = 0; j < 4; j++) {
                acc[i][j] = __builtin_amdgcn_mfma_f32_16x16x32_bf16(ah[i], bh[j], acc[i][j], 0, 0, 0);
                acc[i][j] = __builtin_amdgcn_mfma_f32_16x16x32_bf16(ah[i], bl[j], acc[i][j], 0, 0, 0);
                acc[i][j] = __builtin_amdgcn_mfma_f32_16x16x32_bf16(al[i], bh[j], acc[i][j], 0, 0, 0);
            }
    }

    if (EPI == 0) {
        #pragma unroll
        for (int i = 0; i < 4; i++) {
            int gr0 = rb + wr + i * 16 + quad * 4;
            #pragma unroll
            for (int j = 0; j < 4; j++) {
                int gc = cb + wc + j * 16 + m;
                float bv = bias[gc];
                #pragma unroll
                for (int r = 0; r < 4; r++)
                    C[(long)(gr0 + r) * N + gc] = acc[i][j][r] + bv;
            }
        }
    } else {
        #pragma unroll
        for (int i = 0; i < 4; i++) {
            #pragma unroll
            for (int r = 0; r < 4; r++) {
                int gr = rb + wr + i * 16 + quad * 4 + r;
                float bv = acc[i][0][r];
                int bp = cb + wc + m;
                #pragma unroll
                for (int j = 1; j < 4; j++) {
                    float v = acc[i][j][r];
                    int p = cb + wc + j * 16 + m;   // ascending; > keeps lowest p
                    if (v > bv) { bv = v; bp = p; }
                }
                // reduce across the 16 lanes of this quad (they share rows)
                #pragma unroll
                for (int off = 1; off < 16; off <<= 1) {
                    float ov = __shfl_xor(bv, off, 64);
                    int op = __shfl_xor(bp, off, 64);
                    if (ov > bv || (ov == bv && op < bp)) { bv = ov; bp = op; }
                }
                if (m == 0) {
                    unsigned u = __float_as_uint(bv);
                    u = (u & 0x80000000u) ? ~u : (u | 0x80000000u);
                    unsigned long long key =
                        ((unsigned long long)u << 32) | (unsigned)(0xFFFFFFFFu - (unsigned)bp);
                    atomicMax(&rowkey[gr], key);
                }
            }
        }
    }
}

// ---------------- rowkey -> cantor position ---------------------------------
__global__ __launch_bounds__(256) void k_pos(const unsigned long long* __restrict__ rowkey,
                                             const float* __restrict__ spos,
                                             float* __restrict__ pos) {
    int i = blockIdx.x * 256 + threadIdx.x;
    unsigned p = 0xFFFFFFFFu - (unsigned)(rowkey[i] & 0xFFFFFFFFull);
    pos[i] = spos[p];
}

// ---------------- K3: per-row LayerNorm -> gelu -> L2 normalize -------------
__global__ __launch_bounds__(256) void k_ln_gelu_norm(const float* __restrict__ Zin,
                                                      const float* __restrict__ g,
                                                      const float* __restrict__ b,
                                                      float* __restrict__ Z) {
    long row = blockIdx.x;
    int t = threadIdx.x;
    __shared__ float sm4[4];
    float x0 = Zin[row * P_DIM + t], x1 = Zin[row * P_DIM + t + 256];
    float mu = block_reduce_sum(x0 + x1, sm4) * (1.0f / P_DIM);
    float d0 = x0 - mu, d1 = x1 - mu;
    float var = block_reduce_sum(d0 * d0 + d1 * d1, sm4) * (1.0f / P_DIM);
    float rs = 1.0f / sqrtf(var + 1e-5f);
    float y0 = gelu_exact(d0 * rs * g[t] + b[t]);
    float y1 = gelu_exact(d1 * rs * g[t + 256] + b[t + 256]);
    float nn = block_reduce_sum(y0 * y0 + y1 * y1, sm4);
    float n = fmaxf(sqrtf(nn), 1e-12f);
    Z[row * P_DIM + t]       = y0 / n;
    Z[row * P_DIM + t + 256] = y1 / n;
}

// ---------------- K5: per-batch bitonic argsort of positions ----------------
__global__ __launch_bounds__(256) void k_sort(const float* __restrict__ pos,
                                              int* __restrict__ order,
                                              int* __restrict__ rank_of) {
    int b = blockIdx.x, t = threadIdx.x;
    __shared__ unsigned long long key[2048];
    for (int u = 0; u < 8; u++) {
        int i = t + u * 256;
        key[i] = (((unsigned long long)__float_as_uint(pos[b * 2048 + i])) << 32)
                 | (unsigned)i;
    }
    __syncthreads();
    for (int k = 2; k <= 2048; k <<= 1) {
        for (int j = k >> 1; j > 0; j >>= 1) {
            for (int u = 0; u < 8; u++) {
                int i = t + u * 256;
                int l = i ^ j;
                if (l > i) {
                    bool up = ((i & k) == 0);
                    unsigned long long a = key[i], c = key[l];
                    if ((a > c) == up) { key[i] = c; key[l] = a; }
                }
            }
            __syncthreads();
        }
    }
    for (int u = 0; u < 8; u++) {
        int r = t + u * 256;
        int tok = (int)(key[r] & 0xffffffffu);
        order[b * 2048 + r] = tok;
        rank_of[b * 2048 + tok] = r;
    }
}

// ---------------- K6: exact jax-tiebreak top-128 -> emits RANKS -------------
__global__ __launch_bounds__(256) void k_routes(const float* __restrict__ pos,
                                                const int* __restrict__ rank_of,
                                                int* __restrict__ routes) {
    int bi = blockIdx.x;          // global query token
    int b = bi >> 11, i = bi & 2047;
    int t = threadIdx.x;
    __shared__ float ps[S_LEN];
    __shared__ unsigned int hist[256];
    __shared__ int sh_digit;
    __shared__ unsigned int sh_cum;
    __shared__ unsigned int cnt;

    #pragma unroll
    for (int u = 0; u < 8; u++) ps[t + u * 256] = pos[b * S_LEN + t + u * 256];
    __syncthreads();
    float pi = ps[i];

    unsigned long long key[8];
    #pragma unroll
    for (int u = 0; u < 8; u++) {
        int j = t + u * 256;
        float d = fabsf(pi - ps[j]);
        key[u] = (((unsigned long long)__float_as_uint(d)) << 11) | (unsigned)j;
    }

    unsigned long long prefix = 0;
    int want = KN;
    for (int pass = 0; pass < 6; pass++) {
        int shift = 40 - pass * 8;
        hist[t] = 0;
        __syncthreads();
        #pragma unroll
        for (int u = 0; u < 8; u++) {
            if ((key[u] >> (shift + 8)) == prefix)
                atomicAdd(&hist[(unsigned)((key[u] >> shift) & 0xFF)], 1u);
        }
        __syncthreads();
        if (t == 0) {
            unsigned int cum = 0;
            int d = 0;
            for (; d < 256; d++) {
                unsigned h = hist[d];
                if (cum + h >= (unsigned)want) break;
                cum += h;
            }
            if (d == 256) d = 255;  // unreachable guard
            sh_digit = d; sh_cum = cum;
        }
        __syncthreads();
        prefix = (prefix << 8) | (unsigned)sh_digit;
        want -= (int)sh_cum;
        __syncthreads();
    }
    unsigned long long KTH = prefix;  // exact 128th-smallest key
    if (t == 0) cnt = 0;
    __syncthreads();
    int out_base = bi * KN;
    #pragma unroll
    for (int u = 0; u < 8; u++) {
        if (key[u] <= KTH) {
            unsigned slot = atomicAdd(&cnt, 1u);
            routes[out_base + slot] = rank_of[b * 2048 + (int)(key[u] & 0x7FF)];
        }
    }
}

// ---------------- K7: flash-style gathered attention ------------------------
// Block = 16 rank-adjacent queries; thread = (q, h, half). Head stride padded
// to 68 floats (row 544) so b128 LDS reads spread over all bank groups
// ((h + j) mod 8) -> residual 2-way aliasing only (free).
__global__ __launch_bounds__(256) void k_attn(const float* __restrict__ qkv,
                                              const int* __restrict__ order,
                                              const int* __restrict__ routes,
                                              float* __restrict__ attn_out) {
    constexpr int HS = 68;          // padded head stride (floats)
    constexpr int RS = NHEAD * HS;  // 544 floats per row
    int gb = blockIdx.x;            // 256 blocks
    int b = gb >> 7;
    int r0 = (gb & 127) * 16;
    int t = threadIdx.x;
    int q    = t >> 4;              // 0..15
    int h    = (t >> 1) & 7;        // 0..7
    int half = t & 1;               // 0..1  (32 dims each)

    __shared__ float Kch[8 * RS];
    __shared__ float Vch[8 * RS];
    __shared__ unsigned long long bm[16][32];
    __shared__ int sh_tok[16];
    __shared__ int sh_lo, sh_hi;

    if (t < 16) sh_tok[t] = order[b * 2048 + r0 + t];
    if (t == 0) { sh_lo = 1 << 30; sh_hi = 0; }
    {
        unsigned long long* bmf = (unsigned long long*)bm;
        bmf[t] = 0ull; bmf[t + 256] = 0ull;
    }
    __syncthreads();

    int lmin = 1 << 30, lmax = 0;
    #pragma unroll
    for (int u = 0; u < 8; u++) {
        int e = t + u * 256;        // 0..2047
        int qq = e >> 7, kk = e & 127;
        int rk = routes[((long)(b * 2048 + sh_tok[qq])) * KN + kk];
        atomicOr(&bm[qq][rk >> 6], 1ull << (rk & 63));
        lmin = min(lmin, rk); lmax = max(lmax, rk);
    }
    atomicMin(&sh_lo, lmin);
    atomicMax(&sh_hi, lmax);

    // q fragment (32 dims) in registers
    float qreg[32];
    {
        const float* qp = qkv + ((long)(b * 2048 + sh_tok[q])) * 1536
                          + h * HD + half * 32;
        #pragma unroll
        for (int i = 0; i < 8; i++) {
            float4 v = ((const float4*)qp)[i];
            qreg[i*4+0]=v.x; qreg[i*4+1]=v.y; qreg[i*4+2]=v.z; qreg[i*4+3]=v.w;
        }
    }
    float O[32];
    #pragma unroll
    for (int i = 0; i < 32; i++) O[i] = 0.f;
    float m = -1e30f, l = 0.f;
    __syncthreads();
    int lo = sh_lo & ~7, hi = sh_hi + 1;

    for (int c0 = lo; c0 < hi; c0 += 8) {
        __syncthreads();   // previous chunk fully consumed
        {
            int nrow4 = min(8, 2048 - c0) * 128;
            #pragma unroll
            for (int u = 0; u < 4; u++) {
                int idx = t + u * 256;          // 0..1023
                int rr = idx >> 7, cc = idx & 127;
                int hh = cc >> 4, w = cc & 15;
                int dst = rr * (RS/4) + hh * (HS/4) + w;  // float4 index
                if (idx < nrow4) {
                    int tok = order[b * 2048 + c0 + rr];
                    const float4* src =
                        (const float4*)(qkv + ((long)(b * 2048 + tok)) * 1536);
                    ((float4*)Kch)[dst] = src[128 + cc];
                    ((float4*)Vch)[dst] = src[256 + cc];
                } else {
                    float4 zz = {0.f, 0.f, 0.f, 0.f};
                    ((float4*)Kch)[dst] = zz;
                    ((float4*)Vch)[dst] = zz;
                }
            }
        }
        __syncthreads();

        float s[8];
        #pragma unroll
        for (int rr = 0; rr < 8; rr++) {
            int rank = c0 + rr;
            bool mem = (rank < 2048) && ((bm[q][rank >> 6] >> (rank & 63)) & 1);
            float sv = -3e38f;
            if (mem) {  // uniform across the lane pair (same q,h)
                const float* kp = Kch + rr * RS + h * HS + half * 32;
                float part = 0.f;
                #pragma unroll
                for (int i2 = 0; i2 < 32; i2++) part = fmaf(qreg[i2], kp[i2], part);
                part += __shfl_xor(part, 1, 64);
                sv = part * 0.125f;
            }
            s[rr] = sv;
        }
        // online softmax update
        float mx = s[0];
        #pragma unroll
        for (int rr = 1; rr < 8; rr++) mx = fmaxf(mx, s[rr]);
        float mnew = fmaxf(m, mx);
        float alpha = __expf(m - mnew);
        float p[8], psum = 0.f;
        #pragma unroll
        for (int rr = 0; rr < 8; rr++) { p[rr] = __expf(s[rr] - mnew); psum += p[rr]; }
        l = l * alpha + psum;
        m = mnew;
        #pragma unroll
        for (int i2 = 0; i2 < 32; i2++) O[i2] *= alpha;
        #pragma unroll
        for (int rr = 0; rr < 8; rr++) {
            const float* vp = Vch + rr * RS + h * HS + half * 32;
            float pv = p[rr];
            #pragma unroll
            for (int i2 = 0; i2 < 32; i2++) O[i2] = fmaf(pv, vp[i2], O[i2]);
        }
    }

    float inv = 1.0f / l;
    float* op = attn_out + ((long)(b * 2048 + sh_tok[q])) * P_DIM
                + h * HD + half * 32;
    #pragma unroll
    for (int i2 = 0; i2 < 8; i2++) {
        float4 v;
        v.x = O[i2*4+0]*inv; v.y = O[i2*4+1]*inv;
        v.z = O[i2*4+2]*inv; v.w = O[i2*4+3]*inv;
        ((float4*)op)[i2] = v;
    }
}

// ---------------- K9: pooled partial sums (atomic) --------------------------
__global__ __launch_bounds__(256) void k_pool(const float* __restrict__ zatt,
                                              float* __restrict__ pooled) {
    int b = blockIdx.y, chunk = blockIdx.x, t = threadIdx.x;
    float a0 = 0.f, a1 = 0.f;
    for (int s = 0; s < 128; s++) {
        long row = ((long)b * S_LEN + chunk * 128 + s) * P_DIM;
        a0 += zatt[row + t];
        a1 += zatt[row + t + 256];
    }
    atomicAdd(&pooled[b * P_DIM + t], a0);
    atomicAdd(&pooled[b * P_DIM + t + 256], a1);
}

// ---------------- Expert stage 1: h = pooled/S @ w1 + b1 (all 3 experts) ----
__global__ __launch_bounds__(256) void k_exp_fc1(const float* __restrict__ pooled,
                                                 const float* __restrict__ w1_0, const float* __restrict__ b1_0,
                                                 const float* __restrict__ w1_1, const float* __restrict__ b1_1,
                                                 const float* __restrict__ w1_2, const float* __restrict__ b1_2,
                                                 float* __restrict__ h) {
    int t = threadIdx.x, b = blockIdx.y;
    int c = blockIdx.x * 256 + t;  // [0, 1792)
    __shared__ float pl[P_DIM];
    pl[t]       = pooled[b * P_DIM + t]       * (1.0f / S_LEN);
    pl[t + 256] = pooled[b * P_DIM + t + 256] * (1.0f / S_LEN);
    __syncthreads();

    const float* wp; const float* bp; int s2, j;
    if (c < 256)      { wp = w1_0; bp = b1_0; s2 = 256;  j = c; }
    else if (c < 768) { wp = w1_1; bp = b1_1; s2 = 512;  j = c - 256; }
    else              { wp = w1_2; bp = b1_2; s2 = 1024; j = c - 768; }

    const float* p = wp + j;
    float acc = 0.f;
    #pragma unroll 16
    for (int k = 0; k < P_DIM; k++) {
        acc = fmaf(pl[k], *p, acc);
        p += s2;
    }
    h[(long)b * 1792 + c] = acc + bp[j];
}

// ---------------- Expert stage 2: LN + gelu per (expert, batch) -------------
__global__ __launch_bounds__(256) void k_exp_ln(float* __restrict__ h,
                                                const float* __restrict__ g0, const float* __restrict__ bb0,
                                                const float* __restrict__ g1, const float* __restrict__ bb1,
                                                const float* __restrict__ g2, const float* __restrict__ bb2) {
    int e = blockIdx.x, b = blockIdx.y, t = threadIdx.x;
    __shared__ float sm4[4];
    const int offs[3] = {0, 256, 768};
    const int ns[3]   = {256, 512, 1024};
    const float* gs[3]  = {g0, g1, g2};
    const float* bbs[3] = {bb0, bb1, bb2};
    int n = ns[e];
    float* hp = h + (long)b * 1792 + offs[e];
    const float* g = gs[e]; const float* bb = bbs[e];

    float x[4];
    float loc = 0.f;
    for (int u = 0; u < 4; u++) {
        int j = t + u * 256;
        x[u] = (j < n) ? hp[j] : 0.f;
        loc += x[u];
    }
    float mu = block_reduce_sum(loc, sm4) / (float)n;
    loc = 0.f;
    for (int u = 0; u < 4; u++) {
        int j = t + u * 256;
        if (j < n) { float d = x[u] - mu; loc += d * d; }
    }
    float var = block_reduce_sum(loc, sm4) / (float)n;
    float rs = 1.0f / sqrtf(var + 1e-5f);
    for (int u = 0; u < 4; u++) {
        int j = t + u * 256;
        if (j < n) hp[j] = gelu_exact((x[u] - mu) * rs * g[j] + bb[j]);
    }
}

// ---------------- Expert stage 3: out = h @ w2 + b2 (all 3 experts) ---------
__global__ __launch_bounds__(256) void k_exp_fc2(const float* __restrict__ h,
                                                 const float* __restrict__ w2_0, const float* __restrict__ b2_0,
                                                 const float* __restrict__ w2_1, const float* __restrict__ b2_1,
                                                 const float* __restrict__ w2_2, const float* __restrict__ b2_2,
                                                 float* __restrict__ out) {
    int t = threadIdx.x, b = blockIdx.y;
    int c = blockIdx.x * 256 + t;  // [0, 1024), valid < 896
    __shared__ float hs[1792];
    for (int u = 0; u < 7; u++) hs[t + u * 256] = h[(long)b * 1792 + t + u * 256];
    __syncthreads();
    if (c >= 896) return;

    const float* wp; const float* bp; int s2, sN, j, off_h;
    if (c < 128)      { wp = w2_0; bp = b2_0; s2 = 256;  sN = 128; j = c;       off_h = 0; }
    else if (c < 384) { wp = w2_1; bp = b2_1; s2 = 512;  sN = 256; j = c - 128; off_h = 256; }
    else              { wp = w2_2; bp = b2_2; s2 = 1024; sN = 512; j = c - 384; off_h = 768; }

    const float* p = wp + j;
    const float* hh = hs + off_h;
    float acc = 0.f;
    #pragma unroll 16
    for (int k = 0; k < s2; k++) {
        acc = fmaf(hh[k], *p, acc);
        p += sN;
    }
    out[b * 896 + c] = acc + bp[j];
}

// ---------------------------------------------------------------------------
extern "C" void kernel_launch(void* const* d_in, const int* in_sizes, int n_in,
                              void* d_out, int out_size, void* d_ws, size_t ws_size,
                              hipStream_t stream) {
    const float* seq   = (const float*)d_in[0];
    const float* penta = (const float*)d_in[1];
    const float* spos  = (const float*)d_in[2];
    const float* projW = (const float*)d_in[3];
    const float* projb = (const float*)d_in[4];
    const float* lng   = (const float*)d_in[5];
    const float* lnb   = (const float*)d_in[6];
    const float* qkvW  = (const float*)d_in[7];
    const float* qkvb  = (const float*)d_in[8];
    const float* outW  = (const float*)d_in[9];
    const float* outb  = (const float*)d_in[10];

    float* ws      = (float*)d_ws;
    float* z_pre   = ws;                      // 2097152 (zatt alias)
    float* z       = z_pre + 2097152;         // 2097152 (attn alias)
    float* qkv     = z + 2097152;             // 6291456
    float* pos     = qkv + 6291456;           // 4096
    float* pooled  = pos + 4096;              // 1024
    float* hbuf    = pooled + 1024;           // 4096
    unsigned long long* rowkey = (unsigned long long*)(hbuf + 4096);  // 4096 ull
    int*   routes  = (int*)(hbuf + 4096 + 8192);  // 524288
    int*   order   = routes + 524288;         // 4096
    int*   rank_of = order + 4096;            // 4096
    short* cent_h  = (short*)(rank_of + 4096);// 524288 shorts
    short* cent_l  = cent_h + 524288;
    short* pjWT_h  = cent_l + 524288;         // 512x1024
    short* pjWT_l  = pjWT_h + 524288;
    short* qkWT_h  = pjWT_l + 524288;         // 1536x512
    short* qkWT_l  = qkWT_h + 786432;
    short* owWT_h  = qkWT_l + 786432;         // 512x512
    short* owWT_l  = owWT_h + 262144;
    float* attn    = z;       // z dead after qkv GEMM
    float* zatt    = z_pre;   // z_pre dead after ln_gelu

    // weight prep
    k_cent<<<1024, 256, 0, stream>>>(penta, cent_h, cent_l);
    { dim3 g(16, 8);  k_wt<IN_DIM, P_DIM><<<g, 256, 0, stream>>>(projW, pjWT_h, pjWT_l); }
    { dim3 g(8, 24);  k_wt<P_DIM, 3 * P_DIM><<<g, 256, 0, stream>>>(qkvW, qkWT_h, qkWT_l); }
    { dim3 g(8, 8);   k_wt<P_DIM, P_DIM><<<g, 256, 0, stream>>>(outW, owWT_h, owWT_l); }

    // proj -> ln/gelu/norm
    { dim3 g(32, 4);  k_mm<IN_DIM, P_DIM, 0><<<g, 256, 0, stream>>>(seq, pjWT_h, pjWT_l, projb, z_pre, nullptr); }
    k_ln_gelu_norm<<<4096, 256, 0, stream>>>(z_pre, lng, lnb, z);

    // anchor argmax -> positions -> sort
    hipMemsetAsync(rowkey, 0, 4096 * sizeof(unsigned long long), stream);
    { dim3 g(32, 8);  k_mm<P_DIM, 1024, 1><<<g, 256, 0, stream>>>(z, cent_h, cent_l, nullptr, nullptr, rowkey); }
    k_pos<<<16, 256, 0, stream>>>(rowkey, spos, pos);
    k_sort<<<2, 256, 0, stream>>>(pos, order, rank_of);

    // qkv -> routes -> attention -> out-proj
    { dim3 g(32, 12); k_mm<P_DIM, 3 * P_DIM, 0><<<g, 256, 0, stream>>>(z, qkWT_h, qkWT_l, qkvb, qkv, nullptr); }
    k_routes<<<4096, 256, 0, stream>>>(pos, rank_of, routes);
    k_attn<<<256, 256, 0, stream>>>(qkv, order, routes, attn);
    { dim3 g(32, 4);  k_mm<P_DIM, P_DIM, 0><<<g, 256, 0, stream>>>(attn, owWT_h, owWT_l, outb, zatt, nullptr); }

    // pool + experts
    hipMemsetAsync(pooled, 0, 1024 * sizeof(float), stream);
    { dim3 pg(16, 2); k_pool<<<pg, 256, 0, stream>>>(zatt, pooled); }

    dim3 g1(7, 2);
    k_exp_fc1<<<g1, 256, 0, stream>>>(pooled,
        (const float*)d_in[11], (const float*)d_in[12],
        (const float*)d_in[17], (const float*)d_in[18],
        (const float*)d_in[23], (const float*)d_in[24], hbuf);
    dim3 g2(3, 2);
    k_exp_ln<<<g2, 256, 0, stream>>>(hbuf,
        (const float*)d_in[13], (const float*)d_in[14],
        (const float*)d_in[19], (const float*)d_in[20],
        (const float*)d_in[25], (const float*)d_in[26]);
    dim3 g3(4, 2);
    k_exp_fc2<<<g3, 256, 0, stream>>>(hbuf,
        (const float*)d_in[15], (const float*)d_in[16],
        (const float*)d_in[21], (const float*)d_in[22],
        (const float*)d_in[27], (const float*)d_in[28], (float*)d_out);
}

// Round 6
// 589.092 us; speedup vs baseline: 2.4912x; 1.1066x over previous
//
#include <hip/hip_runtime.h>
#include <math.h>

#define DEV __device__ __forceinline__

static constexpr int S_LEN  = 2048;
static constexpr int IN_DIM = 1024;
static constexpr int P_DIM  = 512;
static constexpr int NHEAD  = 8;
static constexpr int HD     = 64;
static constexpr int KN     = 128;

typedef __attribute__((ext_vector_type(8))) short bf16x8;
typedef __attribute__((ext_vector_type(4))) float f32x4;

DEV float gelu_exact(float x) {
    return 0.5f * x * (1.0f + erff(x * 0.70710678118654752440f));
}

// float -> bf16 (RNE), and the split residual helpers
DEV short bf_hi(float x) {
    unsigned u = __float_as_uint(x);
    unsigned r = (u + 0x7fffu + ((u >> 16) & 1u)) >> 16;
    return (short)r;
}
DEV float bf_f(short h) { return __uint_as_float(((unsigned)(unsigned short)h) << 16); }

// 256-thread block sum reduction. sm4 must be float[4] shared.
DEV float block_reduce_sum(float v, float* sm4) {
    #pragma unroll
    for (int off = 32; off; off >>= 1) v += __shfl_down(v, off, 64);
    int lane = threadIdx.x & 63, w = threadIdx.x >> 6;
    __syncthreads();
    if (lane == 0) sm4[w] = v;
    __syncthreads();
    return sm4[0] + sm4[1] + sm4[2] + sm4[3];
}

// ---------------- K1: centroids, L2-normalized, split-bf16 [p][d] -----------
__global__ __launch_bounds__(256) void k_cent(const float* __restrict__ penta,
                                              short* __restrict__ ch,
                                              short* __restrict__ cl) {
    int p = blockIdx.x, t = threadIdx.x;
    __shared__ float sm4[4];
    float c0 = 0.f, c1 = 0.f;
    #pragma unroll
    for (int v = 0; v < 5; v++) {
        const float* row = penta + ((long)p * 5 + v) * P_DIM;
        c0 += row[t];
        c1 += row[t + 256];
    }
    c0 /= 5.0f; c1 /= 5.0f;
    float tot = block_reduce_sum(c0 * c0 + c1 * c1, sm4);
    float n = fmaxf(sqrtf(tot), 1e-12f);
    float v0 = c0 / n, v1 = c1 / n;
    short h0 = bf_hi(v0), h1 = bf_hi(v1);
    ch[p * P_DIM + t]       = h0;
    ch[p * P_DIM + t + 256] = h1;
    cl[p * P_DIM + t]       = bf_hi(v0 - bf_f(h0));
    cl[p * P_DIM + t + 256] = bf_hi(v1 - bf_f(h1));
}

// ---------------- weight transpose + split: W (K x N) -> WT_hi/lo (N x K) ---
template <int K, int N>
__global__ __launch_bounds__(256) void k_wt(const float* __restrict__ W,
                                            short* __restrict__ WTh,
                                            short* __restrict__ WTl) {
    __shared__ float tile[64][65];
    int bk = blockIdx.x, bn = blockIdx.y;
    int t = threadIdx.x;
    int c = t & 63, r4 = t >> 6;
    #pragma unroll
    for (int i = 0; i < 16; i++) {
        int row = r4 + i * 4;
        tile[row][c] = W[(long)(bk * 64 + row) * N + bn * 64 + c];
    }
    __syncthreads();
    #pragma unroll
    for (int i = 0; i < 16; i++) {
        int n = r4 + i * 4;
        float v = tile[c][n];
        short h = bf_hi(v);
        long o = (long)(bn * 64 + n) * K + bk * 64 + c;
        WTh[o] = h;
        WTl[o] = bf_hi(v - bf_f(h));
    }
}

// ---------------- MFMA split-bf16 GEMM: C = A@W + bias ----------------------
template <int K, int N, int EPI>
__global__ __launch_bounds__(256) void k_mm(const float* __restrict__ A,
                                            const short* __restrict__ BTh,
                                            const short* __restrict__ BTl,
                                            const float* __restrict__ bias,
                                            float* __restrict__ C,
                                            unsigned long long* __restrict__ rowkey) {
    __shared__ short Ah[128 * 40], Al[128 * 40], Bh[128 * 40], Bl[128 * 40];
    int t = threadIdx.x;
    int lane = t & 63, wave = t >> 6;
    int wr = (wave >> 1) * 64, wc = (wave & 1) * 64;
    int m = lane & 15, quad = lane >> 4;
    int rb = blockIdx.x * 128, cb = blockIdx.y * 128;

    f32x4 acc[4][4];
    #pragma unroll
    for (int i = 0; i < 4; i++)
        #pragma unroll
        for (int j = 0; j < 4; j++) acc[i][j] = (f32x4){0.f, 0.f, 0.f, 0.f};

    for (int k0 = 0; k0 < K; k0 += 32) {
        __syncthreads();
        #pragma unroll
        for (int ps = 0; ps < 4; ps++) {
            int row = (t >> 3) + ps * 32;
            int seg = t & 7;
            float4 v = *(const float4*)(A + (long)(rb + row) * K + k0 + seg * 4);
            short h0 = bf_hi(v.x), h1 = bf_hi(v.y), h2 = bf_hi(v.z), h3 = bf_hi(v.w);
            short l0 = bf_hi(v.x - bf_f(h0)), l1 = bf_hi(v.y - bf_f(h1));
            short l2 = bf_hi(v.z - bf_f(h2)), l3 = bf_hi(v.w - bf_f(h3));
            *(short4*)(Ah + row * 40 + seg * 4) = make_short4(h0, h1, h2, h3);
            *(short4*)(Al + row * 40 + seg * 4) = make_short4(l0, l1, l2, l3);
        }
        #pragma unroll
        for (int ps = 0; ps < 2; ps++) {
            int row = (t >> 2) + ps * 64;
            int seg = t & 3;
            *(float4*)(Bh + row * 40 + seg * 8) =
                *(const float4*)(BTh + (long)(cb + row) * K + k0 + seg * 8);
            *(float4*)(Bl + row * 40 + seg * 8) =
                *(const float4*)(BTl + (long)(cb + row) * K + k0 + seg * 8);
        }
        __syncthreads();

        bf16x8 ah[4], al[4], bh[4], bl[4];
        #pragma unroll
        for (int i = 0; i < 4; i++) {
            ah[i] = *(const bf16x8*)(Ah + (wr + i * 16 + m) * 40 + quad * 8);
            al[i] = *(const bf16x8*)(Al + (wr + i * 16 + m) * 40 + quad * 8);
            bh[i] = *(const bf16x8*)(Bh + (wc + i * 16 + m) * 40 + quad * 8);
            bl[i] = *(const bf16x8*)(Bl + (wc + i * 16 + m) * 40 + quad * 8);
        }
        #pragma unroll
        for (int i = 0; i < 4; i++)
            #pragma unroll
            for (int j = 0; j < 4; j++) {
                acc[i][j] = __builtin_amdgcn_mfma_f32_16x16x32_bf16(ah[i], bh[j], acc[i][j], 0, 0, 0);
                acc[i][j] = __builtin_amdgcn_mfma_f32_16x16x32_bf16(ah[i], bl[j], acc[i][j], 0, 0, 0);
                acc[i][j] = __builtin_amdgcn_mfma_f32_16x16x32_bf16(al[i], bh[j], acc[i][j], 0, 0, 0);
            }
    }

    if (EPI == 0) {
        #pragma unroll
        for (int i = 0; i < 4; i++) {
            int gr0 = rb + wr + i * 16 + quad * 4;
            #pragma unroll
            for (int j = 0; j < 4; j++) {
                int gc = cb + wc + j * 16 + m;
                float bv = bias[gc];
                #pragma unroll
                for (int r = 0; r < 4; r++)
                    C[(long)(gr0 + r) * N + gc] = acc[i][j][r] + bv;
            }
        }
    } else {
        #pragma unroll
        for (int i = 0; i < 4; i++) {
            #pragma unroll
            for (int r = 0; r < 4; r++) {
                int gr = rb + wr + i * 16 + quad * 4 + r;
                float bv = acc[i][0][r];
                int bp = cb + wc + m;
                #pragma unroll
                for (int j = 1; j < 4; j++) {
                    float v = acc[i][j][r];
                    int p = cb + wc + j * 16 + m;   // ascending; > keeps lowest p
                    if (v > bv) { bv = v; bp = p; }
                }
                #pragma unroll
                for (int off = 1; off < 16; off <<= 1) {
                    float ov = __shfl_xor(bv, off, 64);
                    int op = __shfl_xor(bp, off, 64);
                    if (ov > bv || (ov == bv && op < bp)) { bv = ov; bp = op; }
                }
                if (m == 0) {
                    unsigned u = __float_as_uint(bv);
                    u = (u & 0x80000000u) ? ~u : (u | 0x80000000u);
                    unsigned long long key =
                        ((unsigned long long)u << 32) | (unsigned)(0xFFFFFFFFu - (unsigned)bp);
                    atomicMax(&rowkey[gr], key);
                }
            }
        }
    }
}

// ---------------- rowkey -> cantor position ---------------------------------
__global__ __launch_bounds__(256) void k_pos(const unsigned long long* __restrict__ rowkey,
                                             const float* __restrict__ spos,
                                             float* __restrict__ pos) {
    int i = blockIdx.x * 256 + threadIdx.x;
    unsigned p = 0xFFFFFFFFu - (unsigned)(rowkey[i] & 0xFFFFFFFFull);
    pos[i] = spos[p];
}

// ---------------- K3: per-row LayerNorm -> gelu -> L2 normalize -------------
__global__ __launch_bounds__(256) void k_ln_gelu_norm(const float* __restrict__ Zin,
                                                      const float* __restrict__ g,
                                                      const float* __restrict__ b,
                                                      float* __restrict__ Z) {
    long row = blockIdx.x;
    int t = threadIdx.x;
    __shared__ float sm4[4];
    float x0 = Zin[row * P_DIM + t], x1 = Zin[row * P_DIM + t + 256];
    float mu = block_reduce_sum(x0 + x1, sm4) * (1.0f / P_DIM);
    float d0 = x0 - mu, d1 = x1 - mu;
    float var = block_reduce_sum(d0 * d0 + d1 * d1, sm4) * (1.0f / P_DIM);
    float rs = 1.0f / sqrtf(var + 1e-5f);
    float y0 = gelu_exact(d0 * rs * g[t] + b[t]);
    float y1 = gelu_exact(d1 * rs * g[t + 256] + b[t + 256]);
    float nn = block_reduce_sum(y0 * y0 + y1 * y1, sm4);
    float n = fmaxf(sqrtf(nn), 1e-12f);
    Z[row * P_DIM + t]       = y0 / n;
    Z[row * P_DIM + t + 256] = y1 / n;
}

// ---------------- K5: per-batch bitonic argsort of positions ----------------
// also emits sorted positions (pos_srt[rank]).
__global__ __launch_bounds__(256) void k_sort(const float* __restrict__ pos,
                                              int* __restrict__ order,
                                              float* __restrict__ pos_srt) {
    int b = blockIdx.x, t = threadIdx.x;
    __shared__ unsigned long long key[2048];
    for (int u = 0; u < 8; u++) {
        int i = t + u * 256;
        key[i] = (((unsigned long long)__float_as_uint(pos[b * 2048 + i])) << 32)
                 | (unsigned)i;
    }
    __syncthreads();
    for (int k = 2; k <= 2048; k <<= 1) {
        for (int j = k >> 1; j > 0; j >>= 1) {
            for (int u = 0; u < 8; u++) {
                int i = t + u * 256;
                int l = i ^ j;
                if (l > i) {
                    bool up = ((i & k) == 0);
                    unsigned long long a = key[i], c = key[l];
                    if ((a > c) == up) { key[i] = c; key[l] = a; }
                }
            }
            __syncthreads();
        }
    }
    for (int u = 0; u < 8; u++) {
        int r = t + u * 256;
        unsigned long long kk = key[r];
        order[b * 2048 + r]   = (int)(kk & 0xffffffffu);
        pos_srt[b * 2048 + r] = __uint_as_float((unsigned)(kk >> 32));
    }
}

// ---------------- K6: exact top-128 via rank-window + tie resolution --------
// One thread per query (in rank space). Emits a 2048-bit membership bitmap
// (32 u64 per query-rank) + [lo,hi] member-rank bounds.
// Exactness: T = 128th smallest fp32 distance (identical arithmetic to ref);
// members = {d < T} ∪ {need lowest token indices among d == T}, where the
// d==T ranks form <=2 contiguous rank runs (distance is monotone away from
// the query rank). Matches jax.lax.top_k lexicographic (d, idx) semantics.
__global__ __launch_bounds__(256) void k_routes(const float* __restrict__ pos_srt,
                                                const int* __restrict__ order,
                                                unsigned long long* __restrict__ bmG,
                                                uint2* __restrict__ bounds) {
    int blk = blockIdx.x;                 // 16 blocks
    int b = blk >> 3;
    int r = (blk & 7) * 256 + threadIdx.x;
    int t = threadIdx.x;
    __shared__ float ps[2048];
    __shared__ unsigned short tk[2048];
    for (int u = 0; u < 8; u++) {
        int i = t + u * 256;
        ps[i] = pos_srt[b * 2048 + i];
        tk[i] = (unsigned short)order[b * 2048 + i];
    }
    __syncthreads();

    float pi = ps[r];
    // phase 1: two-pointer expansion, 128 picks (self first)
    int wl = r, wr = r;
    float T = 0.0f;
    for (int n = 1; n < 128; n++) {
        float dl = (wl > 0)    ? (pi - ps[wl - 1]) : 3e38f;
        float dr = (wr < 2047) ? (ps[wr + 1] - pi) : 3e38f;
        if (dl <= dr) { wl--; T = fmaxf(T, dl); }
        else          { wr++; T = fmaxf(T, dr); }
    }

    // phase 2: tie runs with d == T (maximal contiguous, <=2 of them)
    int e1 = 2048, e2 = -1, e3 = 2048, e4 = -1;
    {
        int a = -1;
        if (fabsf(pi - ps[wl]) == T) a = wl;
        else if (wl > 0 && fabsf(pi - ps[wl - 1]) == T) a = wl - 1;
        if (a >= 0) {
            e1 = a; while (e1 > 0 && fabsf(pi - ps[e1 - 1]) == T) e1--;
            e2 = a; while (e2 < 2047 && fabsf(pi - ps[e2 + 1]) == T) e2++;
        }
        if (wr > e2) {
            int a2 = -1;
            if (fabsf(pi - ps[wr]) == T) a2 = wr;
            else if (wr < 2047 && fabsf(pi - ps[wr + 1]) == T) a2 = wr + 1;
            if (a2 >= 0) {
                e3 = a2; while (e3 - 1 > e2 && fabsf(pi - ps[e3 - 1]) == T) e3--;
                e4 = a2; while (e4 < 2047 && fabsf(pi - ps[e4 + 1]) == T) e4++;
            }
        }
    }
    // need = number of d==T members = overlap of tie runs with the window
    int need = 0;
    if (e2 >= e1) need += max(0, min(wr, e2) - max(wl, e1) + 1);
    if (e4 >= e3) need += max(0, min(wr, e4) - max(wl, e3) + 1);
    int tiecount = (e2 >= e1 ? e2 - e1 + 1 : 0) + (e4 >= e3 ? e4 - e3 + 1 : 0);

    // phase 3: token-index threshold X = need-th smallest tie index
    int X = 65535;
    if (need < tiecount) {
        int lo2 = 0, hi2 = 2047;
        while (lo2 < hi2) {
            int mid = (lo2 + hi2) >> 1;
            int cnt = 0;
            for (int j = e1; j <= e2; j++) cnt += (tk[j] <= mid) ? 1 : 0;
            for (int j = e3; j <= e4; j++) cnt += (tk[j] <= mid) ? 1 : 0;
            if (cnt >= need) hi2 = mid; else lo2 = mid + 1;
        }
        X = lo2;
    }

    // phase 4: emit bitmap words + bounds
    int mn = wl, mx = wr;
    if (e2 >= e1) { mn = min(mn, e1); mx = max(mx, e2); }
    if (e4 >= e3) mx = max(mx, e4);
    int qlo = 2048, qhi = -1;
    unsigned long long* bmq = bmG + ((long)(b * 2048 + r)) * 32;
    for (int w = 0; w < 32; w++) {
        unsigned long long bits = 0;
        int lo_r = w << 6, hi_r = lo_r + 63;
        if (hi_r >= mn && lo_r <= mx) {
            int j0 = max(lo_r, mn), j1 = min(hi_r, mx);
            for (int j = j0; j <= j1; j++) {
                float dj = fabsf(pi - ps[j]);
                bool mem;
                if (dj < T) mem = (j >= wl && j <= wr);
                else        mem = (dj == T) && (tk[j] <= X);
                if (mem) {
                    bits |= 1ull << (j - lo_r);
                    qlo = min(qlo, j); qhi = max(qhi, j);
                }
            }
        }
        bmq[w] = bits;
    }
    bounds[b * 2048 + r] = make_uint2((unsigned)qlo, (unsigned)qhi);
}

// ---------------- K7: flash-style gathered attention ------------------------
// Block = 16 rank-adjacent queries; membership from precomputed bitmaps.
__global__ __launch_bounds__(256) void k_attn(const float* __restrict__ qkv,
                                              const int* __restrict__ order,
                                              const unsigned long long* __restrict__ bmG,
                                              const uint2* __restrict__ bounds,
                                              float* __restrict__ attn_out) {
    constexpr int HS = 68;          // padded head stride (floats)
    constexpr int RS = NHEAD * HS;  // 544 floats per row
    int gb = blockIdx.x;            // 256 blocks
    int b = gb >> 7;
    int r0 = (gb & 127) * 16;
    int t = threadIdx.x;
    int q    = t >> 4;              // 0..15
    int h    = (t >> 1) & 7;        // 0..7
    int half = t & 1;               // 0..1  (32 dims each)

    __shared__ float Kch[8 * RS];
    __shared__ float Vch[8 * RS];
    __shared__ unsigned long long bm[16][32];
    __shared__ int sh_tok[16];
    __shared__ int sh_lo, sh_hi;

    if (t < 16) sh_tok[t] = order[b * 2048 + r0 + t];
    if (t == 0) { sh_lo = 1 << 30; sh_hi = 0; }
    {
        const unsigned long long* src = bmG + ((long)(b * 2048 + r0)) * 32;
        ((unsigned long long*)bm)[t]       = src[t];
        ((unsigned long long*)bm)[t + 256] = src[t + 256];
    }
    __syncthreads();
    if (t < 16) {
        uint2 bd = bounds[b * 2048 + r0 + t];
        atomicMin(&sh_lo, (int)bd.x);
        atomicMax(&sh_hi, (int)bd.y);
    }

    // q fragment (32 dims) in registers
    float qreg[32];
    {
        const float* qp = qkv + ((long)(b * 2048 + sh_tok[q])) * 1536
                          + h * HD + half * 32;
        #pragma unroll
        for (int i = 0; i < 8; i++) {
            float4 v = ((const float4*)qp)[i];
            qreg[i*4+0]=v.x; qreg[i*4+1]=v.y; qreg[i*4+2]=v.z; qreg[i*4+3]=v.w;
        }
    }
    float O[32];
    #pragma unroll
    for (int i = 0; i < 32; i++) O[i] = 0.f;
    float m = -1e30f, l = 0.f;
    __syncthreads();
    int lo = sh_lo & ~7, hi = sh_hi + 1;

    for (int c0 = lo; c0 < hi; c0 += 8) {
        __syncthreads();   // previous chunk fully consumed
        {
            int nrow4 = min(8, 2048 - c0) * 128;
            #pragma unroll
            for (int u = 0; u < 4; u++) {
                int idx = t + u * 256;          // 0..1023
                int rr = idx >> 7, cc = idx & 127;
                int hh = cc >> 4, w = cc & 15;
                int dst = rr * (RS/4) + hh * (HS/4) + w;  // float4 index
                if (idx < nrow4) {
                    int tok = order[b * 2048 + c0 + rr];
                    const float4* src =
                        (const float4*)(qkv + ((long)(b * 2048 + tok)) * 1536);
                    ((float4*)Kch)[dst] = src[128 + cc];
                    ((float4*)Vch)[dst] = src[256 + cc];
                } else {
                    float4 zz = {0.f, 0.f, 0.f, 0.f};
                    ((float4*)Kch)[dst] = zz;
                    ((float4*)Vch)[dst] = zz;
                }
            }
        }
        __syncthreads();

        float s[8];
        #pragma unroll
        for (int rr = 0; rr < 8; rr++) {
            int rank = c0 + rr;
            bool mem = (rank < 2048) && ((bm[q][rank >> 6] >> (rank & 63)) & 1);
            float sv = -3e38f;
            if (mem) {  // uniform across the lane pair (same q,h)
                const float* kp = Kch + rr * RS + h * HS + half * 32;
                float part = 0.f;
                #pragma unroll
                for (int i2 = 0; i2 < 32; i2++) part = fmaf(qreg[i2], kp[i2], part);
                part += __shfl_xor(part, 1, 64);
                sv = part * 0.125f;
            }
            s[rr] = sv;
        }
        // online softmax update
        float mx = s[0];
        #pragma unroll
        for (int rr = 1; rr < 8; rr++) mx = fmaxf(mx, s[rr]);
        float mnew = fmaxf(m, mx);
        float alpha = __expf(m - mnew);
        float p[8], psum = 0.f;
        #pragma unroll
        for (int rr = 0; rr < 8; rr++) { p[rr] = __expf(s[rr] - mnew); psum += p[rr]; }
        l = l * alpha + psum;
        m = mnew;
        #pragma unroll
        for (int i2 = 0; i2 < 32; i2++) O[i2] *= alpha;
        #pragma unroll
        for (int rr = 0; rr < 8; rr++) {
            const float* vp = Vch + rr * RS + h * HS + half * 32;
            float pv = p[rr];
            #pragma unroll
            for (int i2 = 0; i2 < 32; i2++) O[i2] = fmaf(pv, vp[i2], O[i2]);
        }
    }

    float inv = 1.0f / l;
    float* op = attn_out + ((long)(b * 2048 + sh_tok[q])) * P_DIM
                + h * HD + half * 32;
    #pragma unroll
    for (int i2 = 0; i2 < 8; i2++) {
        float4 v;
        v.x = O[i2*4+0]*inv; v.y = O[i2*4+1]*inv;
        v.z = O[i2*4+2]*inv; v.w = O[i2*4+3]*inv;
        ((float4*)op)[i2] = v;
    }
}

// ---------------- K9: pooled partial sums (atomic) --------------------------
__global__ __launch_bounds__(256) void k_pool(const float* __restrict__ zatt,
                                              float* __restrict__ pooled) {
    int b = blockIdx.y, chunk = blockIdx.x, t = threadIdx.x;
    float a0 = 0.f, a1 = 0.f;
    for (int s = 0; s < 128; s++) {
        long row = ((long)b * S_LEN + chunk * 128 + s) * P_DIM;
        a0 += zatt[row + t];
        a1 += zatt[row + t + 256];
    }
    atomicAdd(&pooled[b * P_DIM + t], a0);
    atomicAdd(&pooled[b * P_DIM + t + 256], a1);
}

// ---------------- Expert stage 1: h = pooled/S @ w1 + b1 (all 3 experts) ----
__global__ __launch_bounds__(256) void k_exp_fc1(const float* __restrict__ pooled,
                                                 const float* __restrict__ w1_0, const float* __restrict__ b1_0,
                                                 const float* __restrict__ w1_1, const float* __restrict__ b1_1,
                                                 const float* __restrict__ w1_2, const float* __restrict__ b1_2,
                                                 float* __restrict__ h) {
    int t = threadIdx.x, b = blockIdx.y;
    int c = blockIdx.x * 256 + t;  // [0, 1792)
    __shared__ float pl[P_DIM];
    pl[t]       = pooled[b * P_DIM + t]       * (1.0f / S_LEN);
    pl[t + 256] = pooled[b * P_DIM + t + 256] * (1.0f / S_LEN);
    __syncthreads();

    const float* wp; const float* bp; int s2, j;
    if (c < 256)      { wp = w1_0; bp = b1_0; s2 = 256;  j = c; }
    else if (c < 768) { wp = w1_1; bp = b1_1; s2 = 512;  j = c - 256; }
    else              { wp = w1_2; bp = b1_2; s2 = 1024; j = c - 768; }

    const float* p = wp + j;
    float acc = 0.f;
    #pragma unroll 16
    for (int k = 0; k < P_DIM; k++) {
        acc = fmaf(pl[k], *p, acc);
        p += s2;
    }
    h[(long)b * 1792 + c] = acc + bp[j];
}

// ---------------- Expert stage 2: LN + gelu per (expert, batch) -------------
__global__ __launch_bounds__(256) void k_exp_ln(float* __restrict__ h,
                                                const float* __restrict__ g0, const float* __restrict__ bb0,
                                                const float* __restrict__ g1, const float* __restrict__ bb1,
                                                const float* __restrict__ g2, const float* __restrict__ bb2) {
    int e = blockIdx.x, b = blockIdx.y, t = threadIdx.x;
    __shared__ float sm4[4];
    const int offs[3] = {0, 256, 768};
    const int ns[3]   = {256, 512, 1024};
    const float* gs[3]  = {g0, g1, g2};
    const float* bbs[3] = {bb0, bb1, bb2};
    int n = ns[e];
    float* hp = h + (long)b * 1792 + offs[e];
    const float* g = gs[e]; const float* bb = bbs[e];

    float x[4];
    float loc = 0.f;
    for (int u = 0; u < 4; u++) {
        int j = t + u * 256;
        x[u] = (j < n) ? hp[j] : 0.f;
        loc += x[u];
    }
    float mu = block_reduce_sum(loc, sm4) / (float)n;
    loc = 0.f;
    for (int u = 0; u < 4; u++) {
        int j = t + u * 256;
        if (j < n) { float d = x[u] - mu; loc += d * d; }
    }
    float var = block_reduce_sum(loc, sm4) / (float)n;
    float rs = 1.0f / sqrtf(var + 1e-5f);
    for (int u = 0; u < 4; u++) {
        int j = t + u * 256;
        if (j < n) hp[j] = gelu_exact((x[u] - mu) * rs * g[j] + bb[j]);
    }
}

// ---------------- Expert stage 3: out = h @ w2 + b2 (all 3 experts) ---------
__global__ __launch_bounds__(256) void k_exp_fc2(const float* __restrict__ h,
                                                 const float* __restrict__ w2_0, const float* __restrict__ b2_0,
                                                 const float* __restrict__ w2_1, const float* __restrict__ b2_1,
                                                 const float* __restrict__ w2_2, const float* __restrict__ b2_2,
                                                 float* __restrict__ out) {
    int t = threadIdx.x, b = blockIdx.y;
    int c = blockIdx.x * 256 + t;  // [0, 1024), valid < 896
    __shared__ float hs[1792];
    for (int u = 0; u < 7; u++) hs[t + u * 256] = h[(long)b * 1792 + t + u * 256];
    __syncthreads();
    if (c >= 896) return;

    const float* wp; const float* bp; int s2, sN, j, off_h;
    if (c < 128)      { wp = w2_0; bp = b2_0; s2 = 256;  sN = 128; j = c;       off_h = 0; }
    else if (c < 384) { wp = w2_1; bp = b2_1; s2 = 512;  sN = 256; j = c - 128; off_h = 256; }
    else              { wp = w2_2; bp = b2_2; s2 = 1024; sN = 512; j = c - 384; off_h = 768; }

    const float* p = wp + j;
    const float* hh = hs + off_h;
    float acc = 0.f;
    #pragma unroll 16
    for (int k = 0; k < s2; k++) {
        acc = fmaf(hh[k], *p, acc);
        p += sN;
    }
    out[b * 896 + c] = acc + bp[j];
}

// ---------------------------------------------------------------------------
extern "C" void kernel_launch(void* const* d_in, const int* in_sizes, int n_in,
                              void* d_out, int out_size, void* d_ws, size_t ws_size,
                              hipStream_t stream) {
    const float* seq   = (const float*)d_in[0];
    const float* penta = (const float*)d_in[1];
    const float* spos  = (const float*)d_in[2];
    const float* projW = (const float*)d_in[3];
    const float* projb = (const float*)d_in[4];
    const float* lng   = (const float*)d_in[5];
    const float* lnb   = (const float*)d_in[6];
    const float* qkvW  = (const float*)d_in[7];
    const float* qkvb  = (const float*)d_in[8];
    const float* outW  = (const float*)d_in[9];
    const float* outb  = (const float*)d_in[10];

    float* ws      = (float*)d_ws;
    float* z_pre   = ws;                      // 2097152 (zatt alias)
    float* z       = z_pre + 2097152;         // 2097152 (attn alias)
    float* qkv     = z + 2097152;             // 6291456
    float* pos     = qkv + 6291456;           // 4096
    float* pooled  = pos + 4096;              // 1024
    float* hbuf    = pooled + 1024;           // 4096
    unsigned long long* rowkey = (unsigned long long*)(hbuf + 4096);  // 4096 ull
    float* pos_srt = (float*)(rowkey + 4096); // 4096
    int*   order   = (int*)(pos_srt + 4096);  // 4096
    uint2* bounds  = (uint2*)(order + 4096);  // 4096 uint2
    unsigned long long* bmG = (unsigned long long*)(bounds + 4096); // 131072 ull
    short* cent_h  = (short*)(bmG + 131072);  // 524288 shorts
    short* cent_l  = cent_h + 524288;
    short* pjWT_h  = cent_l + 524288;         // 512x1024
    short* pjWT_l  = pjWT_h + 524288;
    short* qkWT_h  = pjWT_l + 524288;         // 1536x512
    short* qkWT_l  = qkWT_h + 786432;
    short* owWT_h  = qkWT_l + 786432;         // 512x512
    short* owWT_l  = owWT_h + 262144;
    float* attn    = z;       // z dead after qkv GEMM
    float* zatt    = z_pre;   // z_pre dead after ln_gelu

    // weight prep
    k_cent<<<1024, 256, 0, stream>>>(penta, cent_h, cent_l);
    { dim3 g(16, 8);  k_wt<IN_DIM, P_DIM><<<g, 256, 0, stream>>>(projW, pjWT_h, pjWT_l); }
    { dim3 g(8, 24);  k_wt<P_DIM, 3 * P_DIM><<<g, 256, 0, stream>>>(qkvW, qkWT_h, qkWT_l); }
    { dim3 g(8, 8);   k_wt<P_DIM, P_DIM><<<g, 256, 0, stream>>>(outW, owWT_h, owWT_l); }

    // proj -> ln/gelu/norm
    { dim3 g(32, 4);  k_mm<IN_DIM, P_DIM, 0><<<g, 256, 0, stream>>>(seq, pjWT_h, pjWT_l, projb, z_pre, nullptr); }
    k_ln_gelu_norm<<<4096, 256, 0, stream>>>(z_pre, lng, lnb, z);

    // anchor argmax -> positions -> sort
    hipMemsetAsync(rowkey, 0, 4096 * sizeof(unsigned long long), stream);
    { dim3 g(32, 8);  k_mm<P_DIM, 1024, 1><<<g, 256, 0, stream>>>(z, cent_h, cent_l, nullptr, nullptr, rowkey); }
    k_pos<<<16, 256, 0, stream>>>(rowkey, spos, pos);
    k_sort<<<2, 256, 0, stream>>>(pos, order, pos_srt);

    // qkv -> routes(bitmap) -> attention -> out-proj
    { dim3 g(32, 12); k_mm<P_DIM, 3 * P_DIM, 0><<<g, 256, 0, stream>>>(z, qkWT_h, qkWT_l, qkvb, qkv, nullptr); }
    k_routes<<<16, 256, 0, stream>>>(pos_srt, order, bmG, bounds);
    k_attn<<<256, 256, 0, stream>>>(qkv, order, bmG, bounds, attn);
    { dim3 g(32, 4);  k_mm<P_DIM, P_DIM, 0><<<g, 256, 0, stream>>>(attn, owWT_h, owWT_l, outb, zatt, nullptr); }

    // pool + experts
    hipMemsetAsync(pooled, 0, 1024 * sizeof(float), stream);
    { dim3 pg(16, 2); k_pool<<<pg, 256, 0, stream>>>(zatt, pooled); }

    dim3 g1(7, 2);
    k_exp_fc1<<<g1, 256, 0, stream>>>(pooled,
        (const float*)d_in[11], (const float*)d_in[12],
        (const float*)d_in[17], (const float*)d_in[18],
        (const float*)d_in[23], (const float*)d_in[24], hbuf);
    dim3 g2(3, 2);
    k_exp_ln<<<g2, 256, 0, stream>>>(hbuf,
        (const float*)d_in[13], (const float*)d_in[14],
        (const float*)d_in[19], (const float*)d_in[20],
        (const float*)d_in[25], (const float*)d_in[26]);
    dim3 g3(4, 2);
    k_exp_fc2<<<g3, 256, 0, stream>>>(hbuf,
        (const float*)d_in[15], (const float*)d_in[16],
        (const float*)d_in[21], (const float*)d_in[22],
        (const float*)d_in[27], (const float*)d_in[28], (float*)d_out);
}

// Round 7
// 565.376 us; speedup vs baseline: 2.5957x; 1.0419x over previous
//
#include <hip/hip_runtime.h>
#include <math.h>

#define DEV __device__ __forceinline__

static constexpr int S_LEN  = 2048;
static constexpr int IN_DIM = 1024;
static constexpr int P_DIM  = 512;
static constexpr int NHEAD  = 8;
static constexpr int HD     = 64;
static constexpr int KN     = 128;

typedef __attribute__((ext_vector_type(8))) short bf16x8;
typedef __attribute__((ext_vector_type(4))) float f32x4;

DEV float gelu_exact(float x) {
    return 0.5f * x * (1.0f + erff(x * 0.70710678118654752440f));
}

// float -> bf16 (RNE), and the split residual helpers
DEV short bf_hi(float x) {
    unsigned u = __float_as_uint(x);
    unsigned r = (u + 0x7fffu + ((u >> 16) & 1u)) >> 16;
    return (short)r;
}
DEV float bf_f(short h) { return __uint_as_float(((unsigned)(unsigned short)h) << 16); }

// 256-thread block sum reduction. sm4 must be float[4] shared.
DEV float block_reduce_sum(float v, float* sm4) {
    #pragma unroll
    for (int off = 32; off; off >>= 1) v += __shfl_down(v, off, 64);
    int lane = threadIdx.x & 63, w = threadIdx.x >> 6;
    __syncthreads();
    if (lane == 0) sm4[w] = v;
    __syncthreads();
    return sm4[0] + sm4[1] + sm4[2] + sm4[3];
}

// ---------------- K1: centroids, L2-normalized, split-bf16 [p][d] -----------
__global__ __launch_bounds__(256) void k_cent(const float* __restrict__ penta,
                                              short* __restrict__ ch,
                                              short* __restrict__ cl) {
    int p = blockIdx.x, t = threadIdx.x;
    __shared__ float sm4[4];
    float c0 = 0.f, c1 = 0.f;
    #pragma unroll
    for (int v = 0; v < 5; v++) {
        const float* row = penta + ((long)p * 5 + v) * P_DIM;
        c0 += row[t];
        c1 += row[t + 256];
    }
    c0 /= 5.0f; c1 /= 5.0f;
    float tot = block_reduce_sum(c0 * c0 + c1 * c1, sm4);
    float n = fmaxf(sqrtf(tot), 1e-12f);
    float v0 = c0 / n, v1 = c1 / n;
    short h0 = bf_hi(v0), h1 = bf_hi(v1);
    ch[p * P_DIM + t]       = h0;
    ch[p * P_DIM + t + 256] = h1;
    cl[p * P_DIM + t]       = bf_hi(v0 - bf_f(h0));
    cl[p * P_DIM + t + 256] = bf_hi(v1 - bf_f(h1));
}

// ---------------- weight transpose + split: W (K x N) -> WT_hi/lo (N x K) ---
template <int K, int N>
__global__ __launch_bounds__(256) void k_wt(const float* __restrict__ W,
                                            short* __restrict__ WTh,
                                            short* __restrict__ WTl) {
    __shared__ float tile[64][65];
    int bk = blockIdx.x, bn = blockIdx.y;
    int t = threadIdx.x;
    int c = t & 63, r4 = t >> 6;
    #pragma unroll
    for (int i = 0; i < 16; i++) {
        int row = r4 + i * 4;
        tile[row][c] = W[(long)(bk * 64 + row) * N + bn * 64 + c];
    }
    __syncthreads();
    #pragma unroll
    for (int i = 0; i < 16; i++) {
        int n = r4 + i * 4;
        float v = tile[c][n];
        short h = bf_hi(v);
        long o = (long)(bn * 64 + n) * K + bk * 64 + c;
        WTh[o] = h;
        WTl[o] = bf_hi(v - bf_f(h));
    }
}

// ---------------- MFMA split-bf16 GEMM: C = A@W + bias ----------------------
template <int K, int N, int EPI>
__global__ __launch_bounds__(256) void k_mm(const float* __restrict__ A,
                                            const short* __restrict__ BTh,
                                            const short* __restrict__ BTl,
                                            const float* __restrict__ bias,
                                            float* __restrict__ C,
                                            unsigned long long* __restrict__ rowkey) {
    __shared__ short Ah[128 * 40], Al[128 * 40], Bh[128 * 40], Bl[128 * 40];
    int t = threadIdx.x;
    int lane = t & 63, wave = t >> 6;
    int wr = (wave >> 1) * 64, wc = (wave & 1) * 64;
    int m = lane & 15, quad = lane >> 4;
    int rb = blockIdx.x * 128, cb = blockIdx.y * 128;

    f32x4 acc[4][4];
    #pragma unroll
    for (int i = 0; i < 4; i++)
        #pragma unroll
        for (int j = 0; j < 4; j++) acc[i][j] = (f32x4){0.f, 0.f, 0.f, 0.f};

    for (int k0 = 0; k0 < K; k0 += 32) {
        __syncthreads();
        #pragma unroll
        for (int ps = 0; ps < 4; ps++) {
            int row = (t >> 3) + ps * 32;
            int seg = t & 7;
            float4 v = *(const float4*)(A + (long)(rb + row) * K + k0 + seg * 4);
            short h0 = bf_hi(v.x), h1 = bf_hi(v.y), h2 = bf_hi(v.z), h3 = bf_hi(v.w);
            short l0 = bf_hi(v.x - bf_f(h0)), l1 = bf_hi(v.y - bf_f(h1));
            short l2 = bf_hi(v.z - bf_f(h2)), l3 = bf_hi(v.w - bf_f(h3));
            *(short4*)(Ah + row * 40 + seg * 4) = make_short4(h0, h1, h2, h3);
            *(short4*)(Al + row * 40 + seg * 4) = make_short4(l0, l1, l2, l3);
        }
        #pragma unroll
        for (int ps = 0; ps < 2; ps++) {
            int row = (t >> 2) + ps * 64;
            int seg = t & 3;
            *(float4*)(Bh + row * 40 + seg * 8) =
                *(const float4*)(BTh + (long)(cb + row) * K + k0 + seg * 8);
            *(float4*)(Bl + row * 40 + seg * 8) =
                *(const float4*)(BTl + (long)(cb + row) * K + k0 + seg * 8);
        }
        __syncthreads();

        bf16x8 ah[4], al[4], bh[4], bl[4];
        #pragma unroll
        for (int i = 0; i < 4; i++) {
            ah[i] = *(const bf16x8*)(Ah + (wr + i * 16 + m) * 40 + quad * 8);
            al[i] = *(const bf16x8*)(Al + (wr + i * 16 + m) * 40 + quad * 8);
            bh[i] = *(const bf16x8*)(Bh + (wc + i * 16 + m) * 40 + quad * 8);
            bl[i] = *(const bf16x8*)(Bl + (wc + i * 16 + m) * 40 + quad * 8);
        }
        #pragma unroll
        for (int i = 0; i < 4; i++)
            #pragma unroll
            for (int j = 0; j < 4; j++) {
                acc[i][j] = __builtin_amdgcn_mfma_f32_16x16x32_bf16(ah[i], bh[j], acc[i][j], 0, 0, 0);
                acc[i][j] = __builtin_amdgcn_mfma_f32_16x16x32_bf16(ah[i], bl[j], acc[i][j], 0, 0, 0);
                acc[i][j] = __builtin_amdgcn_mfma_f32_16x16x32_bf16(al[i], bh[j], acc[i][j], 0, 0, 0);
            }
    }

    if (EPI == 0) {
        #pragma unroll
        for (int i = 0; i < 4; i++) {
            int gr0 = rb + wr + i * 16 + quad * 4;
            #pragma unroll
            for (int j = 0; j < 4; j++) {
                int gc = cb + wc + j * 16 + m;
                float bv = bias[gc];
                #pragma unroll
                for (int r = 0; r < 4; r++)
                    C[(long)(gr0 + r) * N + gc] = acc[i][j][r] + bv;
            }
        }
    } else {
        #pragma unroll
        for (int i = 0; i < 4; i++) {
            #pragma unroll
            for (int r = 0; r < 4; r++) {
                int gr = rb + wr + i * 16 + quad * 4 + r;
                float bv = acc[i][0][r];
                int bp = cb + wc + m;
                #pragma unroll
                for (int j = 1; j < 4; j++) {
                    float v = acc[i][j][r];
                    int p = cb + wc + j * 16 + m;   // ascending; > keeps lowest p
                    if (v > bv) { bv = v; bp = p; }
                }
                #pragma unroll
                for (int off = 1; off < 16; off <<= 1) {
                    float ov = __shfl_xor(bv, off, 64);
                    int op = __shfl_xor(bp, off, 64);
                    if (ov > bv || (ov == bv && op < bp)) { bv = ov; bp = op; }
                }
                if (m == 0) {
                    unsigned u = __float_as_uint(bv);
                    u = (u & 0x80000000u) ? ~u : (u | 0x80000000u);
                    unsigned long long key =
                        ((unsigned long long)u << 32) | (unsigned)(0xFFFFFFFFu - (unsigned)bp);
                    atomicMax(&rowkey[gr], key);
                }
            }
        }
    }
}

// ---------------- rowkey -> cantor position ---------------------------------
__global__ __launch_bounds__(256) void k_pos(const unsigned long long* __restrict__ rowkey,
                                             const float* __restrict__ spos,
                                             float* __restrict__ pos) {
    int i = blockIdx.x * 256 + threadIdx.x;
    unsigned p = 0xFFFFFFFFu - (unsigned)(rowkey[i] & 0xFFFFFFFFull);
    pos[i] = spos[p];
}

// ---------------- K3: per-row LayerNorm -> gelu -> L2 normalize -------------
__global__ __launch_bounds__(256) void k_ln_gelu_norm(const float* __restrict__ Zin,
                                                      const float* __restrict__ g,
                                                      const float* __restrict__ b,
                                                      float* __restrict__ Z) {
    long row = blockIdx.x;
    int t = threadIdx.x;
    __shared__ float sm4[4];
    float x0 = Zin[row * P_DIM + t], x1 = Zin[row * P_DIM + t + 256];
    float mu = block_reduce_sum(x0 + x1, sm4) * (1.0f / P_DIM);
    float d0 = x0 - mu, d1 = x1 - mu;
    float var = block_reduce_sum(d0 * d0 + d1 * d1, sm4) * (1.0f / P_DIM);
    float rs = 1.0f / sqrtf(var + 1e-5f);
    float y0 = gelu_exact(d0 * rs * g[t] + b[t]);
    float y1 = gelu_exact(d1 * rs * g[t + 256] + b[t + 256]);
    float nn = block_reduce_sum(y0 * y0 + y1 * y1, sm4);
    float n = fmaxf(sqrtf(nn), 1e-12f);
    Z[row * P_DIM + t]       = y0 / n;
    Z[row * P_DIM + t + 256] = y1 / n;
}

// ---------------- K5: per-batch bitonic argsort of positions ----------------
__global__ __launch_bounds__(256) void k_sort(const float* __restrict__ pos,
                                              int* __restrict__ order,
                                              float* __restrict__ pos_srt) {
    int b = blockIdx.x, t = threadIdx.x;
    __shared__ unsigned long long key[2048];
    for (int u = 0; u < 8; u++) {
        int i = t + u * 256;
        key[i] = (((unsigned long long)__float_as_uint(pos[b * 2048 + i])) << 32)
                 | (unsigned)i;
    }
    __syncthreads();
    for (int k = 2; k <= 2048; k <<= 1) {
        for (int j = k >> 1; j > 0; j >>= 1) {
            for (int u = 0; u < 8; u++) {
                int i = t + u * 256;
                int l = i ^ j;
                if (l > i) {
                    bool up = ((i & k) == 0);
                    unsigned long long a = key[i], c = key[l];
                    if ((a > c) == up) { key[i] = c; key[l] = a; }
                }
            }
            __syncthreads();
        }
    }
    for (int u = 0; u < 8; u++) {
        int r = t + u * 256;
        unsigned long long kk = key[r];
        order[b * 2048 + r]   = (int)(kk & 0xffffffffu);
        pos_srt[b * 2048 + r] = __uint_as_float((unsigned)(kk >> 32));
    }
}

// ---------------- K6: exact top-128 via rank-window + tie resolution --------
__global__ __launch_bounds__(256) void k_routes(const float* __restrict__ pos_srt,
                                                const int* __restrict__ order,
                                                unsigned long long* __restrict__ bmG,
                                                uint2* __restrict__ bounds) {
    int blk = blockIdx.x;                 // 16 blocks
    int b = blk >> 3;
    int r = (blk & 7) * 256 + threadIdx.x;
    int t = threadIdx.x;
    __shared__ float ps[2048];
    __shared__ unsigned short tk[2048];
    for (int u = 0; u < 8; u++) {
        int i = t + u * 256;
        ps[i] = pos_srt[b * 2048 + i];
        tk[i] = (unsigned short)order[b * 2048 + i];
    }
    __syncthreads();

    float pi = ps[r];
    // phase 1: two-pointer expansion, 128 picks (self first)
    int wl = r, wr = r;
    float T = 0.0f;
    for (int n = 1; n < 128; n++) {
        float dl = (wl > 0)    ? (pi - ps[wl - 1]) : 3e38f;
        float dr = (wr < 2047) ? (ps[wr + 1] - pi) : 3e38f;
        if (dl <= dr) { wl--; T = fmaxf(T, dl); }
        else          { wr++; T = fmaxf(T, dr); }
    }

    // phase 2: tie runs with d == T (maximal contiguous, <=2 of them)
    int e1 = 2048, e2 = -1, e3 = 2048, e4 = -1;
    {
        int a = -1;
        if (fabsf(pi - ps[wl]) == T) a = wl;
        else if (wl > 0 && fabsf(pi - ps[wl - 1]) == T) a = wl - 1;
        if (a >= 0) {
            e1 = a; while (e1 > 0 && fabsf(pi - ps[e1 - 1]) == T) e1--;
            e2 = a; while (e2 < 2047 && fabsf(pi - ps[e2 + 1]) == T) e2++;
        }
        if (wr > e2) {
            int a2 = -1;
            if (fabsf(pi - ps[wr]) == T) a2 = wr;
            else if (wr < 2047 && fabsf(pi - ps[wr + 1]) == T) a2 = wr + 1;
            if (a2 >= 0) {
                e3 = a2; while (e3 - 1 > e2 && fabsf(pi - ps[e3 - 1]) == T) e3--;
                e4 = a2; while (e4 < 2047 && fabsf(pi - ps[e4 + 1]) == T) e4++;
            }
        }
    }
    int need = 0;
    if (e2 >= e1) need += max(0, min(wr, e2) - max(wl, e1) + 1);
    if (e4 >= e3) need += max(0, min(wr, e4) - max(wl, e3) + 1);
    int tiecount = (e2 >= e1 ? e2 - e1 + 1 : 0) + (e4 >= e3 ? e4 - e3 + 1 : 0);

    int X = 65535;
    if (need < tiecount) {
        int lo2 = 0, hi2 = 2047;
        while (lo2 < hi2) {
            int mid = (lo2 + hi2) >> 1;
            int cnt = 0;
            for (int j = e1; j <= e2; j++) cnt += (tk[j] <= mid) ? 1 : 0;
            for (int j = e3; j <= e4; j++) cnt += (tk[j] <= mid) ? 1 : 0;
            if (cnt >= need) hi2 = mid; else lo2 = mid + 1;
        }
        X = lo2;
    }

    int mn = wl, mx = wr;
    if (e2 >= e1) { mn = min(mn, e1); mx = max(mx, e2); }
    if (e4 >= e3) mx = max(mx, e4);
    int qlo = 2048, qhi = -1;
    unsigned long long* bmq = bmG + ((long)(b * 2048 + r)) * 32;
    for (int w = 0; w < 32; w++) {
        unsigned long long bits = 0;
        int lo_r = w << 6, hi_r = lo_r + 63;
        if (hi_r >= mn && lo_r <= mx) {
            int j0 = max(lo_r, mn), j1 = min(hi_r, mx);
            for (int j = j0; j <= j1; j++) {
                float dj = fabsf(pi - ps[j]);
                bool mem;
                if (dj < T) mem = (j >= wl && j <= wr);
                else        mem = (dj == T) && (tk[j] <= X);
                if (mem) {
                    bits |= 1ull << (j - lo_r);
                    qlo = min(qlo, j); qhi = max(qhi, j);
                }
            }
        }
        bmq[w] = bits;
    }
    bounds[b * 2048 + r] = make_uint2((unsigned)qlo, (unsigned)qhi);
}

// ---------------- K7: flash attention, head-split for occupancy -------------
// Grid 1024: gb = b*512 + qg*4 + hp. Block = 16 rank-adjacent queries x 2
// heads (h0 = hp*2). Thread = (q:16, hl:2, seg:8 x 8dims). Register-prefetch
// software pipeline on the K/V staging. LDS head slice padded to 68 floats
// -> 2-head layout lands on disjoint bank groups (2-way max aliasing, free).
__global__ __launch_bounds__(256) void k_attn(const float* __restrict__ qkv,
                                              const int* __restrict__ order,
                                              const unsigned long long* __restrict__ bmG,
                                              const uint2* __restrict__ bounds,
                                              float* __restrict__ attn_out) {
    constexpr int HS = 68;           // padded head-slice stride (floats)
    constexpr int RS = 2 * HS;       // 136 floats per staged row (2 heads)
    int gb = blockIdx.x;             // 1024 blocks
    int b  = gb >> 9;
    int qg = (gb >> 2) & 127;
    int hp = gb & 3;
    int h0 = hp * 2;
    int r0 = qg * 16;
    int t = threadIdx.x;
    int q   = t >> 4;                // 0..15
    int hl  = (t >> 3) & 1;          // 0..1
    int seg = t & 7;                 // 0..7 (8 dims each)

    __shared__ float Kch[8 * RS];
    __shared__ float Vch[8 * RS];
    __shared__ unsigned long long bm[16][32];
    __shared__ int sh_tok[16];
    __shared__ int sh_lo, sh_hi;

    if (t < 16) sh_tok[t] = order[b * 2048 + r0 + t];
    if (t == 0) { sh_lo = 1 << 30; sh_hi = 0; }
    {
        const unsigned long long* src = bmG + ((long)(b * 2048 + r0)) * 32;
        ((unsigned long long*)bm)[t]       = src[t];
        ((unsigned long long*)bm)[t + 256] = src[t + 256];
    }
    __syncthreads();
    if (t < 16) {
        uint2 bd = bounds[b * 2048 + r0 + t];
        atomicMin(&sh_lo, (int)bd.x);
        atomicMax(&sh_hi, (int)bd.y);
    }

    // staging decode (constant per thread): idx = t + u*256 in [0,512)
    int rr_u[2], f4_u[2], dst_u[2], kv_u[2];
    #pragma unroll
    for (int u = 0; u < 2; u++) {
        int idx = t + u * 256;
        rr_u[u] = idx >> 6;
        int c6 = idx & 63;
        kv_u[u] = c6 >> 5;
        int hh = (c6 >> 4) & 1, w = c6 & 15;
        f4_u[u]  = (kv_u[u] ? 256 : 128) + (h0 + hh) * 16 + w;   // float4 idx in row
        dst_u[u] = (rr_u[u] * RS + hh * HS) / 4 + w;             // float4 idx in LDS
    }

    // q fragment (8 dims) in registers
    float qreg[8];
    {
        const float* qp = qkv + ((long)(b * 2048 + sh_tok[q])) * 1536
                          + (h0 + hl) * HD + seg * 8;
        float4 v0 = ((const float4*)qp)[0], v1 = ((const float4*)qp)[1];
        qreg[0]=v0.x; qreg[1]=v0.y; qreg[2]=v0.z; qreg[3]=v0.w;
        qreg[4]=v1.x; qreg[5]=v1.y; qreg[6]=v1.z; qreg[7]=v1.w;
    }
    float O[8];
    #pragma unroll
    for (int i = 0; i < 8; i++) O[i] = 0.f;
    float m = -1e30f, l = 0.f;
    __syncthreads();
    int lo = sh_lo & ~7, hi = sh_hi + 1;

    // prefetch first chunk into regs
    float4 pre[2];
    #pragma unroll
    for (int u = 0; u < 2; u++) {
        int row = min(lo + rr_u[u], 2047);
        int tok = order[b * 2048 + row];
        pre[u] = ((const float4*)(qkv + (long)(b * 2048 + tok) * 1536))[f4_u[u]];
    }

    for (int c0 = lo; c0 < hi; c0 += 8) {
        __syncthreads();   // previous chunk fully consumed
        #pragma unroll
        for (int u = 0; u < 2; u++)
            ((float4*)(kv_u[u] ? Vch : Kch))[dst_u[u]] = pre[u];
        // issue next chunk's loads (latency hidden behind compute below)
        int cn = c0 + 8;
        if (cn < hi) {
            #pragma unroll
            for (int u = 0; u < 2; u++) {
                int row = min(cn + rr_u[u], 2047);
                int tok = order[b * 2048 + row];
                pre[u] = ((const float4*)(qkv + (long)(b * 2048 + tok) * 1536))[f4_u[u]];
            }
        }
        __syncthreads();

        float s[8];
        #pragma unroll
        for (int rr = 0; rr < 8; rr++) {
            int rank = c0 + rr;
            bool mem = (rank < 2048) && ((bm[q][rank >> 6] >> (rank & 63)) & 1);
            float sv = -3e38f;
            if (mem) {  // uniform across the 8 seg lanes of this (q,hl)
                const float* kp = Kch + rr * RS + hl * HS + seg * 8;
                float part = 0.f;
                #pragma unroll
                for (int i2 = 0; i2 < 8; i2++) part = fmaf(qreg[i2], kp[i2], part);
                part += __shfl_xor(part, 1, 64);
                part += __shfl_xor(part, 2, 64);
                part += __shfl_xor(part, 4, 64);
                sv = part * 0.125f;
            }
            s[rr] = sv;
        }
        // online softmax update
        float mx = s[0];
        #pragma unroll
        for (int rr = 1; rr < 8; rr++) mx = fmaxf(mx, s[rr]);
        float mnew = fmaxf(m, mx);
        float alpha = __expf(m - mnew);
        float p[8], psum = 0.f;
        #pragma unroll
        for (int rr = 0; rr < 8; rr++) { p[rr] = __expf(s[rr] - mnew); psum += p[rr]; }
        l = l * alpha + psum;
        m = mnew;
        #pragma unroll
        for (int i2 = 0; i2 < 8; i2++) O[i2] *= alpha;
        #pragma unroll
        for (int rr = 0; rr < 8; rr++) {
            const float* vp = Vch + rr * RS + hl * HS + seg * 8;
            float pv = p[rr];
            #pragma unroll
            for (int i2 = 0; i2 < 8; i2++) O[i2] = fmaf(pv, vp[i2], O[i2]);
        }
    }

    float inv = 1.0f / l;
    float* op = attn_out + ((long)(b * 2048 + sh_tok[q])) * P_DIM
                + (h0 + hl) * HD + seg * 8;
    float4 v0, v1;
    v0.x = O[0]*inv; v0.y = O[1]*inv; v0.z = O[2]*inv; v0.w = O[3]*inv;
    v1.x = O[4]*inv; v1.y = O[5]*inv; v1.z = O[6]*inv; v1.w = O[7]*inv;
    ((float4*)op)[0] = v0;
    ((float4*)op)[1] = v1;
}

// ---------------- K9: pooled partial sums (atomic) --------------------------
__global__ __launch_bounds__(256) void k_pool(const float* __restrict__ zatt,
                                              float* __restrict__ pooled) {
    int b = blockIdx.y, chunk = blockIdx.x, t = threadIdx.x;
    float a0 = 0.f, a1 = 0.f;
    for (int s = 0; s < 128; s++) {
        long row = ((long)b * S_LEN + chunk * 128 + s) * P_DIM;
        a0 += zatt[row + t];
        a1 += zatt[row + t + 256];
    }
    atomicAdd(&pooled[b * P_DIM + t], a0);
    atomicAdd(&pooled[b * P_DIM + t + 256], a1);
}

// ---------------- Expert stage 1: h = pooled/S @ w1 + b1 (all 3 experts) ----
__global__ __launch_bounds__(256) void k_exp_fc1(const float* __restrict__ pooled,
                                                 const float* __restrict__ w1_0, const float* __restrict__ b1_0,
                                                 const float* __restrict__ w1_1, const float* __restrict__ b1_1,
                                                 const float* __restrict__ w1_2, const float* __restrict__ b1_2,
                                                 float* __restrict__ h) {
    int t = threadIdx.x, b = blockIdx.y;
    int c = blockIdx.x * 256 + t;  // [0, 1792)
    __shared__ float pl[P_DIM];
    pl[t]       = pooled[b * P_DIM + t]       * (1.0f / S_LEN);
    pl[t + 256] = pooled[b * P_DIM + t + 256] * (1.0f / S_LEN);
    __syncthreads();

    const float* wp; const float* bp; int s2, j;
    if (c < 256)      { wp = w1_0; bp = b1_0; s2 = 256;  j = c; }
    else if (c < 768) { wp = w1_1; bp = b1_1; s2 = 512;  j = c - 256; }
    else              { wp = w1_2; bp = b1_2; s2 = 1024; j = c - 768; }

    const float* p = wp + j;
    float acc = 0.f;
    #pragma unroll 16
    for (int k = 0; k < P_DIM; k++) {
        acc = fmaf(pl[k], *p, acc);
        p += s2;
    }
    h[(long)b * 1792 + c] = acc + bp[j];
}

// ---------------- Expert stage 2: LN + gelu per (expert, batch) -------------
__global__ __launch_bounds__(256) void k_exp_ln(float* __restrict__ h,
                                                const float* __restrict__ g0, const float* __restrict__ bb0,
                                                const float* __restrict__ g1, const float* __restrict__ bb1,
                                                const float* __restrict__ g2, const float* __restrict__ bb2) {
    int e = blockIdx.x, b = blockIdx.y, t = threadIdx.x;
    __shared__ float sm4[4];
    const int offs[3] = {0, 256, 768};
    const int ns[3]   = {256, 512, 1024};
    const float* gs[3]  = {g0, g1, g2};
    const float* bbs[3] = {bb0, bb1, bb2};
    int n = ns[e];
    float* hp = h + (long)b * 1792 + offs[e];
    const float* g = gs[e]; const float* bb = bbs[e];

    float x[4];
    float loc = 0.f;
    for (int u = 0; u < 4; u++) {
        int j = t + u * 256;
        x[u] = (j < n) ? hp[j] : 0.f;
        loc += x[u];
    }
    float mu = block_reduce_sum(loc, sm4) / (float)n;
    loc = 0.f;
    for (int u = 0; u < 4; u++) {
        int j = t + u * 256;
        if (j < n) { float d = x[u] - mu; loc += d * d; }
    }
    float var = block_reduce_sum(loc, sm4) / (float)n;
    float rs = 1.0f / sqrtf(var + 1e-5f);
    for (int u = 0; u < 4; u++) {
        int j = t + u * 256;
        if (j < n) hp[j] = gelu_exact((x[u] - mu) * rs * g[j] + bb[j]);
    }
}

// ---------------- Expert stage 3: out = h @ w2 + b2 (all 3 experts) ---------
__global__ __launch_bounds__(256) void k_exp_fc2(const float* __restrict__ h,
                                                 const float* __restrict__ w2_0, const float* __restrict__ b2_0,
                                                 const float* __restrict__ w2_1, const float* __restrict__ b2_1,
                                                 const float* __restrict__ w2_2, const float* __restrict__ b2_2,
                                                 float* __restrict__ out) {
    int t = threadIdx.x, b = blockIdx.y;
    int c = blockIdx.x * 256 + t;  // [0, 1024), valid < 896
    __shared__ float hs[1792];
    for (int u = 0; u < 7; u++) hs[t + u * 256] = h[(long)b * 1792 + t + u * 256];
    __syncthreads();
    if (c >= 896) return;

    const float* wp; const float* bp; int s2, sN, j, off_h;
    if (c < 128)      { wp = w2_0; bp = b2_0; s2 = 256;  sN = 128; j = c;       off_h = 0; }
    else if (c < 384) { wp = w2_1; bp = b2_1; s2 = 512;  sN = 256; j = c - 128; off_h = 256; }
    else              { wp = w2_2; bp = b2_2; s2 = 1024; sN = 512; j = c - 384; off_h = 768; }

    const float* p = wp + j;
    const float* hh = hs + off_h;
    float acc = 0.f;
    #pragma unroll 16
    for (int k = 0; k < s2; k++) {
        acc = fmaf(hh[k], *p, acc);
        p += sN;
    }
    out[b * 896 + c] = acc + bp[j];
}

// ---------------------------------------------------------------------------
extern "C" void kernel_launch(void* const* d_in, const int* in_sizes, int n_in,
                              void* d_out, int out_size, void* d_ws, size_t ws_size,
                              hipStream_t stream) {
    const float* seq   = (const float*)d_in[0];
    const float* penta = (const float*)d_in[1];
    const float* spos  = (const float*)d_in[2];
    const float* projW = (const float*)d_in[3];
    const float* projb = (const float*)d_in[4];
    const float* lng   = (const float*)d_in[5];
    const float* lnb   = (const float*)d_in[6];
    const float* qkvW  = (const float*)d_in[7];
    const float* qkvb  = (const float*)d_in[8];
    const float* outW  = (const float*)d_in[9];
    const float* outb  = (const float*)d_in[10];

    float* ws      = (float*)d_ws;
    float* z_pre   = ws;                      // 2097152 (zatt alias)
    float* z       = z_pre + 2097152;         // 2097152 (attn alias)
    float* qkv     = z + 2097152;             // 6291456
    float* pos     = qkv + 6291456;           // 4096
    float* pooled  = pos + 4096;              // 1024
    float* hbuf    = pooled + 1024;           // 4096
    unsigned long long* rowkey = (unsigned long long*)(hbuf + 4096);  // 4096 ull
    float* pos_srt = (float*)(rowkey + 4096); // 4096
    int*   order   = (int*)(pos_srt + 4096);  // 4096
    uint2* bounds  = (uint2*)(order + 4096);  // 4096 uint2
    unsigned long long* bmG = (unsigned long long*)(bounds + 4096); // 131072 ull
    short* cent_h  = (short*)(bmG + 131072);  // 524288 shorts
    short* cent_l  = cent_h + 524288;
    short* pjWT_h  = cent_l + 524288;         // 512x1024
    short* pjWT_l  = pjWT_h + 524288;
    short* qkWT_h  = pjWT_l + 524288;         // 1536x512
    short* qkWT_l  = qkWT_h + 786432;
    short* owWT_h  = qkWT_l + 786432;         // 512x512
    short* owWT_l  = owWT_h + 262144;
    float* attn    = z;       // z dead after qkv GEMM
    float* zatt    = z_pre;   // z_pre dead after ln_gelu

    // weight prep
    k_cent<<<1024, 256, 0, stream>>>(penta, cent_h, cent_l);
    { dim3 g(16, 8);  k_wt<IN_DIM, P_DIM><<<g, 256, 0, stream>>>(projW, pjWT_h, pjWT_l); }
    { dim3 g(8, 24);  k_wt<P_DIM, 3 * P_DIM><<<g, 256, 0, stream>>>(qkvW, qkWT_h, qkWT_l); }
    { dim3 g(8, 8);   k_wt<P_DIM, P_DIM><<<g, 256, 0, stream>>>(outW, owWT_h, owWT_l); }

    // proj -> ln/gelu/norm
    { dim3 g(32, 4);  k_mm<IN_DIM, P_DIM, 0><<<g, 256, 0, stream>>>(seq, pjWT_h, pjWT_l, projb, z_pre, nullptr); }
    k_ln_gelu_norm<<<4096, 256, 0, stream>>>(z_pre, lng, lnb, z);

    // anchor argmax -> positions -> sort
    hipMemsetAsync(rowkey, 0, 4096 * sizeof(unsigned long long), stream);
    { dim3 g(32, 8);  k_mm<P_DIM, 1024, 1><<<g, 256, 0, stream>>>(z, cent_h, cent_l, nullptr, nullptr, rowkey); }
    k_pos<<<16, 256, 0, stream>>>(rowkey, spos, pos);
    k_sort<<<2, 256, 0, stream>>>(pos, order, pos_srt);

    // qkv -> routes(bitmap) -> attention -> out-proj
    { dim3 g(32, 12); k_mm<P_DIM, 3 * P_DIM, 0><<<g, 256, 0, stream>>>(z, qkWT_h, qkWT_l, qkvb, qkv, nullptr); }
    k_routes<<<16, 256, 0, stream>>>(pos_srt, order, bmG, bounds);
    k_attn<<<1024, 256, 0, stream>>>(qkv, order, bmG, bounds, attn);
    { dim3 g(32, 4);  k_mm<P_DIM, P_DIM, 0><<<g, 256, 0, stream>>>(attn, owWT_h, owWT_l, outb, zatt, nullptr); }

    // pool + experts
    hipMemsetAsync(pooled, 0, 1024 * sizeof(float), stream);
    { dim3 pg(16, 2); k_pool<<<pg, 256, 0, stream>>>(zatt, pooled); }

    dim3 g1(7, 2);
    k_exp_fc1<<<g1, 256, 0, stream>>>(pooled,
        (const float*)d_in[11], (const float*)d_in[12],
        (const float*)d_in[17], (const float*)d_in[18],
        (const float*)d_in[23], (const float*)d_in[24], hbuf);
    dim3 g2(3, 2);
    k_exp_ln<<<g2, 256, 0, stream>>>(hbuf,
        (const float*)d_in[13], (const float*)d_in[14],
        (const float*)d_in[19], (const float*)d_in[20],
        (const float*)d_in[25], (const float*)d_in[26]);
    dim3 g3(4, 2);
    k_exp_fc2<<<g3, 256, 0, stream>>>(hbuf,
        (const float*)d_in[15], (const float*)d_in[16],
        (const float*)d_in[21], (const float*)d_in[22],
        (const float*)d_in[27], (const float*)d_in[28], (float*)d_out);
}

// Round 8
// 539.135 us; speedup vs baseline: 2.7220x; 1.0487x over previous
//
#include <hip/hip_runtime.h>
#include <math.h>

#define DEV __device__ __forceinline__

static constexpr int S_LEN  = 2048;
static constexpr int IN_DIM = 1024;
static constexpr int P_DIM  = 512;
static constexpr int NHEAD  = 8;
static constexpr int HD     = 64;
static constexpr int KN     = 128;

typedef __attribute__((ext_vector_type(8))) short bf16x8;
typedef __attribute__((ext_vector_type(4))) float f32x4;

DEV float gelu_exact(float x) {
    return 0.5f * x * (1.0f + erff(x * 0.70710678118654752440f));
}

// float -> bf16 (RNE), and the split residual helpers
DEV short bf_hi(float x) {
    unsigned u = __float_as_uint(x);
    unsigned r = (u + 0x7fffu + ((u >> 16) & 1u)) >> 16;
    return (short)r;
}
DEV float bf_f(short h) { return __uint_as_float(((unsigned)(unsigned short)h) << 16); }

// 256-thread block sum reduction. sm4 must be float[4] shared.
DEV float block_reduce_sum(float v, float* sm4) {
    #pragma unroll
    for (int off = 32; off; off >>= 1) v += __shfl_down(v, off, 64);
    int lane = threadIdx.x & 63, w = threadIdx.x >> 6;
    __syncthreads();
    if (lane == 0) sm4[w] = v;
    __syncthreads();
    return sm4[0] + sm4[1] + sm4[2] + sm4[3];
}

// ---------------- K1: centroids, L2-normalized, split-bf16 [p][d] -----------
__global__ __launch_bounds__(256) void k_cent(const float* __restrict__ penta,
                                              short* __restrict__ ch,
                                              short* __restrict__ cl) {
    int p = blockIdx.x, t = threadIdx.x;
    __shared__ float sm4[4];
    float c0 = 0.f, c1 = 0.f;
    #pragma unroll
    for (int v = 0; v < 5; v++) {
        const float* row = penta + ((long)p * 5 + v) * P_DIM;
        c0 += row[t];
        c1 += row[t + 256];
    }
    c0 /= 5.0f; c1 /= 5.0f;
    float tot = block_reduce_sum(c0 * c0 + c1 * c1, sm4);
    float n = fmaxf(sqrtf(tot), 1e-12f);
    float v0 = c0 / n, v1 = c1 / n;
    short h0 = bf_hi(v0), h1 = bf_hi(v1);
    ch[p * P_DIM + t]       = h0;
    ch[p * P_DIM + t + 256] = h1;
    cl[p * P_DIM + t]       = bf_hi(v0 - bf_f(h0));
    cl[p * P_DIM + t + 256] = bf_hi(v1 - bf_f(h1));
}

// ---------------- weight transpose + split: W (K x N) -> WT_hi/lo (N x K) ---
template <int K, int N>
__global__ __launch_bounds__(256) void k_wt(const float* __restrict__ W,
                                            short* __restrict__ WTh,
                                            short* __restrict__ WTl) {
    __shared__ float tile[64][65];
    int bk = blockIdx.x, bn = blockIdx.y;
    int t = threadIdx.x;
    int c = t & 63, r4 = t >> 6;
    #pragma unroll
    for (int i = 0; i < 16; i++) {
        int row = r4 + i * 4;
        tile[row][c] = W[(long)(bk * 64 + row) * N + bn * 64 + c];
    }
    __syncthreads();
    #pragma unroll
    for (int i = 0; i < 16; i++) {
        int n = r4 + i * 4;
        float v = tile[c][n];
        short h = bf_hi(v);
        long o = (long)(bn * 64 + n) * K + bk * 64 + c;
        WTh[o] = h;
        WTl[o] = bf_hi(v - bf_f(h));
    }
}

// ---------------- MFMA split-bf16 GEMM: C = A@W + bias ----------------------
// SPLITA=false: A fp32 M x K, split on the fly.
// SPLITA=true:  A pre-split (Ash/Asl bf16 M x K) -> staging is a pure copy.
// EPI 0: C = acc + bias. EPI 1: per-row argmax -> atomicMax rowkey.
template <int K, int N, int EPI, bool SPLITA>
__global__ __launch_bounds__(256) void k_mm(const float* __restrict__ Af,
                                            const short* __restrict__ Ash,
                                            const short* __restrict__ Asl,
                                            const short* __restrict__ BTh,
                                            const short* __restrict__ BTl,
                                            const float* __restrict__ bias,
                                            float* __restrict__ C,
                                            unsigned long long* __restrict__ rowkey) {
    __shared__ short Ah[128 * 40], Al[128 * 40], Bh[128 * 40], Bl[128 * 40];
    int t = threadIdx.x;
    int lane = t & 63, wave = t >> 6;
    int wr = (wave >> 1) * 64, wc = (wave & 1) * 64;
    int m = lane & 15, quad = lane >> 4;
    int rb = blockIdx.x * 128, cb = blockIdx.y * 128;

    f32x4 acc[4][4];
    #pragma unroll
    for (int i = 0; i < 4; i++)
        #pragma unroll
        for (int j = 0; j < 4; j++) acc[i][j] = (f32x4){0.f, 0.f, 0.f, 0.f};

    for (int k0 = 0; k0 < K; k0 += 32) {
        __syncthreads();
        if constexpr (SPLITA) {
            #pragma unroll
            for (int ps = 0; ps < 2; ps++) {
                int idx = t + ps * 256;       // 0..511
                int row = idx >> 2, c4 = idx & 3;
                *(float4*)(Ah + row * 40 + c4 * 8) =
                    *(const float4*)(Ash + (long)(rb + row) * K + k0 + c4 * 8);
                *(float4*)(Al + row * 40 + c4 * 8) =
                    *(const float4*)(Asl + (long)(rb + row) * K + k0 + c4 * 8);
            }
        } else {
            #pragma unroll
            for (int ps = 0; ps < 4; ps++) {
                int row = (t >> 3) + ps * 32;
                int seg = t & 7;
                float4 v = *(const float4*)(Af + (long)(rb + row) * K + k0 + seg * 4);
                short h0 = bf_hi(v.x), h1 = bf_hi(v.y), h2 = bf_hi(v.z), h3 = bf_hi(v.w);
                short l0 = bf_hi(v.x - bf_f(h0)), l1 = bf_hi(v.y - bf_f(h1));
                short l2 = bf_hi(v.z - bf_f(h2)), l3 = bf_hi(v.w - bf_f(h3));
                *(short4*)(Ah + row * 40 + seg * 4) = make_short4(h0, h1, h2, h3);
                *(short4*)(Al + row * 40 + seg * 4) = make_short4(l0, l1, l2, l3);
            }
        }
        #pragma unroll
        for (int ps = 0; ps < 2; ps++) {
            int row = (t >> 2) + ps * 64;
            int seg = t & 3;
            *(float4*)(Bh + row * 40 + seg * 8) =
                *(const float4*)(BTh + (long)(cb + row) * K + k0 + seg * 8);
            *(float4*)(Bl + row * 40 + seg * 8) =
                *(const float4*)(BTl + (long)(cb + row) * K + k0 + seg * 8);
        }
        __syncthreads();

        bf16x8 ah[4], al[4], bh[4], bl[4];
        #pragma unroll
        for (int i = 0; i < 4; i++) {
            ah[i] = *(const bf16x8*)(Ah + (wr + i * 16 + m) * 40 + quad * 8);
            al[i] = *(const bf16x8*)(Al + (wr + i * 16 + m) * 40 + quad * 8);
            bh[i] = *(const bf16x8*)(Bh + (wc + i * 16 + m) * 40 + quad * 8);
            bl[i] = *(const bf16x8*)(Bl + (wc + i * 16 + m) * 40 + quad * 8);
        }
        #pragma unroll
        for (int i = 0; i < 4; i++)
            #pragma unroll
            for (int j = 0; j < 4; j++) {
                acc[i][j] = __builtin_amdgcn_mfma_f32_16x16x32_bf16(ah[i], bh[j], acc[i][j], 0, 0, 0);
                acc[i][j] = __builtin_amdgcn_mfma_f32_16x16x32_bf16(ah[i], bl[j], acc[i][j], 0, 0, 0);
                acc[i][j] = __builtin_amdgcn_mfma_f32_16x16x32_bf16(al[i], bh[j], acc[i][j], 0, 0, 0);
            }
    }

    if (EPI == 0) {
        #pragma unroll
        for (int i = 0; i < 4; i++) {
            int gr0 = rb + wr + i * 16 + quad * 4;
            #pragma unroll
            for (int j = 0; j < 4; j++) {
                int gc = cb + wc + j * 16 + m;
                float bv = bias[gc];
                #pragma unroll
                for (int r = 0; r < 4; r++)
                    C[(long)(gr0 + r) * N + gc] = acc[i][j][r] + bv;
            }
        }
    } else {
        #pragma unroll
        for (int i = 0; i < 4; i++) {
            #pragma unroll
            for (int r = 0; r < 4; r++) {
                int gr = rb + wr + i * 16 + quad * 4 + r;
                float bv = acc[i][0][r];
                int bp = cb + wc + m;
                #pragma unroll
                for (int j = 1; j < 4; j++) {
                    float v = acc[i][j][r];
                    int p = cb + wc + j * 16 + m;   // ascending; > keeps lowest p
                    if (v > bv) { bv = v; bp = p; }
                }
                #pragma unroll
                for (int off = 1; off < 16; off <<= 1) {
                    float ov = __shfl_xor(bv, off, 64);
                    int op = __shfl_xor(bp, off, 64);
                    if (ov > bv || (ov == bv && op < bp)) { bv = ov; bp = op; }
                }
                if (m == 0) {
                    unsigned u = __float_as_uint(bv);
                    u = (u & 0x80000000u) ? ~u : (u | 0x80000000u);
                    unsigned long long key =
                        ((unsigned long long)u << 32) | (unsigned)(0xFFFFFFFFu - (unsigned)bp);
                    atomicMax(&rowkey[gr], key);
                }
            }
        }
    }
}

// ---------------- rowkey -> cantor position ---------------------------------
__global__ __launch_bounds__(256) void k_pos(const unsigned long long* __restrict__ rowkey,
                                             const float* __restrict__ spos,
                                             float* __restrict__ pos) {
    int i = blockIdx.x * 256 + threadIdx.x;
    unsigned p = 0xFFFFFFFFu - (unsigned)(rowkey[i] & 0xFFFFFFFFull);
    pos[i] = spos[p];
}

// ---------------- K3: LayerNorm -> gelu -> L2 norm -> emit SPLIT bf16 -------
__global__ __launch_bounds__(256) void k_ln_gelu_norm(const float* __restrict__ Zin,
                                                      const float* __restrict__ g,
                                                      const float* __restrict__ b,
                                                      short* __restrict__ z_h,
                                                      short* __restrict__ z_l) {
    long row = blockIdx.x;
    int t = threadIdx.x;
    __shared__ float sm4[4];
    float x0 = Zin[row * P_DIM + t], x1 = Zin[row * P_DIM + t + 256];
    float mu = block_reduce_sum(x0 + x1, sm4) * (1.0f / P_DIM);
    float d0 = x0 - mu, d1 = x1 - mu;
    float var = block_reduce_sum(d0 * d0 + d1 * d1, sm4) * (1.0f / P_DIM);
    float rs = 1.0f / sqrtf(var + 1e-5f);
    float y0 = gelu_exact(d0 * rs * g[t] + b[t]);
    float y1 = gelu_exact(d1 * rs * g[t + 256] + b[t + 256]);
    float nn = block_reduce_sum(y0 * y0 + y1 * y1, sm4);
    float n = fmaxf(sqrtf(nn), 1e-12f);
    float v0 = y0 / n, v1 = y1 / n;
    short h0 = bf_hi(v0), h1 = bf_hi(v1);
    z_h[row * P_DIM + t]       = h0;
    z_h[row * P_DIM + t + 256] = h1;
    z_l[row * P_DIM + t]       = bf_hi(v0 - bf_f(h0));
    z_l[row * P_DIM + t + 256] = bf_hi(v1 - bf_f(h1));
}

// ---------------- K5: per-batch bitonic argsort of positions ----------------
__global__ __launch_bounds__(256) void k_sort(const float* __restrict__ pos,
                                              int* __restrict__ order,
                                              float* __restrict__ pos_srt) {
    int b = blockIdx.x, t = threadIdx.x;
    __shared__ unsigned long long key[2048];
    for (int u = 0; u < 8; u++) {
        int i = t + u * 256;
        key[i] = (((unsigned long long)__float_as_uint(pos[b * 2048 + i])) << 32)
                 | (unsigned)i;
    }
    __syncthreads();
    for (int k = 2; k <= 2048; k <<= 1) {
        for (int j = k >> 1; j > 0; j >>= 1) {
            for (int u = 0; u < 8; u++) {
                int i = t + u * 256;
                int l = i ^ j;
                if (l > i) {
                    bool up = ((i & k) == 0);
                    unsigned long long a = key[i], c = key[l];
                    if ((a > c) == up) { key[i] = c; key[l] = a; }
                }
            }
            __syncthreads();
        }
    }
    for (int u = 0; u < 8; u++) {
        int r = t + u * 256;
        unsigned long long kk = key[r];
        order[b * 2048 + r]   = (int)(kk & 0xffffffffu);
        pos_srt[b * 2048 + r] = __uint_as_float((unsigned)(kk >> 32));
    }
}

// ---------------- K6: exact top-128 via rank-window + tie resolution --------
__global__ __launch_bounds__(256) void k_routes(const float* __restrict__ pos_srt,
                                                const int* __restrict__ order,
                                                unsigned long long* __restrict__ bmG,
                                                uint2* __restrict__ bounds) {
    int blk = blockIdx.x;                 // 16 blocks
    int b = blk >> 3;
    int r = (blk & 7) * 256 + threadIdx.x;
    int t = threadIdx.x;
    __shared__ float ps[2048];
    __shared__ unsigned short tk[2048];
    for (int u = 0; u < 8; u++) {
        int i = t + u * 256;
        ps[i] = pos_srt[b * 2048 + i];
        tk[i] = (unsigned short)order[b * 2048 + i];
    }
    __syncthreads();

    float pi = ps[r];
    int wl = r, wr = r;
    float T = 0.0f;
    for (int n = 1; n < 128; n++) {
        float dl = (wl > 0)    ? (pi - ps[wl - 1]) : 3e38f;
        float dr = (wr < 2047) ? (ps[wr + 1] - pi) : 3e38f;
        if (dl <= dr) { wl--; T = fmaxf(T, dl); }
        else          { wr++; T = fmaxf(T, dr); }
    }

    int e1 = 2048, e2 = -1, e3 = 2048, e4 = -1;
    {
        int a = -1;
        if (fabsf(pi - ps[wl]) == T) a = wl;
        else if (wl > 0 && fabsf(pi - ps[wl - 1]) == T) a = wl - 1;
        if (a >= 0) {
            e1 = a; while (e1 > 0 && fabsf(pi - ps[e1 - 1]) == T) e1--;
            e2 = a; while (e2 < 2047 && fabsf(pi - ps[e2 + 1]) == T) e2++;
        }
        if (wr > e2) {
            int a2 = -1;
            if (fabsf(pi - ps[wr]) == T) a2 = wr;
            else if (wr < 2047 && fabsf(pi - ps[wr + 1]) == T) a2 = wr + 1;
            if (a2 >= 0) {
                e3 = a2; while (e3 - 1 > e2 && fabsf(pi - ps[e3 - 1]) == T) e3--;
                e4 = a2; while (e4 < 2047 && fabsf(pi - ps[e4 + 1]) == T) e4++;
            }
        }
    }
    int need = 0;
    if (e2 >= e1) need += max(0, min(wr, e2) - max(wl, e1) + 1);
    if (e4 >= e3) need += max(0, min(wr, e4) - max(wl, e3) + 1);
    int tiecount = (e2 >= e1 ? e2 - e1 + 1 : 0) + (e4 >= e3 ? e4 - e3 + 1 : 0);

    int X = 65535;
    if (need < tiecount) {
        int lo2 = 0, hi2 = 2047;
        while (lo2 < hi2) {
            int mid = (lo2 + hi2) >> 1;
            int cnt = 0;
            for (int j = e1; j <= e2; j++) cnt += (tk[j] <= mid) ? 1 : 0;
            for (int j = e3; j <= e4; j++) cnt += (tk[j] <= mid) ? 1 : 0;
            if (cnt >= need) hi2 = mid; else lo2 = mid + 1;
        }
        X = lo2;
    }

    int mn = wl, mx = wr;
    if (e2 >= e1) { mn = min(mn, e1); mx = max(mx, e2); }
    if (e4 >= e3) mx = max(mx, e4);
    int qlo = 2048, qhi = -1;
    unsigned long long* bmq = bmG + ((long)(b * 2048 + r)) * 32;
    for (int w = 0; w < 32; w++) {
        unsigned long long bits = 0;
        int lo_r = w << 6, hi_r = lo_r + 63;
        if (hi_r >= mn && lo_r <= mx) {
            int j0 = max(lo_r, mn), j1 = min(hi_r, mx);
            for (int j = j0; j <= j1; j++) {
                float dj = fabsf(pi - ps[j]);
                bool mem;
                if (dj < T) mem = (j >= wl && j <= wr);
                else        mem = (dj == T) && (tk[j] <= X);
                if (mem) {
                    bits |= 1ull << (j - lo_r);
                    qlo = min(qlo, j); qhi = max(qhi, j);
                }
            }
        }
        bmq[w] = bits;
    }
    bounds[b * 2048 + r] = make_uint2((unsigned)qlo, (unsigned)qhi);
}

// ---------------- K7: flash attention, head-split, double-buffered ----------
// Grid 1024: gb = b*512 + qg*4 + hp. 16 queries x 2 heads per block.
// Thread = (q:16, hl:2, seg:8 x 8dims). One barrier per 8-rank chunk (LDS
// double buffer); per-chunk 8-bit membership mask; alpha-rescale only when
// the running max changes. Output emitted pre-split (bf16 hi/lo).
__global__ __launch_bounds__(256) void k_attn(const float* __restrict__ qkv,
                                              const int* __restrict__ order,
                                              const unsigned long long* __restrict__ bmG,
                                              const uint2* __restrict__ bounds,
                                              short* __restrict__ attn_h,
                                              short* __restrict__ attn_l) {
    constexpr int HS = 68;           // padded head-slice stride (floats)
    constexpr int RS = 2 * HS;       // 136 floats per staged row (2 heads)
    int gb = blockIdx.x;             // 1024 blocks
    int b  = gb >> 9;
    int qg = (gb >> 2) & 127;
    int hp = gb & 3;
    int h0 = hp * 2;
    int r0 = qg * 16;
    int t = threadIdx.x;
    int q   = t >> 4;                // 0..15
    int hl  = (t >> 3) & 1;          // 0..1
    int seg = t & 7;                 // 0..7 (8 dims each)

    __shared__ float Kch[2][8 * RS];
    __shared__ float Vch[2][8 * RS];
    __shared__ unsigned long long bm[16][32];
    __shared__ int sh_tok[16];
    __shared__ int sh_lo, sh_hi;

    if (t < 16) sh_tok[t] = order[b * 2048 + r0 + t];
    if (t == 0) { sh_lo = 1 << 30; sh_hi = 0; }
    {
        const unsigned long long* src = bmG + ((long)(b * 2048 + r0)) * 32;
        ((unsigned long long*)bm)[t]       = src[t];
        ((unsigned long long*)bm)[t + 256] = src[t + 256];
    }
    __syncthreads();
    if (t < 16) {
        uint2 bd = bounds[b * 2048 + r0 + t];
        atomicMin(&sh_lo, (int)bd.x);
        atomicMax(&sh_hi, (int)bd.y);
    }

    // staging decode (constant per thread): idx = t + u*256 in [0,512)
    int rr_u[2], f4_u[2], dst_u[2], kv_u[2];
    #pragma unroll
    for (int u = 0; u < 2; u++) {
        int idx = t + u * 256;
        rr_u[u] = idx >> 6;
        int c6 = idx & 63;
        kv_u[u] = c6 >> 5;
        int hh = (c6 >> 4) & 1, w = c6 & 15;
        f4_u[u]  = (kv_u[u] ? 256 : 128) + (h0 + hh) * 16 + w;   // float4 idx in row
        dst_u[u] = (rr_u[u] * RS + hh * HS) / 4 + w;             // float4 idx in LDS
    }

    // q fragment (8 dims) in registers
    float qreg[8];
    {
        const float* qp = qkv + ((long)(b * 2048 + sh_tok[q])) * 1536
                          + (h0 + hl) * HD + seg * 8;
        float4 v0 = ((const float4*)qp)[0], v1 = ((const float4*)qp)[1];
        qreg[0]=v0.x; qreg[1]=v0.y; qreg[2]=v0.z; qreg[3]=v0.w;
        qreg[4]=v1.x; qreg[5]=v1.y; qreg[6]=v1.z; qreg[7]=v1.w;
    }
    float O[8];
    #pragma unroll
    for (int i = 0; i < 8; i++) O[i] = 0.f;
    float m = -1e30f, l = 0.f;
    __syncthreads();
    int lo = sh_lo & ~7, hi = sh_hi + 1;

    // prefetch first chunk into regs
    float4 pre[2];
    #pragma unroll
    for (int u = 0; u < 2; u++) {
        int row = min(lo + rr_u[u], 2047);
        int tok = order[b * 2048 + row];
        pre[u] = ((const float4*)(qkv + (long)(b * 2048 + tok) * 1536))[f4_u[u]];
    }

    int parity = 0;
    for (int c0 = lo; c0 < hi; c0 += 8, parity ^= 1) {
        // write prefetched chunk into buffer[parity]
        #pragma unroll
        for (int u = 0; u < 2; u++)
            ((float4*)(kv_u[u] ? Vch[parity] : Kch[parity]))[dst_u[u]] = pre[u];
        // issue next chunk's loads (hidden behind this chunk's compute)
        int cn = c0 + 8;
        if (cn < hi) {
            #pragma unroll
            for (int u = 0; u < 2; u++) {
                int row = min(cn + rr_u[u], 2047);
                int tok = order[b * 2048 + row];
                pre[u] = ((const float4*)(qkv + (long)(b * 2048 + tok) * 1536))[f4_u[u]];
            }
        }
        __syncthreads();   // single barrier per chunk (double buffer)

        // 8-bit membership mask for this (q, chunk); c0 is 8-aligned
        unsigned mask8 = (unsigned)((bm[q][c0 >> 6] >> (c0 & 63)) & 0xFFull);
        if (mask8) {
            const float* Kb = Kch[parity];
            const float* Vb = Vch[parity];
            float s[8];
            #pragma unroll
            for (int rr = 0; rr < 8; rr++) {
                float sv = -3e38f;
                if ((mask8 >> rr) & 1) {  // uniform across the 8 seg lanes
                    const float* kp = Kb + rr * RS + hl * HS + seg * 8;
                    float part = 0.f;
                    #pragma unroll
                    for (int i2 = 0; i2 < 8; i2++) part = fmaf(qreg[i2], kp[i2], part);
                    part += __shfl_xor(part, 1, 64);
                    part += __shfl_xor(part, 2, 64);
                    part += __shfl_xor(part, 4, 64);
                    sv = part * 0.125f;
                }
                s[rr] = sv;
            }
            // online softmax update (rescale only when max changes)
            float mx = s[0];
            #pragma unroll
            for (int rr = 1; rr < 8; rr++) mx = fmaxf(mx, s[rr]);
            if (mx > m) {
                float alpha = __expf(m - mx);
                m = mx;
                l *= alpha;
                #pragma unroll
                for (int i2 = 0; i2 < 8; i2++) O[i2] *= alpha;
            }
            float p[8], psum = 0.f;
            #pragma unroll
            for (int rr = 0; rr < 8; rr++) { p[rr] = __expf(s[rr] - m); psum += p[rr]; }
            l += psum;
            #pragma unroll
            for (int rr = 0; rr < 8; rr++) {
                const float* vp = Vb + rr * RS + hl * HS + seg * 8;
                float pv = p[rr];
                #pragma unroll
                for (int i2 = 0; i2 < 8; i2++) O[i2] = fmaf(pv, vp[i2], O[i2]);
            }
        }
    }

    float inv = 1.0f / l;
    long off = ((long)(b * 2048 + sh_tok[q])) * P_DIM + (h0 + hl) * HD + seg * 8;
    short hs[8], ls[8];
    #pragma unroll
    for (int i2 = 0; i2 < 8; i2++) {
        float v = O[i2] * inv;
        hs[i2] = bf_hi(v);
        ls[i2] = bf_hi(v - bf_f(hs[i2]));
    }
    *(short4*)(attn_h + off)     = make_short4(hs[0], hs[1], hs[2], hs[3]);
    *(short4*)(attn_h + off + 4) = make_short4(hs[4], hs[5], hs[6], hs[7]);
    *(short4*)(attn_l + off)     = make_short4(ls[0], ls[1], ls[2], ls[3]);
    *(short4*)(attn_l + off + 4) = make_short4(ls[4], ls[5], ls[6], ls[7]);
}

// ---------------- K9: pooled partial sums (atomic) --------------------------
__global__ __launch_bounds__(256) void k_pool(const float* __restrict__ zatt,
                                              float* __restrict__ pooled) {
    int b = blockIdx.y, chunk = blockIdx.x, t = threadIdx.x;
    float a0 = 0.f, a1 = 0.f;
    for (int s = 0; s < 16; s++) {
        long row = ((long)b * S_LEN + chunk * 16 + s) * P_DIM;
        a0 += zatt[row + t];
        a1 += zatt[row + t + 256];
    }
    atomicAdd(&pooled[b * P_DIM + t], a0);
    atomicAdd(&pooled[b * P_DIM + t + 256], a1);
}

// ---------------- Expert stage 1: h = pooled/S @ w1 + b1 (all 3 experts) ----
__global__ __launch_bounds__(256) void k_exp_fc1(const float* __restrict__ pooled,
                                                 const float* __restrict__ w1_0, const float* __restrict__ b1_0,
                                                 const float* __restrict__ w1_1, const float* __restrict__ b1_1,
                                                 const float* __restrict__ w1_2, const float* __restrict__ b1_2,
                                                 float* __restrict__ h) {
    int t = threadIdx.x, b = blockIdx.y;
    int c = blockIdx.x * 256 + t;  // [0, 1792)
    __shared__ float pl[P_DIM];
    pl[t]       = pooled[b * P_DIM + t]       * (1.0f / S_LEN);
    pl[t + 256] = pooled[b * P_DIM + t + 256] * (1.0f / S_LEN);
    __syncthreads();

    const float* wp; const float* bp; int s2, j;
    if (c < 256)      { wp = w1_0; bp = b1_0; s2 = 256;  j = c; }
    else if (c < 768) { wp = w1_1; bp = b1_1; s2 = 512;  j = c - 256; }
    else              { wp = w1_2; bp = b1_2; s2 = 1024; j = c - 768; }

    const float* p = wp + j;
    float acc = 0.f;
    #pragma unroll 16
    for (int k = 0; k < P_DIM; k++) {
        acc = fmaf(pl[k], *p, acc);
        p += s2;
    }
    h[(long)b * 1792 + c] = acc + bp[j];
}

// ---------------- Expert stage 2: LN + gelu per (expert, batch) -------------
__global__ __launch_bounds__(256) void k_exp_ln(float* __restrict__ h,
                                                const float* __restrict__ g0, const float* __restrict__ bb0,
                                                const float* __restrict__ g1, const float* __restrict__ bb1,
                                                const float* __restrict__ g2, const float* __restrict__ bb2) {
    int e = blockIdx.x, b = blockIdx.y, t = threadIdx.x;
    __shared__ float sm4[4];
    const int offs[3] = {0, 256, 768};
    const int ns[3]   = {256, 512, 1024};
    const float* gs[3]  = {g0, g1, g2};
    const float* bbs[3] = {bb0, bb1, bb2};
    int n = ns[e];
    float* hp = h + (long)b * 1792 + offs[e];
    const float* g = gs[e]; const float* bb = bbs[e];

    float x[4];
    float loc = 0.f;
    for (int u = 0; u < 4; u++) {
        int j = t + u * 256;
        x[u] = (j < n) ? hp[j] : 0.f;
        loc += x[u];
    }
    float mu = block_reduce_sum(loc, sm4) / (float)n;
    loc = 0.f;
    for (int u = 0; u < 4; u++) {
        int j = t + u * 256;
        if (j < n) { float d = x[u] - mu; loc += d * d; }
    }
    float var = block_reduce_sum(loc, sm4) / (float)n;
    float rs = 1.0f / sqrtf(var + 1e-5f);
    for (int u = 0; u < 4; u++) {
        int j = t + u * 256;
        if (j < n) hp[j] = gelu_exact((x[u] - mu) * rs * g[j] + bb[j]);
    }
}

// ---------------- Expert stage 3: out = h @ w2 + b2 (all 3 experts) ---------
__global__ __launch_bounds__(256) void k_exp_fc2(const float* __restrict__ h,
                                                 const float* __restrict__ w2_0, const float* __restrict__ b2_0,
                                                 const float* __restrict__ w2_1, const float* __restrict__ b2_1,
                                                 const float* __restrict__ w2_2, const float* __restrict__ b2_2,
                                                 float* __restrict__ out) {
    int t = threadIdx.x, b = blockIdx.y;
    int c = blockIdx.x * 256 + t;  // [0, 1024), valid < 896
    __shared__ float hs[1792];
    for (int u = 0; u < 7; u++) hs[t + u * 256] = h[(long)b * 1792 + t + u * 256];
    __syncthreads();
    if (c >= 896) return;

    const float* wp; const float* bp; int s2, sN, j, off_h;
    if (c < 128)      { wp = w2_0; bp = b2_0; s2 = 256;  sN = 128; j = c;       off_h = 0; }
    else if (c < 384) { wp = w2_1; bp = b2_1; s2 = 512;  sN = 256; j = c - 128; off_h = 256; }
    else              { wp = w2_2; bp = b2_2; s2 = 1024; sN = 512; j = c - 384; off_h = 768; }

    const float* p = wp + j;
    const float* hh = hs + off_h;
    float acc = 0.f;
    #pragma unroll 16
    for (int k = 0; k < s2; k++) {
        acc = fmaf(hh[k], *p, acc);
        p += sN;
    }
    out[b * 896 + c] = acc + bp[j];
}

// ---------------------------------------------------------------------------
extern "C" void kernel_launch(void* const* d_in, const int* in_sizes, int n_in,
                              void* d_out, int out_size, void* d_ws, size_t ws_size,
                              hipStream_t stream) {
    const float* seq   = (const float*)d_in[0];
    const float* penta = (const float*)d_in[1];
    const float* spos  = (const float*)d_in[2];
    const float* projW = (const float*)d_in[3];
    const float* projb = (const float*)d_in[4];
    const float* lng   = (const float*)d_in[5];
    const float* lnb   = (const float*)d_in[6];
    const float* qkvW  = (const float*)d_in[7];
    const float* qkvb  = (const float*)d_in[8];
    const float* outW  = (const float*)d_in[9];
    const float* outb  = (const float*)d_in[10];

    float* ws      = (float*)d_ws;
    float* z_pre   = ws;                      // 2097152 floats (zatt alias)
    short* z_h     = (short*)(z_pre + 2097152); // 2097152 shorts (attn_h alias)
    short* z_l     = z_h + 2097152;           // 2097152 shorts (attn_l alias)
    float* qkv     = (float*)(z_l + 2097152); // 6291456 floats
    float* pos     = qkv + 6291456;           // 4096
    float* pooled  = pos + 4096;              // 1024
    float* hbuf    = pooled + 1024;           // 4096
    unsigned long long* rowkey = (unsigned long long*)(hbuf + 4096);  // 4096 ull
    float* pos_srt = (float*)(rowkey + 4096); // 4096
    int*   order   = (int*)(pos_srt + 4096);  // 4096
    uint2* bounds  = (uint2*)(order + 4096);  // 4096 uint2
    unsigned long long* bmG = (unsigned long long*)(bounds + 4096); // 131072 ull
    short* cent_h  = (short*)(bmG + 131072);  // 524288 shorts
    short* cent_l  = cent_h + 524288;
    short* pjWT_h  = cent_l + 524288;         // 512x1024
    short* pjWT_l  = pjWT_h + 524288;
    short* qkWT_h  = pjWT_l + 524288;         // 1536x512
    short* qkWT_l  = qkWT_h + 786432;
    short* owWT_h  = qkWT_l + 786432;         // 512x512
    short* owWT_l  = owWT_h + 262144;
    short* attn_h  = z_h;     // z_h/z_l dead after anchor+qkv GEMMs
    short* attn_l  = z_l;
    float* zatt    = z_pre;   // z_pre dead after ln_gelu

    // weight prep
    k_cent<<<1024, 256, 0, stream>>>(penta, cent_h, cent_l);
    { dim3 g(16, 8);  k_wt<IN_DIM, P_DIM><<<g, 256, 0, stream>>>(projW, pjWT_h, pjWT_l); }
    { dim3 g(8, 24);  k_wt<P_DIM, 3 * P_DIM><<<g, 256, 0, stream>>>(qkvW, qkWT_h, qkWT_l); }
    { dim3 g(8, 8);   k_wt<P_DIM, P_DIM><<<g, 256, 0, stream>>>(outW, owWT_h, owWT_l); }

    // proj -> ln/gelu/norm (emits pre-split z)
    { dim3 g(32, 4);  k_mm<IN_DIM, P_DIM, 0, false><<<g, 256, 0, stream>>>(
          seq, nullptr, nullptr, pjWT_h, pjWT_l, projb, z_pre, nullptr); }
    k_ln_gelu_norm<<<4096, 256, 0, stream>>>(z_pre, lng, lnb, z_h, z_l);

    // anchor argmax -> positions -> sort
    hipMemsetAsync(rowkey, 0, 4096 * sizeof(unsigned long long), stream);
    { dim3 g(32, 8);  k_mm<P_DIM, 1024, 1, true><<<g, 256, 0, stream>>>(
          nullptr, z_h, z_l, cent_h, cent_l, nullptr, nullptr, rowkey); }
    k_pos<<<16, 256, 0, stream>>>(rowkey, spos, pos);
    k_sort<<<2, 256, 0, stream>>>(pos, order, pos_srt);

    // qkv -> routes(bitmap) -> attention (emits pre-split) -> out-proj
    { dim3 g(32, 12); k_mm<P_DIM, 3 * P_DIM, 0, true><<<g, 256, 0, stream>>>(
          nullptr, z_h, z_l, qkWT_h, qkWT_l, qkvb, qkv, nullptr); }
    k_routes<<<16, 256, 0, stream>>>(pos_srt, order, bmG, bounds);
    k_attn<<<1024, 256, 0, stream>>>(qkv, order, bmG, bounds, attn_h, attn_l);
    { dim3 g(32, 4);  k_mm<P_DIM, P_DIM, 0, true><<<g, 256, 0, stream>>>(
          nullptr, attn_h, attn_l, owWT_h, owWT_l, outb, zatt, nullptr); }

    // pool + experts
    hipMemsetAsync(pooled, 0, 1024 * sizeof(float), stream);
    { dim3 pg(128, 2); k_pool<<<pg, 256, 0, stream>>>(zatt, pooled); }

    dim3 g1(7, 2);
    k_exp_fc1<<<g1, 256, 0, stream>>>(pooled,
        (const float*)d_in[11], (const float*)d_in[12],
        (const float*)d_in[17], (const float*)d_in[18],
        (const float*)d_in[23], (const float*)d_in[24], hbuf);
    dim3 g2(3, 2);
    k_exp_ln<<<g2, 256, 0, stream>>>(hbuf,
        (const float*)d_in[13], (const float*)d_in[14],
        (const float*)d_in[19], (const float*)d_in[20],
        (const float*)d_in[25], (const float*)d_in[26]);
    dim3 g3(4, 2);
    k_exp_fc2<<<g3, 256, 0, stream>>>(hbuf,
        (const float*)d_in[15], (const float*)d_in[16],
        (const float*)d_in[21], (const float*)d_in[22],
        (const float*)d_in[27], (const float*)d_in[28], (float*)d_out);
}

// Round 10
// 495.117 us; speedup vs baseline: 2.9640x; 1.0889x over previous
//
#include <hip/hip_runtime.h>
#include <math.h>

#define DEV __device__ __forceinline__

static constexpr int S_LEN  = 2048;
static constexpr int IN_DIM = 1024;
static constexpr int P_DIM  = 512;
static constexpr int NHEAD  = 8;
static constexpr int HD     = 64;
static constexpr int KN     = 128;

typedef __attribute__((ext_vector_type(8))) short bf16x8;
typedef __attribute__((ext_vector_type(4))) float f32x4;

DEV float gelu_exact(float x) {
    return 0.5f * x * (1.0f + erff(x * 0.70710678118654752440f));
}

// float -> bf16 (RNE), and the split residual helpers
DEV short bf_hi(float x) {
    unsigned u = __float_as_uint(x);
    unsigned r = (u + 0x7fffu + ((u >> 16) & 1u)) >> 16;
    return (short)r;
}
DEV float bf_f(short h) { return __uint_as_float(((unsigned)(unsigned short)h) << 16); }

// 256-thread block sum reduction. sm4 must be float[4] shared.
DEV float block_reduce_sum(float v, float* sm4) {
    #pragma unroll
    for (int off = 32; off; off >>= 1) v += __shfl_down(v, off, 64);
    int lane = threadIdx.x & 63, w = threadIdx.x >> 6;
    __syncthreads();
    if (lane == 0) sm4[w] = v;
    __syncthreads();
    return sm4[0] + sm4[1] + sm4[2] + sm4[3];
}

// ---------------- K1: centroids, L2-normalized, split-bf16 [p][d] -----------
__global__ __launch_bounds__(256) void k_cent(const float* __restrict__ penta,
                                              short* __restrict__ ch,
                                              short* __restrict__ cl) {
    int p = blockIdx.x, t = threadIdx.x;
    __shared__ float sm4[4];
    float c0 = 0.f, c1 = 0.f;
    #pragma unroll
    for (int v = 0; v < 5; v++) {
        const float* row = penta + ((long)p * 5 + v) * P_DIM;
        c0 += row[t];
        c1 += row[t + 256];
    }
    c0 /= 5.0f; c1 /= 5.0f;
    float tot = block_reduce_sum(c0 * c0 + c1 * c1, sm4);
    float n = fmaxf(sqrtf(tot), 1e-12f);
    float v0 = c0 / n, v1 = c1 / n;
    short h0 = bf_hi(v0), h1 = bf_hi(v1);
    ch[p * P_DIM + t]       = h0;
    ch[p * P_DIM + t + 256] = h1;
    cl[p * P_DIM + t]       = bf_hi(v0 - bf_f(h0));
    cl[p * P_DIM + t + 256] = bf_hi(v1 - bf_f(h1));
}

// ---------------- weight transpose + split: W (K x N) -> WT_hi/lo (N x K) ---
template <int K, int N>
__global__ __launch_bounds__(256) void k_wt(const float* __restrict__ W,
                                            short* __restrict__ WTh,
                                            short* __restrict__ WTl) {
    __shared__ float tile[64][65];
    int bk = blockIdx.x, bn = blockIdx.y;
    int t = threadIdx.x;
    int c = t & 63, r4 = t >> 6;
    #pragma unroll
    for (int i = 0; i < 16; i++) {
        int row = r4 + i * 4;
        tile[row][c] = W[(long)(bk * 64 + row) * N + bn * 64 + c];
    }
    __syncthreads();
    #pragma unroll
    for (int i = 0; i < 16; i++) {
        int n = r4 + i * 4;
        float v = tile[c][n];
        short h = bf_hi(v);
        long o = (long)(bn * 64 + n) * K + bk * 64 + c;
        WTh[o] = h;
        WTl[o] = bf_hi(v - bf_f(h));
    }
}

// ---------------- MFMA split-bf16 GEMM: C = A@W + bias ----------------------
template <int K, int N, int EPI, bool SPLITA>
__global__ __launch_bounds__(256) void k_mm(const float* __restrict__ Af,
                                            const short* __restrict__ Ash,
                                            const short* __restrict__ Asl,
                                            const short* __restrict__ BTh,
                                            const short* __restrict__ BTl,
                                            const float* __restrict__ bias,
                                            float* __restrict__ C,
                                            unsigned long long* __restrict__ rowkey) {
    __shared__ short Ah[128 * 40], Al[128 * 40], Bh[128 * 40], Bl[128 * 40];
    int t = threadIdx.x;
    int lane = t & 63, wave = t >> 6;
    int wr = (wave >> 1) * 64, wc = (wave & 1) * 64;
    int m = lane & 15, quad = lane >> 4;
    int rb = blockIdx.x * 128, cb = blockIdx.y * 128;

    f32x4 acc[4][4];
    #pragma unroll
    for (int i = 0; i < 4; i++)
        #pragma unroll
        for (int j = 0; j < 4; j++) acc[i][j] = (f32x4){0.f, 0.f, 0.f, 0.f};

    for (int k0 = 0; k0 < K; k0 += 32) {
        __syncthreads();
        if constexpr (SPLITA) {
            #pragma unroll
            for (int ps = 0; ps < 2; ps++) {
                int idx = t + ps * 256;       // 0..511
                int row = idx >> 2, c4 = idx & 3;
                *(float4*)(Ah + row * 40 + c4 * 8) =
                    *(const float4*)(Ash + (long)(rb + row) * K + k0 + c4 * 8);
                *(float4*)(Al + row * 40 + c4 * 8) =
                    *(const float4*)(Asl + (long)(rb + row) * K + k0 + c4 * 8);
            }
        } else {
            #pragma unroll
            for (int ps = 0; ps < 4; ps++) {
                int row = (t >> 3) + ps * 32;
                int seg = t & 7;
                float4 v = *(const float4*)(Af + (long)(rb + row) * K + k0 + seg * 4);
                short h0 = bf_hi(v.x), h1 = bf_hi(v.y), h2 = bf_hi(v.z), h3 = bf_hi(v.w);
                short l0 = bf_hi(v.x - bf_f(h0)), l1 = bf_hi(v.y - bf_f(h1));
                short l2 = bf_hi(v.z - bf_f(h2)), l3 = bf_hi(v.w - bf_f(h3));
                *(short4*)(Ah + row * 40 + seg * 4) = make_short4(h0, h1, h2, h3);
                *(short4*)(Al + row * 40 + seg * 4) = make_short4(l0, l1, l2, l3);
            }
        }
        #pragma unroll
        for (int ps = 0; ps < 2; ps++) {
            int row = (t >> 2) + ps * 64;
            int seg = t & 3;
            *(float4*)(Bh + row * 40 + seg * 8) =
                *(const float4*)(BTh + (long)(cb + row) * K + k0 + seg * 8);
            *(float4*)(Bl + row * 40 + seg * 8) =
                *(const float4*)(BTl + (long)(cb + row) * K + k0 + seg * 8);
        }
        __syncthreads();

        bf16x8 ah[4], al[4], bh[4], bl[4];
        #pragma unroll
        for (int i = 0; i < 4; i++) {
            ah[i] = *(const bf16x8*)(Ah + (wr + i * 16 + m) * 40 + quad * 8);
            al[i] = *(const bf16x8*)(Al + (wr + i * 16 + m) * 40 + quad * 8);
            bh[i] = *(const bf16x8*)(Bh + (wc + i * 16 + m) * 40 + quad * 8);
            bl[i] = *(const bf16x8*)(Bl + (wc + i * 16 + m) * 40 + quad * 8);
        }
        #pragma unroll
        for (int i = 0; i < 4; i++)
            #pragma unroll
            for (int j = 0; j < 4; j++) {
                acc[i][j] = __builtin_amdgcn_mfma_f32_16x16x32_bf16(ah[i], bh[j], acc[i][j], 0, 0, 0);
                acc[i][j] = __builtin_amdgcn_mfma_f32_16x16x32_bf16(ah[i], bl[j], acc[i][j], 0, 0, 0);
                acc[i][j] = __builtin_amdgcn_mfma_f32_16x16x32_bf16(al[i], bh[j], acc[i][j], 0, 0, 0);
            }
    }

    if (EPI == 0) {
        #pragma unroll
        for (int i = 0; i < 4; i++) {
            int gr0 = rb + wr + i * 16 + quad * 4;
            #pragma unroll
            for (int j = 0; j < 4; j++) {
                int gc = cb + wc + j * 16 + m;
                float bv = bias[gc];
                #pragma unroll
                for (int r = 0; r < 4; r++)
                    C[(long)(gr0 + r) * N + gc] = acc[i][j][r] + bv;
            }
        }
    } else {
        #pragma unroll
        for (int i = 0; i < 4; i++) {
            #pragma unroll
            for (int r = 0; r < 4; r++) {
                int gr = rb + wr + i * 16 + quad * 4 + r;
                float bv = acc[i][0][r];
                int bp = cb + wc + m;
                #pragma unroll
                for (int j = 1; j < 4; j++) {
                    float v = acc[i][j][r];
                    int p = cb + wc + j * 16 + m;   // ascending; > keeps lowest p
                    if (v > bv) { bv = v; bp = p; }
                }
                #pragma unroll
                for (int off = 1; off < 16; off <<= 1) {
                    float ov = __shfl_xor(bv, off, 64);
                    int op = __shfl_xor(bp, off, 64);
                    if (ov > bv || (ov == bv && op < bp)) { bv = ov; bp = op; }
                }
                if (m == 0) {
                    unsigned u = __float_as_uint(bv);
                    u = (u & 0x80000000u) ? ~u : (u | 0x80000000u);
                    unsigned long long key =
                        ((unsigned long long)u << 32) | (unsigned)(0xFFFFFFFFu - (unsigned)bp);
                    atomicMax(&rowkey[gr], key);
                }
            }
        }
    }
}

// ---------------- K3: LayerNorm -> gelu -> L2 norm -> emit SPLIT bf16 -------
__global__ __launch_bounds__(256) void k_ln_gelu_norm(const float* __restrict__ Zin,
                                                      const float* __restrict__ g,
                                                      const float* __restrict__ b,
                                                      short* __restrict__ z_h,
                                                      short* __restrict__ z_l) {
    long row = blockIdx.x;
    int t = threadIdx.x;
    __shared__ float sm4[4];
    float x0 = Zin[row * P_DIM + t], x1 = Zin[row * P_DIM + t + 256];
    float mu = block_reduce_sum(x0 + x1, sm4) * (1.0f / P_DIM);
    float d0 = x0 - mu, d1 = x1 - mu;
    float var = block_reduce_sum(d0 * d0 + d1 * d1, sm4) * (1.0f / P_DIM);
    float rs = 1.0f / sqrtf(var + 1e-5f);
    float y0 = gelu_exact(d0 * rs * g[t] + b[t]);
    float y1 = gelu_exact(d1 * rs * g[t + 256] + b[t + 256]);
    float nn = block_reduce_sum(y0 * y0 + y1 * y1, sm4);
    float n = fmaxf(sqrtf(nn), 1e-12f);
    float v0 = y0 / n, v1 = y1 / n;
    short h0 = bf_hi(v0), h1 = bf_hi(v1);
    z_h[row * P_DIM + t]       = h0;
    z_h[row * P_DIM + t + 256] = h1;
    z_l[row * P_DIM + t]       = bf_hi(v0 - bf_f(h0));
    z_l[row * P_DIM + t + 256] = bf_hi(v1 - bf_f(h1));
}

// ---------------- K5: bitonic argsort (fused rowkey->pos gather) ------------
__global__ __launch_bounds__(256) void k_sort(const unsigned long long* __restrict__ rowkey,
                                              const float* __restrict__ spos,
                                              int* __restrict__ order,
                                              float* __restrict__ pos_srt) {
    int b = blockIdx.x, t = threadIdx.x;
    __shared__ unsigned long long key[2048];
    for (int u = 0; u < 8; u++) {
        int i = t + u * 256;
        unsigned p = 0xFFFFFFFFu - (unsigned)(rowkey[b * 2048 + i] & 0xFFFFFFFFull);
        float pv = spos[p];
        key[i] = (((unsigned long long)__float_as_uint(pv)) << 32) | (unsigned)i;
    }
    __syncthreads();
    for (int k = 2; k <= 2048; k <<= 1) {
        for (int j = k >> 1; j > 0; j >>= 1) {
            for (int u = 0; u < 8; u++) {
                int i = t + u * 256;
                int l = i ^ j;
                if (l > i) {
                    bool up = ((i & k) == 0);
                    unsigned long long a = key[i], c = key[l];
                    if ((a > c) == up) { key[i] = c; key[l] = a; }
                }
            }
            __syncthreads();
        }
    }
    for (int u = 0; u < 8; u++) {
        int r = t + u * 256;
        unsigned long long kk = key[r];
        order[b * 2048 + r]   = (int)(kk & 0xffffffffu);
        pos_srt[b * 2048 + r] = __uint_as_float((unsigned)(kk >> 32));
    }
}

// ---------------- K6: exact top-128 via rank-window + tie resolution --------
__global__ __launch_bounds__(256) void k_routes(const float* __restrict__ pos_srt,
                                                const int* __restrict__ order,
                                                unsigned long long* __restrict__ bmG,
                                                uint2* __restrict__ bounds) {
    int blk = blockIdx.x;                 // 16 blocks
    int b = blk >> 3;
    int r = (blk & 7) * 256 + threadIdx.x;
    int t = threadIdx.x;
    __shared__ float ps[2048];
    __shared__ unsigned short tk[2048];
    for (int u = 0; u < 8; u++) {
        int i = t + u * 256;
        ps[i] = pos_srt[b * 2048 + i];
        tk[i] = (unsigned short)order[b * 2048 + i];
    }
    __syncthreads();

    float pi = ps[r];
    int wl = r, wr = r;
    float T = 0.0f;
    for (int n = 1; n < 128; n++) {
        float dl = (wl > 0)    ? (pi - ps[wl - 1]) : 3e38f;
        float dr = (wr < 2047) ? (ps[wr + 1] - pi) : 3e38f;
        if (dl <= dr) { wl--; T = fmaxf(T, dl); }
        else          { wr++; T = fmaxf(T, dr); }
    }

    int e1 = 2048, e2 = -1, e3 = 2048, e4 = -1;
    {
        int a = -1;
        if (fabsf(pi - ps[wl]) == T) a = wl;
        else if (wl > 0 && fabsf(pi - ps[wl - 1]) == T) a = wl - 1;
        if (a >= 0) {
            e1 = a; while (e1 > 0 && fabsf(pi - ps[e1 - 1]) == T) e1--;
            e2 = a; while (e2 < 2047 && fabsf(pi - ps[e2 + 1]) == T) e2++;
        }
        if (wr > e2) {
            int a2 = -1;
            if (fabsf(pi - ps[wr]) == T) a2 = wr;
            else if (wr < 2047 && fabsf(pi - ps[wr + 1]) == T) a2 = wr + 1;
            if (a2 >= 0) {
                e3 = a2; while (e3 - 1 > e2 && fabsf(pi - ps[e3 - 1]) == T) e3--;
                e4 = a2; while (e4 < 2047 && fabsf(pi - ps[e4 + 1]) == T) e4++;
            }
        }
    }
    int need = 0;
    if (e2 >= e1) need += max(0, min(wr, e2) - max(wl, e1) + 1);
    if (e4 >= e3) need += max(0, min(wr, e4) - max(wl, e3) + 1);
    int tiecount = (e2 >= e1 ? e2 - e1 + 1 : 0) + (e4 >= e3 ? e4 - e3 + 1 : 0);

    int X = 65535;
    if (need < tiecount) {
        int lo2 = 0, hi2 = 2047;
        while (lo2 < hi2) {
            int mid = (lo2 + hi2) >> 1;
            int cnt = 0;
            for (int j = e1; j <= e2; j++) cnt += (tk[j] <= mid) ? 1 : 0;
            for (int j = e3; j <= e4; j++) cnt += (tk[j] <= mid) ? 1 : 0;
            if (cnt >= need) hi2 = mid; else lo2 = mid + 1;
        }
        X = lo2;
    }

    int mn = wl, mx = wr;
    if (e2 >= e1) { mn = min(mn, e1); mx = max(mx, e2); }
    if (e4 >= e3) mx = max(mx, e4);
    int qlo = 2048, qhi = -1;
    unsigned long long* bmq = bmG + ((long)(b * 2048 + r)) * 32;
    for (int w = 0; w < 32; w++) {
        unsigned long long bits = 0;
        int lo_r = w << 6, hi_r = lo_r + 63;
        if (hi_r >= mn && lo_r <= mx) {
            int j0 = max(lo_r, mn), j1 = min(hi_r, mx);
            for (int j = j0; j <= j1; j++) {
                float dj = fabsf(pi - ps[j]);
                bool mem;
                if (dj < T) mem = (j >= wl && j <= wr);
                else        mem = (dj == T) && (tk[j] <= X);
                if (mem) {
                    bits |= 1ull << (j - lo_r);
                    qlo = min(qlo, j); qhi = max(qhi, j);
                }
            }
        }
        bmq[w] = bits;
    }
    bounds[b * 2048 + r] = make_uint2((unsigned)qlo, (unsigned)qhi);
}

// ---------------- K7: MFMA flash attention ----------------------------------
// Grid 1024: gb = b*512 + qg*4 + hp. Block = 16 rank-adjacent queries x 2
// heads. Waves: (rank-half rh, head hs). Per 64-rank stage: QK = split-bf16
// MFMA 16x16x32 (exact), masked softmax (p=0 for non-members, no sentinel
// exp), P split-bf16 via LDS transpose to A-layout, PV = MFMA with V^T
// single-bf16. Skips are WAVE-UNIFORM only (lane-divergent continue around
// the cooperative Pt transpose was the round-9 NaN). 2-way flash merge.
__global__ __launch_bounds__(256) void k_attn(const float* __restrict__ qkv,
                                              const int* __restrict__ order,
                                              const unsigned long long* __restrict__ bmG,
                                              const uint2* __restrict__ bounds,
                                              short* __restrict__ attn_h,
                                              short* __restrict__ attn_l) {
    __shared__ __align__(16) char smem[72320];
    short* Khi = (short*)smem;                              // 64 x 136 u16
    short* Klo = (short*)(smem + 17408);                    // 64 x 136
    short* Vt  = (short*)(smem + 34816);                    // 128 x 88
    short* Pt  = (short*)(smem + 57344);                    // 4 waves x 2 x 16x40
    unsigned short* cm = (unsigned short*)(smem + 67584);   // 128 x 16
    int* sh_tok = (int*)(smem + 71680);                     // 16
    int* sh_lohi = (int*)(smem + 71744);                    // 2
    float2* ml = (float2*)(smem + 71752);                   // [2][2][16]
    float* Opart = (float*)smem;                            // alias: [2][16][128]

    int gb = blockIdx.x;
    int b  = gb >> 9;
    int qg = (gb >> 2) & 127;
    int hp = gb & 3;
    int h0 = hp * 2;
    int r0 = qg * 16;
    int t = threadIdx.x;
    int lane = t & 63, wave = t >> 6;
    int rh = wave & 1, hs = wave >> 1;
    int key = lane & 15, quad = lane >> 4;

    const float4* qkvF4 = (const float4*)qkv;

    if (t < 16) sh_tok[t] = order[b * 2048 + r0 + t];
    if (t == 0) { sh_lohi[0] = 1 << 30; sh_lohi[1] = 0; }
    // build per-chunk membership masks cm[chunk][q]
    #pragma unroll
    for (int u = 0; u < 8; u++) {
        int e = t + u * 256;
        int c = e >> 4, q = e & 15;
        cm[c * 16 + q] = (unsigned short)(
            (bmG[((long)(b * 2048 + r0 + q)) * 32 + (c >> 2)] >> ((c & 3) * 16)) & 0xFFFF);
    }
    __syncthreads();
    if (t < 16) {
        uint2 bd = bounds[b * 2048 + r0 + t];
        atomicMin(&sh_lohi[0], (int)bd.x);
        atomicMax(&sh_lohi[1], (int)bd.y);
    }

    // Q fragments (A-layout: lane&15 = q, k = quad*8+j), split hi/lo, 2 ksteps
    bf16x8 qh[2], ql[2];
    {
        long tq = (long)(b * 2048 + sh_tok[key]) * 384;
        #pragma unroll
        for (int ks = 0; ks < 2; ks++) {
            float4 v0 = qkvF4[tq + (h0 + hs) * 16 + ks * 8 + quad * 2];
            float4 v1 = qkvF4[tq + (h0 + hs) * 16 + ks * 8 + quad * 2 + 1];
            float vv[8] = {v0.x, v0.y, v0.z, v0.w, v1.x, v1.y, v1.z, v1.w};
            #pragma unroll
            for (int j = 0; j < 8; j++) {
                short hb = bf_hi(vv[j]);
                qh[ks][j] = hb;
                ql[ks][j] = bf_hi(vv[j] - bf_f(hb));
            }
        }
    }
    __syncthreads();
    int lo = sh_lohi[0] & ~63, hi = sh_lohi[1] + 1;

    float mrow[4], lrow[4];
    f32x4 Ont[4];
    #pragma unroll
    for (int r = 0; r < 4; r++) { mrow[r] = -1e30f; lrow[r] = 0.f; }
    #pragma unroll
    for (int nt = 0; nt < 4; nt++) Ont[nt] = (f32x4){0.f, 0.f, 0.f, 0.f};

    short* PtH = Pt + wave * 1280;
    short* PtL = PtH + 640;

    for (int c0 = lo; c0 < hi; c0 += 64) {
        __syncthreads();
        // ---- stage K (split hi/lo, [rank][128 dims]) ----
        #pragma unroll
        for (int u = 0; u < 8; u++) {
            int idx = t + u * 256;
            int rl = idx >> 5, f4p = idx & 31;
            int rank = c0 + rl;
            int tok = order[b * 2048 + min(rank, 2047)];
            float4 v = qkvF4[(long)(b * 2048 + tok) * 384 + 128 + h0 * 16 + f4p];
            short h0s = bf_hi(v.x), h1s = bf_hi(v.y), h2s = bf_hi(v.z), h3s = bf_hi(v.w);
            *(short4*)(Khi + rl * 136 + f4p * 4) = make_short4(h0s, h1s, h2s, h3s);
            *(short4*)(Klo + rl * 136 + f4p * 4) =
                make_short4(bf_hi(v.x - bf_f(h0s)), bf_hi(v.y - bf_f(h1s)),
                            bf_hi(v.z - bf_f(h2s)), bf_hi(v.w - bf_f(h3s)));
        }
        // ---- stage V^T (single bf16, [dim 0..127][rank 0..63]) ----
        {
            int rq = t & 15;          // rank-quad: local ranks rq*4..+3
            int dp = t >> 4;          // dims dp*8..+7
            float4 va[4][2];
            #pragma unroll
            for (int i = 0; i < 4; i++) {
                int rank = c0 + rq * 4 + i;
                int tok = order[b * 2048 + min(rank, 2047)];
                long base = (long)(b * 2048 + tok) * 384 + 256 + h0 * 16 + dp * 2;
                va[i][0] = qkvF4[base];
                va[i][1] = qkvF4[base + 1];
            }
            #pragma unroll
            for (int j2 = 0; j2 < 2; j2++)
                #pragma unroll
                for (int c = 0; c < 4; c++) {
                    const float* f0 = (const float*)&va[0][j2];
                    const float* f1 = (const float*)&va[1][j2];
                    const float* f2 = (const float*)&va[2][j2];
                    const float* f3 = (const float*)&va[3][j2];
                    *(short4*)(Vt + (dp * 8 + j2 * 4 + c) * 88 + rq * 4) =
                        make_short4(bf_hi(f0[c]), bf_hi(f1[c]), bf_hi(f2[c]), bf_hi(f3[c]));
                }
        }
        __syncthreads();

        int cb = c0 + rh * 32;
        if (cb >= hi) continue;                  // wave-uniform
        int ch0 = cb >> 4;
        unsigned long long m0 = *(const unsigned long long*)(cm + ch0 * 16 + quad * 4);
        unsigned long long m1 = (ch0 + 1 < 128)
            ? *(const unsigned long long*)(cm + (ch0 + 1) * 16 + quad * 4) : 0ull;
        if (!__any((m0 | m1) != 0ull)) continue; // wave-uniform skip (fix)

        // ---- QK: split-bf16 MFMA, 2 key-tiles x 2 ksteps ----
        f32x4 S0 = (f32x4){0.f,0.f,0.f,0.f}, S1 = (f32x4){0.f,0.f,0.f,0.f};
        #pragma unroll
        for (int ks = 0; ks < 2; ks++) {
            const short* kb0 = Khi + (rh * 32 + key) * 136 + hs * 64 + ks * 32 + quad * 8;
            const short* kl0 = Klo + (rh * 32 + key) * 136 + hs * 64 + ks * 32 + quad * 8;
            const short* kb1 = kb0 + 16 * 136;
            const short* kl1 = kl0 + 16 * 136;
            bf16x8 b0h = *(const bf16x8*)kb0, b0l = *(const bf16x8*)kl0;
            bf16x8 b1h = *(const bf16x8*)kb1, b1l = *(const bf16x8*)kl1;
            S0 = __builtin_amdgcn_mfma_f32_16x16x32_bf16(qh[ks], b0h, S0, 0, 0, 0);
            S0 = __builtin_amdgcn_mfma_f32_16x16x32_bf16(qh[ks], b0l, S0, 0, 0, 0);
            S0 = __builtin_amdgcn_mfma_f32_16x16x32_bf16(ql[ks], b0h, S0, 0, 0, 0);
            S1 = __builtin_amdgcn_mfma_f32_16x16x32_bf16(qh[ks], b1h, S1, 0, 0, 0);
            S1 = __builtin_amdgcn_mfma_f32_16x16x32_bf16(qh[ks], b1l, S1, 0, 0, 0);
            S1 = __builtin_amdgcn_mfma_f32_16x16x32_bf16(ql[ks], b1h, S1, 0, 0, 0);
        }
        // ---- mask + online softmax (p = 0 for non-members; no sentinel exp)
        float s0[4], s1[4], p0[4], p1[4];
        unsigned bit0[4], bit1[4];
        #pragma unroll
        for (int r = 0; r < 4; r++) {
            bit0[r] = (unsigned)((m0 >> (r * 16 + key)) & 1);
            bit1[r] = (unsigned)((m1 >> (r * 16 + key)) & 1);
            s0[r] = bit0[r] ? S0[r] * 0.125f : -1e30f;
            s1[r] = bit1[r] ? S1[r] * 0.125f : -1e30f;
        }
        #pragma unroll
        for (int r = 0; r < 4; r++) {
            float cmax = fmaxf(s0[r], s1[r]);
            cmax = fmaxf(cmax, __shfl_xor(cmax, 1, 64));
            cmax = fmaxf(cmax, __shfl_xor(cmax, 2, 64));
            cmax = fmaxf(cmax, __shfl_xor(cmax, 4, 64));
            cmax = fmaxf(cmax, __shfl_xor(cmax, 8, 64));
            float mn = fmaxf(mrow[r], cmax);
            float alpha = __expf(mrow[r] - mn);
            mrow[r] = mn;
            p0[r] = bit0[r] ? __expf(s0[r] - mn) : 0.f;
            p1[r] = bit1[r] ? __expf(s1[r] - mn) : 0.f;
            float rs = p0[r] + p1[r];
            rs += __shfl_xor(rs, 1, 64);
            rs += __shfl_xor(rs, 2, 64);
            rs += __shfl_xor(rs, 4, 64);
            rs += __shfl_xor(rs, 8, 64);
            lrow[r] = lrow[r] * alpha + rs;
            #pragma unroll
            for (int nt = 0; nt < 4; nt++) Ont[nt][r] *= alpha;
        }
        // ---- P transpose to A-layout (split hi/lo) — FULL wave writes ----
        #pragma unroll
        for (int r = 0; r < 4; r++) {
            short ha = bf_hi(p0[r]);
            PtH[(quad * 4 + r) * 40 + key] = ha;
            PtL[(quad * 4 + r) * 40 + key] = bf_hi(p0[r] - bf_f(ha));
            short hb = bf_hi(p1[r]);
            PtH[(quad * 4 + r) * 40 + 16 + key] = hb;
            PtL[(quad * 4 + r) * 40 + 16 + key] = bf_hi(p1[r] - bf_f(hb));
        }
        // ---- PV MFMA (same-wave LDS roundtrip; in-order LDS per wave) ----
        bf16x8 pfh = *(const bf16x8*)(PtH + key * 40 + quad * 8);
        bf16x8 pfl = *(const bf16x8*)(PtL + key * 40 + quad * 8);
        #pragma unroll
        for (int nt = 0; nt < 4; nt++) {
            bf16x8 vf = *(const bf16x8*)(Vt + (hs * 64 + nt * 16 + key) * 88
                                         + rh * 32 + quad * 8);
            Ont[nt] = __builtin_amdgcn_mfma_f32_16x16x32_bf16(pfh, vf, Ont[nt], 0, 0, 0);
            Ont[nt] = __builtin_amdgcn_mfma_f32_16x16x32_bf16(pfl, vf, Ont[nt], 0, 0, 0);
        }
    }

    // ---- write per-wave partial state ----
    if (key == 0) {
        #pragma unroll
        for (int r = 0; r < 4; r++)
            ml[(rh * 2 + hs) * 16 + quad * 4 + r] = make_float2(mrow[r], lrow[r]);
    }
    __syncthreads();   // K/Vt dead; Opart aliases them
    #pragma unroll
    for (int nt = 0; nt < 4; nt++)
        #pragma unroll
        for (int r = 0; r < 4; r++)
            Opart[rh * 2048 + (quad * 4 + r) * 128 + hs * 64 + nt * 16 + key] = Ont[nt][r];
    __syncthreads();

    // ---- 2-way flash merge + pre-split output ----
    {
        int q = t >> 4, hs2 = (t >> 3) & 1, ds = t & 7;
        float2 a = ml[(0 * 2 + hs2) * 16 + q];
        float2 c = ml[(1 * 2 + hs2) * 16 + q];
        float M = fmaxf(a.x, c.x);
        float w0 = __expf(a.x - M), w1 = __expf(c.x - M);
        float denom = a.y * w0 + c.y * w1;
        float inv = 1.0f / fmaxf(denom, 1e-37f);
        long off = (long)(b * 2048 + sh_tok[q]) * P_DIM + (h0 + hs2) * HD + ds * 8;
        short hsv[8], lsv[8];
        #pragma unroll
        for (int j = 0; j < 8; j++) {
            int d = hs2 * 64 + ds * 8 + j;
            float o = (Opart[q * 128 + d] * w0 + Opart[2048 + q * 128 + d] * w1) * inv;
            hsv[j] = bf_hi(o);
            lsv[j] = bf_hi(o - bf_f(hsv[j]));
        }
        *(short4*)(attn_h + off)     = make_short4(hsv[0], hsv[1], hsv[2], hsv[3]);
        *(short4*)(attn_h + off + 4) = make_short4(hsv[4], hsv[5], hsv[6], hsv[7]);
        *(short4*)(attn_l + off)     = make_short4(lsv[0], lsv[1], lsv[2], lsv[3]);
        *(short4*)(attn_l + off + 4) = make_short4(lsv[4], lsv[5], lsv[6], lsv[7]);
    }
}

// ---------------- K9: pooled partial sums (atomic) --------------------------
__global__ __launch_bounds__(256) void k_pool(const float* __restrict__ zatt,
                                              float* __restrict__ pooled) {
    int b = blockIdx.y, chunk = blockIdx.x, t = threadIdx.x;
    float a0 = 0.f, a1 = 0.f;
    for (int s = 0; s < 16; s++) {
        long row = ((long)b * S_LEN + chunk * 16 + s) * P_DIM;
        a0 += zatt[row + t];
        a1 += zatt[row + t + 256];
    }
    atomicAdd(&pooled[b * P_DIM + t], a0);
    atomicAdd(&pooled[b * P_DIM + t + 256], a1);
}

// ---------------- Expert stage 1: h = pooled/S @ w1 + b1 (all 3 experts) ----
__global__ __launch_bounds__(256) void k_exp_fc1(const float* __restrict__ pooled,
                                                 const float* __restrict__ w1_0, const float* __restrict__ b1_0,
                                                 const float* __restrict__ w1_1, const float* __restrict__ b1_1,
                                                 const float* __restrict__ w1_2, const float* __restrict__ b1_2,
                                                 float* __restrict__ h) {
    int t = threadIdx.x, b = blockIdx.y;
    int c = blockIdx.x * 256 + t;  // [0, 1792)
    __shared__ float pl[P_DIM];
    pl[t]       = pooled[b * P_DIM + t]       * (1.0f / S_LEN);
    pl[t + 256] = pooled[b * P_DIM + t + 256] * (1.0f / S_LEN);
    __syncthreads();

    const float* wp; const float* bp; int s2, j;
    if (c < 256)      { wp = w1_0; bp = b1_0; s2 = 256;  j = c; }
    else if (c < 768) { wp = w1_1; bp = b1_1; s2 = 512;  j = c - 256; }
    else              { wp = w1_2; bp = b1_2; s2 = 1024; j = c - 768; }

    const float* p = wp + j;
    float acc = 0.f;
    #pragma unroll 16
    for (int k = 0; k < P_DIM; k++) {
        acc = fmaf(pl[k], *p, acc);
        p += s2;
    }
    h[(long)b * 1792 + c] = acc + bp[j];
}

// ---------------- Expert stage 2: LN + gelu per (expert, batch) -------------
__global__ __launch_bounds__(256) void k_exp_ln(float* __restrict__ h,
                                                const float* __restrict__ g0, const float* __restrict__ bb0,
                                                const float* __restrict__ g1, const float* __restrict__ bb1,
                                                const float* __restrict__ g2, const float* __restrict__ bb2) {
    int e = blockIdx.x, b = blockIdx.y, t = threadIdx.x;
    __shared__ float sm4[4];
    const int offs[3] = {0, 256, 768};
    const int ns[3]   = {256, 512, 1024};
    const float* gs[3]  = {g0, g1, g2};
    const float* bbs[3] = {bb0, bb1, bb2};
    int n = ns[e];
    float* hp = h + (long)b * 1792 + offs[e];
    const float* g = gs[e]; const float* bb = bbs[e];

    float x[4];
    float loc = 0.f;
    for (int u = 0; u < 4; u++) {
        int j = t + u * 256;
        x[u] = (j < n) ? hp[j] : 0.f;
        loc += x[u];
    }
    float mu = block_reduce_sum(loc, sm4) / (float)n;
    loc = 0.f;
    for (int u = 0; u < 4; u++) {
        int j = t + u * 256;
        if (j < n) { float d = x[u] - mu; loc += d * d; }
    }
    float var = block_reduce_sum(loc, sm4) / (float)n;
    float rs = 1.0f / sqrtf(var + 1e-5f);
    for (int u = 0; u < 4; u++) {
        int j = t + u * 256;
        if (j < n) hp[j] = gelu_exact((x[u] - mu) * rs * g[j] + bb[j]);
    }
}

// ---------------- Expert stage 3: out = h @ w2 + b2 (all 3 experts) ---------
__global__ __launch_bounds__(256) void k_exp_fc2(const float* __restrict__ h,
                                                 const float* __restrict__ w2_0, const float* __restrict__ b2_0,
                                                 const float* __restrict__ w2_1, const float* __restrict__ b2_1,
                                                 const float* __restrict__ w2_2, const float* __restrict__ b2_2,
                                                 float* __restrict__ out) {
    int t = threadIdx.x, b = blockIdx.y;
    int c = blockIdx.x * 256 + t;  // [0, 1024), valid < 896
    __shared__ float hs[1792];
    for (int u = 0; u < 7; u++) hs[t + u * 256] = h[(long)b * 1792 + t + u * 256];
    __syncthreads();
    if (c >= 896) return;

    const float* wp; const float* bp; int s2, sN, j, off_h;
    if (c < 128)      { wp = w2_0; bp = b2_0; s2 = 256;  sN = 128; j = c;       off_h = 0; }
    else if (c < 384) { wp = w2_1; bp = b2_1; s2 = 512;  sN = 256; j = c - 128; off_h = 256; }
    else              { wp = w2_2; bp = b2_2; s2 = 1024; sN = 512; j = c - 384; off_h = 768; }

    const float* p = wp + j;
    const float* hh = hs + off_h;
    float acc = 0.f;
    #pragma unroll 16
    for (int k = 0; k < s2; k++) {
        acc = fmaf(hh[k], *p, acc);
        p += sN;
    }
    out[b * 896 + c] = acc + bp[j];
}

// ---------------------------------------------------------------------------
extern "C" void kernel_launch(void* const* d_in, const int* in_sizes, int n_in,
                              void* d_out, int out_size, void* d_ws, size_t ws_size,
                              hipStream_t stream) {
    const float* seq   = (const float*)d_in[0];
    const float* penta = (const float*)d_in[1];
    const float* spos  = (const float*)d_in[2];
    const float* projW = (const float*)d_in[3];
    const float* projb = (const float*)d_in[4];
    const float* lng   = (const float*)d_in[5];
    const float* lnb   = (const float*)d_in[6];
    const float* qkvW  = (const float*)d_in[7];
    const float* qkvb  = (const float*)d_in[8];
    const float* outW  = (const float*)d_in[9];
    const float* outb  = (const float*)d_in[10];

    float* ws      = (float*)d_ws;
    float* z_pre   = ws;                      // 2097152 floats (zatt alias)
    short* z_h     = (short*)(z_pre + 2097152); // 2097152 shorts (attn_h alias)
    short* z_l     = z_h + 2097152;           // 2097152 shorts (attn_l alias)
    float* qkv     = (float*)(z_l + 2097152); // 6291456 floats
    float* pos     = qkv + 6291456;           // 4096 (unused, layout keep)
    float* pooled  = pos + 4096;              // 1024
    float* hbuf    = pooled + 1024;           // 4096
    unsigned long long* rowkey = (unsigned long long*)(hbuf + 4096);  // 4096 ull
    float* pos_srt = (float*)(rowkey + 4096); // 4096
    int*   order   = (int*)(pos_srt + 4096);  // 4096
    uint2* bounds  = (uint2*)(order + 4096);  // 4096 uint2
    unsigned long long* bmG = (unsigned long long*)(bounds + 4096); // 131072 ull
    short* cent_h  = (short*)(bmG + 131072);  // 524288 shorts
    short* cent_l  = cent_h + 524288;
    short* pjWT_h  = cent_l + 524288;         // 512x1024
    short* pjWT_l  = pjWT_h + 524288;
    short* qkWT_h  = pjWT_l + 524288;         // 1536x512
    short* qkWT_l  = qkWT_h + 786432;
    short* owWT_h  = qkWT_l + 786432;         // 512x512
    short* owWT_l  = owWT_h + 262144;
    short* attn_h  = z_h;     // z_h/z_l dead after anchor+qkv GEMMs
    short* attn_l  = z_l;
    float* zatt    = z_pre;   // z_pre dead after ln_gelu

    // weight prep
    k_cent<<<1024, 256, 0, stream>>>(penta, cent_h, cent_l);
    { dim3 g(16, 8);  k_wt<IN_DIM, P_DIM><<<g, 256, 0, stream>>>(projW, pjWT_h, pjWT_l); }
    { dim3 g(8, 24);  k_wt<P_DIM, 3 * P_DIM><<<g, 256, 0, stream>>>(qkvW, qkWT_h, qkWT_l); }
    { dim3 g(8, 8);   k_wt<P_DIM, P_DIM><<<g, 256, 0, stream>>>(outW, owWT_h, owWT_l); }

    // proj -> ln/gelu/norm (emits pre-split z)
    { dim3 g(32, 4);  k_mm<IN_DIM, P_DIM, 0, false><<<g, 256, 0, stream>>>(
          seq, nullptr, nullptr, pjWT_h, pjWT_l, projb, z_pre, nullptr); }
    k_ln_gelu_norm<<<4096, 256, 0, stream>>>(z_pre, lng, lnb, z_h, z_l);

    // anchor argmax -> sort (fused position gather)
    hipMemsetAsync(rowkey, 0, 4096 * sizeof(unsigned long long), stream);
    { dim3 g(32, 8);  k_mm<P_DIM, 1024, 1, true><<<g, 256, 0, stream>>>(
          nullptr, z_h, z_l, cent_h, cent_l, nullptr, nullptr, rowkey); }
    k_sort<<<2, 256, 0, stream>>>(rowkey, spos, order, pos_srt);

    // qkv -> routes(bitmap) -> attention (emits pre-split) -> out-proj
    { dim3 g(32, 12); k_mm<P_DIM, 3 * P_DIM, 0, true><<<g, 256, 0, stream>>>(
          nullptr, z_h, z_l, qkWT_h, qkWT_l, qkvb, qkv, nullptr); }
    k_routes<<<16, 256, 0, stream>>>(pos_srt, order, bmG, bounds);
    k_attn<<<1024, 256, 0, stream>>>(qkv, order, bmG, bounds, attn_h, attn_l);
    { dim3 g(32, 4);  k_mm<P_DIM, P_DIM, 0, true><<<g, 256, 0, stream>>>(
          nullptr, attn_h, attn_l, owWT_h, owWT_l, outb, zatt, nullptr); }

    // pool + experts
    hipMemsetAsync(pooled, 0, 1024 * sizeof(float), stream);
    { dim3 pg(128, 2); k_pool<<<pg, 256, 0, stream>>>(zatt, pooled); }

    dim3 g1(7, 2);
    k_exp_fc1<<<g1, 256, 0, stream>>>(pooled,
        (const float*)d_in[11], (const float*)d_in[12],
        (const float*)d_in[17], (const float*)d_in[18],
        (const float*)d_in[23], (const float*)d_in[24], hbuf);
    dim3 g2(3, 2);
    k_exp_ln<<<g2, 256, 0, stream>>>(hbuf,
        (const float*)d_in[13], (const float*)d_in[14],
        (const float*)d_in[19], (const float*)d_in[20],
        (const float*)d_in[25], (const float*)d_in[26]);
    dim3 g3(4, 2);
    k_exp_fc2<<<g3, 256, 0, stream>>>(hbuf,
        (const float*)d_in[15], (const float*)d_in[16],
        (const float*)d_in[21], (const float*)d_in[22],
        (const float*)d_in[27], (const float*)d_in[28], (float*)d_out);
}

// Round 11
// 440.605 us; speedup vs baseline: 3.3307x; 1.1237x over previous
//
#include <hip/hip_runtime.h>
#include <math.h>

#define DEV __device__ __forceinline__

static constexpr int S_LEN  = 2048;
static constexpr int IN_DIM = 1024;
static constexpr int P_DIM  = 512;
static constexpr int NHEAD  = 8;
static constexpr int HD     = 64;
static constexpr int KN     = 128;

typedef __attribute__((ext_vector_type(8))) short bf16x8;
typedef __attribute__((ext_vector_type(4))) float f32x4;

DEV float gelu_exact(float x) {
    return 0.5f * x * (1.0f + erff(x * 0.70710678118654752440f));
}

// float -> bf16 (RNE), and the split residual helpers
DEV short bf_hi(float x) {
    unsigned u = __float_as_uint(x);
    unsigned r = (u + 0x7fffu + ((u >> 16) & 1u)) >> 16;
    return (short)r;
}
DEV float bf_f(short h) { return __uint_as_float(((unsigned)(unsigned short)h) << 16); }

// 256-thread block sum reduction. sm4 must be float[4] shared.
DEV float block_reduce_sum(float v, float* sm4) {
    #pragma unroll
    for (int off = 32; off; off >>= 1) v += __shfl_down(v, off, 64);
    int lane = threadIdx.x & 63, w = threadIdx.x >> 6;
    __syncthreads();
    if (lane == 0) sm4[w] = v;
    __syncthreads();
    return sm4[0] + sm4[1] + sm4[2] + sm4[3];
}

// ---------------- K1: centroids, L2-normalized, split-bf16 [p][d] -----------
__global__ __launch_bounds__(256) void k_cent(const float* __restrict__ penta,
                                              short* __restrict__ ch,
                                              short* __restrict__ cl) {
    int p = blockIdx.x, t = threadIdx.x;
    __shared__ float sm4[4];
    float c0 = 0.f, c1 = 0.f;
    #pragma unroll
    for (int v = 0; v < 5; v++) {
        const float* row = penta + ((long)p * 5 + v) * P_DIM;
        c0 += row[t];
        c1 += row[t + 256];
    }
    c0 /= 5.0f; c1 /= 5.0f;
    float tot = block_reduce_sum(c0 * c0 + c1 * c1, sm4);
    float n = fmaxf(sqrtf(tot), 1e-12f);
    float v0 = c0 / n, v1 = c1 / n;
    short h0 = bf_hi(v0), h1 = bf_hi(v1);
    ch[p * P_DIM + t]       = h0;
    ch[p * P_DIM + t + 256] = h1;
    cl[p * P_DIM + t]       = bf_hi(v0 - bf_f(h0));
    cl[p * P_DIM + t + 256] = bf_hi(v1 - bf_f(h1));
}

// ---------------- weight transpose + split: W (K x N) -> WT_hi/lo (N x K) ---
template <int K, int N>
__global__ __launch_bounds__(256) void k_wt(const float* __restrict__ W,
                                            short* __restrict__ WTh,
                                            short* __restrict__ WTl) {
    __shared__ float tile[64][65];
    int bk = blockIdx.x, bn = blockIdx.y;
    int t = threadIdx.x;
    int c = t & 63, r4 = t >> 6;
    #pragma unroll
    for (int i = 0; i < 16; i++) {
        int row = r4 + i * 4;
        tile[row][c] = W[(long)(bk * 64 + row) * N + bn * 64 + c];
    }
    __syncthreads();
    #pragma unroll
    for (int i = 0; i < 16; i++) {
        int n = r4 + i * 4;
        float v = tile[c][n];
        short h = bf_hi(v);
        long o = (long)(bn * 64 + n) * K + bk * 64 + c;
        WTh[o] = h;
        WTl[o] = bf_hi(v - bf_f(h));
    }
}

// ---------------- MFMA split-bf16 GEMM: C = A@W + bias ----------------------
template <int K, int N, int EPI, bool SPLITA>
__global__ __launch_bounds__(256) void k_mm(const float* __restrict__ Af,
                                            const short* __restrict__ Ash,
                                            const short* __restrict__ Asl,
                                            const short* __restrict__ BTh,
                                            const short* __restrict__ BTl,
                                            const float* __restrict__ bias,
                                            float* __restrict__ C,
                                            unsigned long long* __restrict__ rowkey) {
    __shared__ short Ah[128 * 40], Al[128 * 40], Bh[128 * 40], Bl[128 * 40];
    int t = threadIdx.x;
    int lane = t & 63, wave = t >> 6;
    int wr = (wave >> 1) * 64, wc = (wave & 1) * 64;
    int m = lane & 15, quad = lane >> 4;
    int rb = blockIdx.x * 128, cb = blockIdx.y * 128;

    f32x4 acc[4][4];
    #pragma unroll
    for (int i = 0; i < 4; i++)
        #pragma unroll
        for (int j = 0; j < 4; j++) acc[i][j] = (f32x4){0.f, 0.f, 0.f, 0.f};

    for (int k0 = 0; k0 < K; k0 += 32) {
        __syncthreads();
        if constexpr (SPLITA) {
            #pragma unroll
            for (int ps = 0; ps < 2; ps++) {
                int idx = t + ps * 256;       // 0..511
                int row = idx >> 2, c4 = idx & 3;
                *(float4*)(Ah + row * 40 + c4 * 8) =
                    *(const float4*)(Ash + (long)(rb + row) * K + k0 + c4 * 8);
                *(float4*)(Al + row * 40 + c4 * 8) =
                    *(const float4*)(Asl + (long)(rb + row) * K + k0 + c4 * 8);
            }
        } else {
            #pragma unroll
            for (int ps = 0; ps < 4; ps++) {
                int row = (t >> 3) + ps * 32;
                int seg = t & 7;
                float4 v = *(const float4*)(Af + (long)(rb + row) * K + k0 + seg * 4);
                short h0 = bf_hi(v.x), h1 = bf_hi(v.y), h2 = bf_hi(v.z), h3 = bf_hi(v.w);
                short l0 = bf_hi(v.x - bf_f(h0)), l1 = bf_hi(v.y - bf_f(h1));
                short l2 = bf_hi(v.z - bf_f(h2)), l3 = bf_hi(v.w - bf_f(h3));
                *(short4*)(Ah + row * 40 + seg * 4) = make_short4(h0, h1, h2, h3);
                *(short4*)(Al + row * 40 + seg * 4) = make_short4(l0, l1, l2, l3);
            }
        }
        #pragma unroll
        for (int ps = 0; ps < 2; ps++) {
            int row = (t >> 2) + ps * 64;
            int seg = t & 3;
            *(float4*)(Bh + row * 40 + seg * 8) =
                *(const float4*)(BTh + (long)(cb + row) * K + k0 + seg * 8);
            *(float4*)(Bl + row * 40 + seg * 8) =
                *(const float4*)(BTl + (long)(cb + row) * K + k0 + seg * 8);
        }
        __syncthreads();

        bf16x8 ah[4], al[4], bh[4], bl[4];
        #pragma unroll
        for (int i = 0; i < 4; i++) {
            ah[i] = *(const bf16x8*)(Ah + (wr + i * 16 + m) * 40 + quad * 8);
            al[i] = *(const bf16x8*)(Al + (wr + i * 16 + m) * 40 + quad * 8);
            bh[i] = *(const bf16x8*)(Bh + (wc + i * 16 + m) * 40 + quad * 8);
            bl[i] = *(const bf16x8*)(Bl + (wc + i * 16 + m) * 40 + quad * 8);
        }
        #pragma unroll
        for (int i = 0; i < 4; i++)
            #pragma unroll
            for (int j = 0; j < 4; j++) {
                acc[i][j] = __builtin_amdgcn_mfma_f32_16x16x32_bf16(ah[i], bh[j], acc[i][j], 0, 0, 0);
                acc[i][j] = __builtin_amdgcn_mfma_f32_16x16x32_bf16(ah[i], bl[j], acc[i][j], 0, 0, 0);
                acc[i][j] = __builtin_amdgcn_mfma_f32_16x16x32_bf16(al[i], bh[j], acc[i][j], 0, 0, 0);
            }
    }

    if (EPI == 0) {
        #pragma unroll
        for (int i = 0; i < 4; i++) {
            int gr0 = rb + wr + i * 16 + quad * 4;
            #pragma unroll
            for (int j = 0; j < 4; j++) {
                int gc = cb + wc + j * 16 + m;
                float bv = bias[gc];
                #pragma unroll
                for (int r = 0; r < 4; r++)
                    C[(long)(gr0 + r) * N + gc] = acc[i][j][r] + bv;
            }
        }
    } else {
        #pragma unroll
        for (int i = 0; i < 4; i++) {
            #pragma unroll
            for (int r = 0; r < 4; r++) {
                int gr = rb + wr + i * 16 + quad * 4 + r;
                float bv = acc[i][0][r];
                int bp = cb + wc + m;
                #pragma unroll
                for (int j = 1; j < 4; j++) {
                    float v = acc[i][j][r];
                    int p = cb + wc + j * 16 + m;   // ascending; > keeps lowest p
                    if (v > bv) { bv = v; bp = p; }
                }
                #pragma unroll
                for (int off = 1; off < 16; off <<= 1) {
                    float ov = __shfl_xor(bv, off, 64);
                    int op = __shfl_xor(bp, off, 64);
                    if (ov > bv || (ov == bv && op < bp)) { bv = ov; bp = op; }
                }
                if (m == 0) {
                    unsigned u = __float_as_uint(bv);
                    u = (u & 0x80000000u) ? ~u : (u | 0x80000000u);
                    unsigned long long key =
                        ((unsigned long long)u << 32) | (unsigned)(0xFFFFFFFFu - (unsigned)bp);
                    atomicMax(&rowkey[gr], key);
                }
            }
        }
    }
}

// ---------------- K3: LayerNorm -> gelu -> L2 norm -> emit SPLIT bf16 -------
__global__ __launch_bounds__(256) void k_ln_gelu_norm(const float* __restrict__ Zin,
                                                      const float* __restrict__ g,
                                                      const float* __restrict__ b,
                                                      short* __restrict__ z_h,
                                                      short* __restrict__ z_l) {
    long row = blockIdx.x;
    int t = threadIdx.x;
    __shared__ float sm4[4];
    float x0 = Zin[row * P_DIM + t], x1 = Zin[row * P_DIM + t + 256];
    float mu = block_reduce_sum(x0 + x1, sm4) * (1.0f / P_DIM);
    float d0 = x0 - mu, d1 = x1 - mu;
    float var = block_reduce_sum(d0 * d0 + d1 * d1, sm4) * (1.0f / P_DIM);
    float rs = 1.0f / sqrtf(var + 1e-5f);
    float y0 = gelu_exact(d0 * rs * g[t] + b[t]);
    float y1 = gelu_exact(d1 * rs * g[t + 256] + b[t + 256]);
    float nn = block_reduce_sum(y0 * y0 + y1 * y1, sm4);
    float n = fmaxf(sqrtf(nn), 1e-12f);
    float v0 = y0 / n, v1 = y1 / n;
    short h0 = bf_hi(v0), h1 = bf_hi(v1);
    z_h[row * P_DIM + t]       = h0;
    z_h[row * P_DIM + t + 256] = h1;
    z_l[row * P_DIM + t]       = bf_hi(v0 - bf_f(h0));
    z_l[row * P_DIM + t + 256] = bf_hi(v1 - bf_f(h1));
}

// ---------------- K5: bitonic argsort (fused rowkey->pos gather) ------------
__global__ __launch_bounds__(256) void k_sort(const unsigned long long* __restrict__ rowkey,
                                              const float* __restrict__ spos,
                                              int* __restrict__ order,
                                              float* __restrict__ pos_srt) {
    int b = blockIdx.x, t = threadIdx.x;
    __shared__ unsigned long long key[2048];
    for (int u = 0; u < 8; u++) {
        int i = t + u * 256;
        unsigned p = 0xFFFFFFFFu - (unsigned)(rowkey[b * 2048 + i] & 0xFFFFFFFFull);
        float pv = spos[p];
        key[i] = (((unsigned long long)__float_as_uint(pv)) << 32) | (unsigned)i;
    }
    __syncthreads();
    for (int k = 2; k <= 2048; k <<= 1) {
        for (int j = k >> 1; j > 0; j >>= 1) {
            for (int u = 0; u < 8; u++) {
                int i = t + u * 256;
                int l = i ^ j;
                if (l > i) {
                    bool up = ((i & k) == 0);
                    unsigned long long a = key[i], c = key[l];
                    if ((a > c) == up) { key[i] = c; key[l] = a; }
                }
            }
            __syncthreads();
        }
    }
    for (int u = 0; u < 8; u++) {
        int r = t + u * 256;
        unsigned long long kk = key[r];
        order[b * 2048 + r]   = (int)(kk & 0xffffffffu);
        pos_srt[b * 2048 + r] = __uint_as_float((unsigned)(kk >> 32));
    }
}

// ---------------- K6: exact top-128, one WAVE per query ---------------------
// T = 128th-smallest |pi-ps[j]| = min over 128-windows of window-max (greedy
// two-pointer equivalence; same fp expressions -> bit-identical). Strict set
// [Ls,Rs] and loose set [mn,mx] via monotone binary searches (ps sorted, fp
// subtract monotone). Ties = [mn,mx]\[Ls,Rs] (<=2 runs; 1 run when T==0).
// X = need-th smallest token index among ties (lane-parallel count).
__global__ __launch_bounds__(256) void k_routes(const float* __restrict__ pos_srt,
                                                const int* __restrict__ order,
                                                unsigned long long* __restrict__ bmG,
                                                uint2* __restrict__ bounds) {
    int blk = blockIdx.x;                 // 1024 blocks, 4 queries (waves) each
    int b = blk >> 9;
    int t = threadIdx.x;
    int lane = t & 63, wave = t >> 6;
    int r = (blk & 511) * 4 + wave;       // query rank in [0,2048)
    __shared__ float ps[2048];
    __shared__ unsigned short tk[2048];
    for (int u = 0; u < 8; u++) {
        int i = t + u * 256;
        ps[i] = pos_srt[b * 2048 + i];
        tk[i] = (unsigned short)order[b * 2048 + i];
    }
    __syncthreads();

    float pi = ps[r];
    // ---- T: min over valid windows [r-a, r+127-a] of max boundary dist ----
    float T = 3e38f;
    #pragma unroll
    for (int a2 = 0; a2 < 2; a2++) {
        int a = lane + a2 * 64;           // 0..127
        int jl = r - a, jr = r + 127 - a;
        if (jl >= 0 && jr <= 2047) {
            float dl = (a > 0)   ? (pi - ps[jl]) : 0.f;
            float dr = (a < 127) ? (ps[jr] - pi) : 0.f;
            T = fminf(T, fmaxf(dl, dr));
        }
    }
    #pragma unroll
    for (int off = 1; off < 64; off <<= 1) T = fminf(T, __shfl_xor(T, off, 64));

    // ---- boundaries via monotone binary search (redundant across lanes) ----
    int lo = 0, hi = r;
    while (lo < hi) { int mid = (lo + hi) >> 1; if (pi - ps[mid] <= T) hi = mid; else lo = mid + 1; }
    int mn = lo;
    lo = r; hi = 2047;
    while (lo < hi) { int mid = (lo + hi + 1) >> 1; if (ps[mid] - pi <= T) lo = mid; else hi = mid - 1; }
    int mx = lo;
    int Ls, Rs;
    if (T > 0.f) {
        lo = 0; hi = r;
        while (lo < hi) { int mid = (lo + hi) >> 1; if (pi - ps[mid] < T) hi = mid; else lo = mid + 1; }
        Ls = lo;
        lo = r; hi = 2047;
        while (lo < hi) { int mid = (lo + hi + 1) >> 1; if (ps[mid] - pi < T) lo = mid; else hi = mid - 1; }
        Rs = lo;
    } else { Ls = r + 1; Rs = r - 1; }   // no strict members when T == 0

    int cnt_strict = (Rs >= Ls) ? (Rs - Ls + 1) : 0;
    int need = 128 - cnt_strict;
    // tie runs (disjoint): strict present -> [mn,Ls-1] and [Rs+1,mx];
    // strict empty (T==0) -> single run [mn,mx].
    int l0a, l0b, r0a, r0b;
    if (cnt_strict > 0) { l0a = mn; l0b = Ls - 1; r0a = Rs + 1; r0b = mx; }
    else                { l0a = mn; l0b = mx;     r0a = 1;      r0b = 0; }
    int nL = (l0b >= l0a) ? (l0b - l0a + 1) : 0;
    int nR = (r0b >= r0a) ? (r0b - r0a + 1) : 0;
    int tiecount = nL + nR;

    // ---- X = need-th smallest token index among ties (parallel count) ----
    int X = 65535;
    if (need < tiecount) {
        int lo2 = 0, hi2 = 2047;
        while (lo2 < hi2) {
            int mid = (lo2 + hi2) >> 1;
            int cnt = 0;
            for (int e = lane; e < tiecount; e += 64) {
                int j = (e < nL) ? (l0a + e) : (r0a + e - nL);
                cnt += (tk[j] <= mid) ? 1 : 0;
            }
            #pragma unroll
            for (int off = 1; off < 64; off <<= 1) cnt += __shfl_xor(cnt, off, 64);
            if (cnt >= need) hi2 = mid; else lo2 = mid + 1;
        }
        X = lo2;
    }

    // ---- emit bitmap (lanes 0..31, one u64 word each) + bounds ----
    int qlo_loc = 1 << 30, qhi_loc = -1;
    if (lane < 32) {
        unsigned long long bits = 0;
        int j0 = lane << 6, j1 = j0 + 63;
        if (cnt_strict > 0) {
            int a0 = max(Ls, j0), a1 = min(Rs, j1);
            if (a0 <= a1) {
                int s = a0 - j0, e = a1 - j0;
                unsigned long long msk = (e - s == 63) ? ~0ull
                                       : (((1ull << (e - s + 1)) - 1) << s);
                bits |= msk;
            }
        }
        int a0 = max(l0a, j0), a1 = min(l0b, j1);
        for (int j = a0; j <= a1; j++) if (tk[j] <= X) bits |= 1ull << (j - j0);
        a0 = max(r0a, j0); a1 = min(r0b, j1);
        for (int j = a0; j <= a1; j++) if (tk[j] <= X) bits |= 1ull << (j - j0);
        if (bits) {
            qlo_loc = j0 + __builtin_ctzll(bits);
            qhi_loc = j0 + 63 - __builtin_clzll(bits);
        }
        bmG[((long)(b * 2048 + r)) * 32 + lane] = bits;
    }
    #pragma unroll
    for (int off = 1; off < 64; off <<= 1) {
        qlo_loc = min(qlo_loc, __shfl_xor(qlo_loc, off, 64));
        qhi_loc = max(qhi_loc, __shfl_xor(qhi_loc, off, 64));
    }
    if (lane == 0)
        bounds[b * 2048 + r] = make_uint2((unsigned)qlo_loc, (unsigned)qhi_loc);
}

// ---------------- K7: MFMA flash attention ----------------------------------
// (unchanged from round 10 — wave-uniform skips, verified)
__global__ __launch_bounds__(256) void k_attn(const float* __restrict__ qkv,
                                              const int* __restrict__ order,
                                              const unsigned long long* __restrict__ bmG,
                                              const uint2* __restrict__ bounds,
                                              short* __restrict__ attn_h,
                                              short* __restrict__ attn_l) {
    __shared__ __align__(16) char smem[72320];
    short* Khi = (short*)smem;                              // 64 x 136 u16
    short* Klo = (short*)(smem + 17408);                    // 64 x 136
    short* Vt  = (short*)(smem + 34816);                    // 128 x 88
    short* Pt  = (short*)(smem + 57344);                    // 4 waves x 2 x 16x40
    unsigned short* cm = (unsigned short*)(smem + 67584);   // 128 x 16
    int* sh_tok = (int*)(smem + 71680);                     // 16
    int* sh_lohi = (int*)(smem + 71744);                    // 2
    float2* ml = (float2*)(smem + 71752);                   // [2][2][16]
    float* Opart = (float*)smem;                            // alias: [2][16][128]

    int gb = blockIdx.x;
    int b  = gb >> 9;
    int qg = (gb >> 2) & 127;
    int hp = gb & 3;
    int h0 = hp * 2;
    int r0 = qg * 16;
    int t = threadIdx.x;
    int lane = t & 63, wave = t >> 6;
    int rh = wave & 1, hs = wave >> 1;
    int key = lane & 15, quad = lane >> 4;

    const float4* qkvF4 = (const float4*)qkv;

    if (t < 16) sh_tok[t] = order[b * 2048 + r0 + t];
    if (t == 0) { sh_lohi[0] = 1 << 30; sh_lohi[1] = 0; }
    #pragma unroll
    for (int u = 0; u < 8; u++) {
        int e = t + u * 256;
        int c = e >> 4, q = e & 15;
        cm[c * 16 + q] = (unsigned short)(
            (bmG[((long)(b * 2048 + r0 + q)) * 32 + (c >> 2)] >> ((c & 3) * 16)) & 0xFFFF);
    }
    __syncthreads();
    if (t < 16) {
        uint2 bd = bounds[b * 2048 + r0 + t];
        atomicMin(&sh_lohi[0], (int)bd.x);
        atomicMax(&sh_lohi[1], (int)bd.y);
    }

    bf16x8 qh[2], ql[2];
    {
        long tq = (long)(b * 2048 + sh_tok[key]) * 384;
        #pragma unroll
        for (int ks = 0; ks < 2; ks++) {
            float4 v0 = qkvF4[tq + (h0 + hs) * 16 + ks * 8 + quad * 2];
            float4 v1 = qkvF4[tq + (h0 + hs) * 16 + ks * 8 + quad * 2 + 1];
            float vv[8] = {v0.x, v0.y, v0.z, v0.w, v1.x, v1.y, v1.z, v1.w};
            #pragma unroll
            for (int j = 0; j < 8; j++) {
                short hb = bf_hi(vv[j]);
                qh[ks][j] = hb;
                ql[ks][j] = bf_hi(vv[j] - bf_f(hb));
            }
        }
    }
    __syncthreads();
    int lo = sh_lohi[0] & ~63, hi = sh_lohi[1] + 1;

    float mrow[4], lrow[4];
    f32x4 Ont[4];
    #pragma unroll
    for (int r = 0; r < 4; r++) { mrow[r] = -1e30f; lrow[r] = 0.f; }
    #pragma unroll
    for (int nt = 0; nt < 4; nt++) Ont[nt] = (f32x4){0.f, 0.f, 0.f, 0.f};

    short* PtH = Pt + wave * 1280;
    short* PtL = PtH + 640;

    for (int c0 = lo; c0 < hi; c0 += 64) {
        __syncthreads();
        #pragma unroll
        for (int u = 0; u < 8; u++) {
            int idx = t + u * 256;
            int rl = idx >> 5, f4p = idx & 31;
            int rank = c0 + rl;
            int tok = order[b * 2048 + min(rank, 2047)];
            float4 v = qkvF4[(long)(b * 2048 + tok) * 384 + 128 + h0 * 16 + f4p];
            short h0s = bf_hi(v.x), h1s = bf_hi(v.y), h2s = bf_hi(v.z), h3s = bf_hi(v.w);
            *(short4*)(Khi + rl * 136 + f4p * 4) = make_short4(h0s, h1s, h2s, h3s);
            *(short4*)(Klo + rl * 136 + f4p * 4) =
                make_short4(bf_hi(v.x - bf_f(h0s)), bf_hi(v.y - bf_f(h1s)),
                            bf_hi(v.z - bf_f(h2s)), bf_hi(v.w - bf_f(h3s)));
        }
        {
            int rq = t & 15;
            int dp = t >> 4;
            float4 va[4][2];
            #pragma unroll
            for (int i = 0; i < 4; i++) {
                int rank = c0 + rq * 4 + i;
                int tok = order[b * 2048 + min(rank, 2047)];
                long base = (long)(b * 2048 + tok) * 384 + 256 + h0 * 16 + dp * 2;
                va[i][0] = qkvF4[base];
                va[i][1] = qkvF4[base + 1];
            }
            #pragma unroll
            for (int j2 = 0; j2 < 2; j2++)
                #pragma unroll
                for (int c = 0; c < 4; c++) {
                    const float* f0 = (const float*)&va[0][j2];
                    const float* f1 = (const float*)&va[1][j2];
                    const float* f2 = (const float*)&va[2][j2];
                    const float* f3 = (const float*)&va[3][j2];
                    *(short4*)(Vt + (dp * 8 + j2 * 4 + c) * 88 + rq * 4) =
                        make_short4(bf_hi(f0[c]), bf_hi(f1[c]), bf_hi(f2[c]), bf_hi(f3[c]));
                }
        }
        __syncthreads();

        int cb = c0 + rh * 32;
        if (cb >= hi) continue;                  // wave-uniform
        int ch0 = cb >> 4;
        unsigned long long m0 = *(const unsigned long long*)(cm + ch0 * 16 + quad * 4);
        unsigned long long m1 = (ch0 + 1 < 128)
            ? *(const unsigned long long*)(cm + (ch0 + 1) * 16 + quad * 4) : 0ull;
        if (!__any((m0 | m1) != 0ull)) continue; // wave-uniform skip

        f32x4 S0 = (f32x4){0.f,0.f,0.f,0.f}, S1 = (f32x4){0.f,0.f,0.f,0.f};
        #pragma unroll
        for (int ks = 0; ks < 2; ks++) {
            const short* kb0 = Khi + (rh * 32 + key) * 136 + hs * 64 + ks * 32 + quad * 8;
            const short* kl0 = Klo + (rh * 32 + key) * 136 + hs * 64 + ks * 32 + quad * 8;
            const short* kb1 = kb0 + 16 * 136;
            const short* kl1 = kl0 + 16 * 136;
            bf16x8 b0h = *(const bf16x8*)kb0, b0l = *(const bf16x8*)kl0;
            bf16x8 b1h = *(const bf16x8*)kb1, b1l = *(const bf16x8*)kl1;
            S0 = __builtin_amdgcn_mfma_f32_16x16x32_bf16(qh[ks], b0h, S0, 0, 0, 0);
            S0 = __builtin_amdgcn_mfma_f32_16x16x32_bf16(qh[ks], b0l, S0, 0, 0, 0);
            S0 = __builtin_amdgcn_mfma_f32_16x16x32_bf16(ql[ks], b0h, S0, 0, 0, 0);
            S1 = __builtin_amdgcn_mfma_f32_16x16x32_bf16(qh[ks], b1h, S1, 0, 0, 0);
            S1 = __builtin_amdgcn_mfma_f32_16x16x32_bf16(qh[ks], b1l, S1, 0, 0, 0);
            S1 = __builtin_amdgcn_mfma_f32_16x16x32_bf16(ql[ks], b1h, S1, 0, 0, 0);
        }
        float s0[4], s1[4], p0[4], p1[4];
        unsigned bit0[4], bit1[4];
        #pragma unroll
        for (int r = 0; r < 4; r++) {
            bit0[r] = (unsigned)((m0 >> (r * 16 + key)) & 1);
            bit1[r] = (unsigned)((m1 >> (r * 16 + key)) & 1);
            s0[r] = bit0[r] ? S0[r] * 0.125f : -1e30f;
            s1[r] = bit1[r] ? S1[r] * 0.125f : -1e30f;
        }
        #pragma unroll
        for (int r = 0; r < 4; r++) {
            float cmax = fmaxf(s0[r], s1[r]);
            cmax = fmaxf(cmax, __shfl_xor(cmax, 1, 64));
            cmax = fmaxf(cmax, __shfl_xor(cmax, 2, 64));
            cmax = fmaxf(cmax, __shfl_xor(cmax, 4, 64));
            cmax = fmaxf(cmax, __shfl_xor(cmax, 8, 64));
            float mn = fmaxf(mrow[r], cmax);
            float alpha = __expf(mrow[r] - mn);
            mrow[r] = mn;
            p0[r] = bit0[r] ? __expf(s0[r] - mn) : 0.f;
            p1[r] = bit1[r] ? __expf(s1[r] - mn) : 0.f;
            float rs = p0[r] + p1[r];
            rs += __shfl_xor(rs, 1, 64);
            rs += __shfl_xor(rs, 2, 64);
            rs += __shfl_xor(rs, 4, 64);
            rs += __shfl_xor(rs, 8, 64);
            lrow[r] = lrow[r] * alpha + rs;
            #pragma unroll
            for (int nt = 0; nt < 4; nt++) Ont[nt][r] *= alpha;
        }
        #pragma unroll
        for (int r = 0; r < 4; r++) {
            short ha = bf_hi(p0[r]);
            PtH[(quad * 4 + r) * 40 + key] = ha;
            PtL[(quad * 4 + r) * 40 + key] = bf_hi(p0[r] - bf_f(ha));
            short hb = bf_hi(p1[r]);
            PtH[(quad * 4 + r) * 40 + 16 + key] = hb;
            PtL[(quad * 4 + r) * 40 + 16 + key] = bf_hi(p1[r] - bf_f(hb));
        }
        bf16x8 pfh = *(const bf16x8*)(PtH + key * 40 + quad * 8);
        bf16x8 pfl = *(const bf16x8*)(PtL + key * 40 + quad * 8);
        #pragma unroll
        for (int nt = 0; nt < 4; nt++) {
            bf16x8 vf = *(const bf16x8*)(Vt + (hs * 64 + nt * 16 + key) * 88
                                         + rh * 32 + quad * 8);
            Ont[nt] = __builtin_amdgcn_mfma_f32_16x16x32_bf16(pfh, vf, Ont[nt], 0, 0, 0);
            Ont[nt] = __builtin_amdgcn_mfma_f32_16x16x32_bf16(pfl, vf, Ont[nt], 0, 0, 0);
        }
    }

    if (key == 0) {
        #pragma unroll
        for (int r = 0; r < 4; r++)
            ml[(rh * 2 + hs) * 16 + quad * 4 + r] = make_float2(mrow[r], lrow[r]);
    }
    __syncthreads();
    #pragma unroll
    for (int nt = 0; nt < 4; nt++)
        #pragma unroll
        for (int r = 0; r < 4; r++)
            Opart[rh * 2048 + (quad * 4 + r) * 128 + hs * 64 + nt * 16 + key] = Ont[nt][r];
    __syncthreads();

    {
        int q = t >> 4, hs2 = (t >> 3) & 1, ds = t & 7;
        float2 a = ml[(0 * 2 + hs2) * 16 + q];
        float2 c = ml[(1 * 2 + hs2) * 16 + q];
        float M = fmaxf(a.x, c.x);
        float w0 = __expf(a.x - M), w1 = __expf(c.x - M);
        float denom = a.y * w0 + c.y * w1;
        float inv = 1.0f / fmaxf(denom, 1e-37f);
        long off = (long)(b * 2048 + sh_tok[q]) * P_DIM + (h0 + hs2) * HD + ds * 8;
        short hsv[8], lsv[8];
        #pragma unroll
        for (int j = 0; j < 8; j++) {
            int d = hs2 * 64 + ds * 8 + j;
            float o = (Opart[q * 128 + d] * w0 + Opart[2048 + q * 128 + d] * w1) * inv;
            hsv[j] = bf_hi(o);
            lsv[j] = bf_hi(o - bf_f(hsv[j]));
        }
        *(short4*)(attn_h + off)     = make_short4(hsv[0], hsv[1], hsv[2], hsv[3]);
        *(short4*)(attn_h + off + 4) = make_short4(hsv[4], hsv[5], hsv[6], hsv[7]);
        *(short4*)(attn_l + off)     = make_short4(lsv[0], lsv[1], lsv[2], lsv[3]);
        *(short4*)(attn_l + off + 4) = make_short4(lsv[4], lsv[5], lsv[6], lsv[7]);
    }
}

// ---------------- K9: pooled partial sums (atomic) --------------------------
__global__ __launch_bounds__(256) void k_pool(const float* __restrict__ zatt,
                                              float* __restrict__ pooled) {
    int b = blockIdx.y, chunk = blockIdx.x, t = threadIdx.x;
    float a0 = 0.f, a1 = 0.f;
    for (int s = 0; s < 16; s++) {
        long row = ((long)b * S_LEN + chunk * 16 + s) * P_DIM;
        a0 += zatt[row + t];
        a1 += zatt[row + t + 256];
    }
    atomicAdd(&pooled[b * P_DIM + t], a0);
    atomicAdd(&pooled[b * P_DIM + t + 256], a1);
}

// ---------------- Expert stage 1: h = pooled/S @ w1 + b1 (all 3 experts) ----
__global__ __launch_bounds__(256) void k_exp_fc1(const float* __restrict__ pooled,
                                                 const float* __restrict__ w1_0, const float* __restrict__ b1_0,
                                                 const float* __restrict__ w1_1, const float* __restrict__ b1_1,
                                                 const float* __restrict__ w1_2, const float* __restrict__ b1_2,
                                                 float* __restrict__ h) {
    int t = threadIdx.x, b = blockIdx.y;
    int c = blockIdx.x * 256 + t;  // [0, 1792)
    __shared__ float pl[P_DIM];
    pl[t]       = pooled[b * P_DIM + t]       * (1.0f / S_LEN);
    pl[t + 256] = pooled[b * P_DIM + t + 256] * (1.0f / S_LEN);
    __syncthreads();

    const float* wp; const float* bp; int s2, j;
    if (c < 256)      { wp = w1_0; bp = b1_0; s2 = 256;  j = c; }
    else if (c < 768) { wp = w1_1; bp = b1_1; s2 = 512;  j = c - 256; }
    else              { wp = w1_2; bp = b1_2; s2 = 1024; j = c - 768; }

    const float* p = wp + j;
    float acc = 0.f;
    #pragma unroll 16
    for (int k = 0; k < P_DIM; k++) {
        acc = fmaf(pl[k], *p, acc);
        p += s2;
    }
    h[(long)b * 1792 + c] = acc + bp[j];
}

// ---------------- Expert stage 2: LN + gelu per (expert, batch) -------------
__global__ __launch_bounds__(256) void k_exp_ln(float* __restrict__ h,
                                                const float* __restrict__ g0, const float* __restrict__ bb0,
                                                const float* __restrict__ g1, const float* __restrict__ bb1,
                                                const float* __restrict__ g2, const float* __restrict__ bb2) {
    int e = blockIdx.x, b = blockIdx.y, t = threadIdx.x;
    __shared__ float sm4[4];
    const int offs[3] = {0, 256, 768};
    const int ns[3]   = {256, 512, 1024};
    const float* gs[3]  = {g0, g1, g2};
    const float* bbs[3] = {bb0, bb1, bb2};
    int n = ns[e];
    float* hp = h + (long)b * 1792 + offs[e];
    const float* g = gs[e]; const float* bb = bbs[e];

    float x[4];
    float loc = 0.f;
    for (int u = 0; u < 4; u++) {
        int j = t + u * 256;
        x[u] = (j < n) ? hp[j] : 0.f;
        loc += x[u];
    }
    float mu = block_reduce_sum(loc, sm4) / (float)n;
    loc = 0.f;
    for (int u = 0; u < 4; u++) {
        int j = t + u * 256;
        if (j < n) { float d = x[u] - mu; loc += d * d; }
    }
    float var = block_reduce_sum(loc, sm4) / (float)n;
    float rs = 1.0f / sqrtf(var + 1e-5f);
    for (int u = 0; u < 4; u++) {
        int j = t + u * 256;
        if (j < n) hp[j] = gelu_exact((x[u] - mu) * rs * g[j] + bb[j]);
    }
}

// ---------------- Expert stage 3: out = h @ w2 + b2 (all 3 experts) ---------
__global__ __launch_bounds__(256) void k_exp_fc2(const float* __restrict__ h,
                                                 const float* __restrict__ w2_0, const float* __restrict__ b2_0,
                                                 const float* __restrict__ w2_1, const float* __restrict__ b2_1,
                                                 const float* __restrict__ w2_2, const float* __restrict__ b2_2,
                                                 float* __restrict__ out) {
    int t = threadIdx.x, b = blockIdx.y;
    int c = blockIdx.x * 256 + t;  // [0, 1024), valid < 896
    __shared__ float hs[1792];
    for (int u = 0; u < 7; u++) hs[t + u * 256] = h[(long)b * 1792 + t + u * 256];
    __syncthreads();
    if (c >= 896) return;

    const float* wp; const float* bp; int s2, sN, j, off_h;
    if (c < 128)      { wp = w2_0; bp = b2_0; s2 = 256;  sN = 128; j = c;       off_h = 0; }
    else if (c < 384) { wp = w2_1; bp = b2_1; s2 = 512;  sN = 256; j = c - 128; off_h = 256; }
    else              { wp = w2_2; bp = b2_2; s2 = 1024; sN = 512; j = c - 384; off_h = 768; }

    const float* p = wp + j;
    const float* hh = hs + off_h;
    float acc = 0.f;
    #pragma unroll 16
    for (int k = 0; k < s2; k++) {
        acc = fmaf(hh[k], *p, acc);
        p += sN;
    }
    out[b * 896 + c] = acc + bp[j];
}

// ---------------------------------------------------------------------------
extern "C" void kernel_launch(void* const* d_in, const int* in_sizes, int n_in,
                              void* d_out, int out_size, void* d_ws, size_t ws_size,
                              hipStream_t stream) {
    const float* seq   = (const float*)d_in[0];
    const float* penta = (const float*)d_in[1];
    const float* spos  = (const float*)d_in[2];
    const float* projW = (const float*)d_in[3];
    const float* projb = (const float*)d_in[4];
    const float* lng   = (const float*)d_in[5];
    const float* lnb   = (const float*)d_in[6];
    const float* qkvW  = (const float*)d_in[7];
    const float* qkvb  = (const float*)d_in[8];
    const float* outW  = (const float*)d_in[9];
    const float* outb  = (const float*)d_in[10];

    float* ws      = (float*)d_ws;
    float* z_pre   = ws;                      // 2097152 floats (zatt alias)
    short* z_h     = (short*)(z_pre + 2097152); // 2097152 shorts (attn_h alias)
    short* z_l     = z_h + 2097152;           // 2097152 shorts (attn_l alias)
    float* qkv     = (float*)(z_l + 2097152); // 6291456 floats
    float* pos     = qkv + 6291456;           // 4096 (unused, layout keep)
    float* pooled  = pos + 4096;              // 1024
    float* hbuf    = pooled + 1024;           // 4096
    unsigned long long* rowkey = (unsigned long long*)(hbuf + 4096);  // 4096 ull
    float* pos_srt = (float*)(rowkey + 4096); // 4096
    int*   order   = (int*)(pos_srt + 4096);  // 4096
    uint2* bounds  = (uint2*)(order + 4096);  // 4096 uint2
    unsigned long long* bmG = (unsigned long long*)(bounds + 4096); // 131072 ull
    short* cent_h  = (short*)(bmG + 131072);  // 524288 shorts
    short* cent_l  = cent_h + 524288;
    short* pjWT_h  = cent_l + 524288;         // 512x1024
    short* pjWT_l  = pjWT_h + 524288;
    short* qkWT_h  = pjWT_l + 524288;         // 1536x512
    short* qkWT_l  = qkWT_h + 786432;
    short* owWT_h  = qkWT_l + 786432;         // 512x512
    short* owWT_l  = owWT_h + 262144;
    short* attn_h  = z_h;     // z_h/z_l dead after anchor+qkv GEMMs
    short* attn_l  = z_l;
    float* zatt    = z_pre;   // z_pre dead after ln_gelu

    // weight prep
    k_cent<<<1024, 256, 0, stream>>>(penta, cent_h, cent_l);
    { dim3 g(16, 8);  k_wt<IN_DIM, P_DIM><<<g, 256, 0, stream>>>(projW, pjWT_h, pjWT_l); }
    { dim3 g(8, 24);  k_wt<P_DIM, 3 * P_DIM><<<g, 256, 0, stream>>>(qkvW, qkWT_h, qkWT_l); }
    { dim3 g(8, 8);   k_wt<P_DIM, P_DIM><<<g, 256, 0, stream>>>(outW, owWT_h, owWT_l); }

    // proj -> ln/gelu/norm (emits pre-split z)
    { dim3 g(32, 4);  k_mm<IN_DIM, P_DIM, 0, false><<<g, 256, 0, stream>>>(
          seq, nullptr, nullptr, pjWT_h, pjWT_l, projb, z_pre, nullptr); }
    k_ln_gelu_norm<<<4096, 256, 0, stream>>>(z_pre, lng, lnb, z_h, z_l);

    // anchor argmax -> sort (fused position gather)
    hipMemsetAsync(rowkey, 0, 4096 * sizeof(unsigned long long), stream);
    { dim3 g(32, 8);  k_mm<P_DIM, 1024, 1, true><<<g, 256, 0, stream>>>(
          nullptr, z_h, z_l, cent_h, cent_l, nullptr, nullptr, rowkey); }
    k_sort<<<2, 256, 0, stream>>>(rowkey, spos, order, pos_srt);

    // qkv -> routes(bitmap) -> attention (emits pre-split) -> out-proj
    { dim3 g(32, 12); k_mm<P_DIM, 3 * P_DIM, 0, true><<<g, 256, 0, stream>>>(
          nullptr, z_h, z_l, qkWT_h, qkWT_l, qkvb, qkv, nullptr); }
    k_routes<<<1024, 256, 0, stream>>>(pos_srt, order, bmG, bounds);
    k_attn<<<1024, 256, 0, stream>>>(qkv, order, bmG, bounds, attn_h, attn_l);
    { dim3 g(32, 4);  k_mm<P_DIM, P_DIM, 0, true><<<g, 256, 0, stream>>>(
          nullptr, attn_h, attn_l, owWT_h, owWT_l, outb, zatt, nullptr); }

    // pool + experts
    hipMemsetAsync(pooled, 0, 1024 * sizeof(float), stream);
    { dim3 pg(128, 2); k_pool<<<pg, 256, 0, stream>>>(zatt, pooled); }

    dim3 g1(7, 2);
    k_exp_fc1<<<g1, 256, 0, stream>>>(pooled,
        (const float*)d_in[11], (const float*)d_in[12],
        (const float*)d_in[17], (const float*)d_in[18],
        (const float*)d_in[23], (const float*)d_in[24], hbuf);
    dim3 g2(3, 2);
    k_exp_ln<<<g2, 256, 0, stream>>>(hbuf,
        (const float*)d_in[13], (const float*)d_in[14],
        (const float*)d_in[19], (const float*)d_in[20],
        (const float*)d_in[25], (const float*)d_in[26]);
    dim3 g3(4, 2);
    k_exp_fc2<<<g3, 256, 0, stream>>>(hbuf,
        (const float*)d_in[15], (const float*)d_in[16],
        (const float*)d_in[21], (const float*)d_in[22],
        (const float*)d_in[27], (const float*)d_in[28], (float*)d_out);
}

// Round 12
// 403.130 us; speedup vs baseline: 3.6403x; 1.0930x over previous
//
#include <hip/hip_runtime.h>
#include <math.h>

#define DEV __device__ __forceinline__

static constexpr int S_LEN  = 2048;
static constexpr int IN_DIM = 1024;
static constexpr int P_DIM  = 512;
static constexpr int NHEAD  = 8;
static constexpr int HD     = 64;
static constexpr int KN     = 128;

typedef __attribute__((ext_vector_type(8))) short bf16x8;
typedef __attribute__((ext_vector_type(4))) float f32x4;

DEV float gelu_exact(float x) {
    return 0.5f * x * (1.0f + erff(x * 0.70710678118654752440f));
}

// float -> bf16 (RNE), and the split residual helpers
DEV short bf_hi(float x) {
    unsigned u = __float_as_uint(x);
    unsigned r = (u + 0x7fffu + ((u >> 16) & 1u)) >> 16;
    return (short)r;
}
DEV float bf_f(short h) { return __uint_as_float(((unsigned)(unsigned short)h) << 16); }

// 256-thread block sum reduction. sm4 must be float[4] shared.
DEV float block_reduce_sum(float v, float* sm4) {
    #pragma unroll
    for (int off = 32; off; off >>= 1) v += __shfl_down(v, off, 64);
    int lane = threadIdx.x & 63, w = threadIdx.x >> 6;
    __syncthreads();
    if (lane == 0) sm4[w] = v;
    __syncthreads();
    return sm4[0] + sm4[1] + sm4[2] + sm4[3];
}

// ---------------- K1: centroids, L2-normalized, split-bf16 [p][d] -----------
__global__ __launch_bounds__(256) void k_cent(const float* __restrict__ penta,
                                              short* __restrict__ ch,
                                              short* __restrict__ cl) {
    int p = blockIdx.x, t = threadIdx.x;
    __shared__ float sm4[4];
    float c0 = 0.f, c1 = 0.f;
    #pragma unroll
    for (int v = 0; v < 5; v++) {
        const float* row = penta + ((long)p * 5 + v) * P_DIM;
        c0 += row[t];
        c1 += row[t + 256];
    }
    c0 /= 5.0f; c1 /= 5.0f;
    float tot = block_reduce_sum(c0 * c0 + c1 * c1, sm4);
    float n = fmaxf(sqrtf(tot), 1e-12f);
    float v0 = c0 / n, v1 = c1 / n;
    short h0 = bf_hi(v0), h1 = bf_hi(v1);
    ch[p * P_DIM + t]       = h0;
    ch[p * P_DIM + t + 256] = h1;
    cl[p * P_DIM + t]       = bf_hi(v0 - bf_f(h0));
    cl[p * P_DIM + t + 256] = bf_hi(v1 - bf_f(h1));
}

// ---------------- weight transpose + split: W (K x N) -> WT_hi/lo (N x K) ---
template <int K, int N>
__global__ __launch_bounds__(256) void k_wt(const float* __restrict__ W,
                                            short* __restrict__ WTh,
                                            short* __restrict__ WTl) {
    __shared__ float tile[64][65];
    int bk = blockIdx.x, bn = blockIdx.y;
    int t = threadIdx.x;
    int c = t & 63, r4 = t >> 6;
    #pragma unroll
    for (int i = 0; i < 16; i++) {
        int row = r4 + i * 4;
        tile[row][c] = W[(long)(bk * 64 + row) * N + bn * 64 + c];
    }
    __syncthreads();
    #pragma unroll
    for (int i = 0; i < 16; i++) {
        int n = r4 + i * 4;
        float v = tile[c][n];
        short h = bf_hi(v);
        long o = (long)(bn * 64 + n) * K + bk * 64 + c;
        WTh[o] = h;
        WTl[o] = bf_hi(v - bf_f(h));
    }
}

// ---------------- MFMA split-bf16 GEMM: C = A@W + bias ----------------------
// BM x 128 block tile (BK=32), 4 waves in 2x2, wave tile (BM/2) x 64.
// Accumulation order per output element identical to the BM=128 original ->
// bit-identical results; BM=64 doubles the grid for occupancy.
template <int BM, int K, int N, int EPI, bool SPLITA>
__global__ __launch_bounds__(256) void k_mm(const float* __restrict__ Af,
                                            const short* __restrict__ Ash,
                                            const short* __restrict__ Asl,
                                            const short* __restrict__ BTh,
                                            const short* __restrict__ BTl,
                                            const float* __restrict__ bias,
                                            float* __restrict__ C,
                                            unsigned long long* __restrict__ rowkey) {
    constexpr int TI = BM / 32;   // i-tiles (of 16 rows) per wave
    __shared__ short Ah[BM * 40], Al[BM * 40], Bh[128 * 40], Bl[128 * 40];
    int t = threadIdx.x;
    int lane = t & 63, wave = t >> 6;
    int wr = (wave >> 1) * (BM / 2), wc = (wave & 1) * 64;
    int m = lane & 15, quad = lane >> 4;
    int rb = blockIdx.x * BM, cb = blockIdx.y * 128;

    f32x4 acc[TI][4];
    #pragma unroll
    for (int i = 0; i < TI; i++)
        #pragma unroll
        for (int j = 0; j < 4; j++) acc[i][j] = (f32x4){0.f, 0.f, 0.f, 0.f};

    for (int k0 = 0; k0 < K; k0 += 32) {
        __syncthreads();
        if constexpr (SPLITA) {
            #pragma unroll
            for (int ps = 0; ps < BM / 64; ps++) {
                int idx = t + ps * 256;       // 0..BM*4-1
                int row = idx >> 2, c4 = idx & 3;
                *(float4*)(Ah + row * 40 + c4 * 8) =
                    *(const float4*)(Ash + (long)(rb + row) * K + k0 + c4 * 8);
                *(float4*)(Al + row * 40 + c4 * 8) =
                    *(const float4*)(Asl + (long)(rb + row) * K + k0 + c4 * 8);
            }
        } else {
            #pragma unroll
            for (int ps = 0; ps < BM / 32; ps++) {
                int row = (t >> 3) + ps * 32;
                int seg = t & 7;
                float4 v = *(const float4*)(Af + (long)(rb + row) * K + k0 + seg * 4);
                short h0 = bf_hi(v.x), h1 = bf_hi(v.y), h2 = bf_hi(v.z), h3 = bf_hi(v.w);
                short l0 = bf_hi(v.x - bf_f(h0)), l1 = bf_hi(v.y - bf_f(h1));
                short l2 = bf_hi(v.z - bf_f(h2)), l3 = bf_hi(v.w - bf_f(h3));
                *(short4*)(Ah + row * 40 + seg * 4) = make_short4(h0, h1, h2, h3);
                *(short4*)(Al + row * 40 + seg * 4) = make_short4(l0, l1, l2, l3);
            }
        }
        #pragma unroll
        for (int ps = 0; ps < 2; ps++) {
            int row = (t >> 2) + ps * 64;
            int seg = t & 3;
            *(float4*)(Bh + row * 40 + seg * 8) =
                *(const float4*)(BTh + (long)(cb + row) * K + k0 + seg * 8);
            *(float4*)(Bl + row * 40 + seg * 8) =
                *(const float4*)(BTl + (long)(cb + row) * K + k0 + seg * 8);
        }
        __syncthreads();

        bf16x8 ah[TI], al[TI], bh[4], bl[4];
        #pragma unroll
        for (int i = 0; i < TI; i++) {
            ah[i] = *(const bf16x8*)(Ah + (wr + i * 16 + m) * 40 + quad * 8);
            al[i] = *(const bf16x8*)(Al + (wr + i * 16 + m) * 40 + quad * 8);
        }
        #pragma unroll
        for (int j = 0; j < 4; j++) {
            bh[j] = *(const bf16x8*)(Bh + (wc + j * 16 + m) * 40 + quad * 8);
            bl[j] = *(const bf16x8*)(Bl + (wc + j * 16 + m) * 40 + quad * 8);
        }
        #pragma unroll
        for (int i = 0; i < TI; i++)
            #pragma unroll
            for (int j = 0; j < 4; j++) {
                acc[i][j] = __builtin_amdgcn_mfma_f32_16x16x32_bf16(ah[i], bh[j], acc[i][j], 0, 0, 0);
                acc[i][j] = __builtin_amdgcn_mfma_f32_16x16x32_bf16(ah[i], bl[j], acc[i][j], 0, 0, 0);
                acc[i][j] = __builtin_amdgcn_mfma_f32_16x16x32_bf16(al[i], bh[j], acc[i][j], 0, 0, 0);
            }
    }

    if (EPI == 0) {
        #pragma unroll
        for (int i = 0; i < TI; i++) {
            int gr0 = rb + wr + i * 16 + quad * 4;
            #pragma unroll
            for (int j = 0; j < 4; j++) {
                int gc = cb + wc + j * 16 + m;
                float bv = bias[gc];
                #pragma unroll
                for (int r = 0; r < 4; r++)
                    C[(long)(gr0 + r) * N + gc] = acc[i][j][r] + bv;
            }
        }
    } else {
        #pragma unroll
        for (int i = 0; i < TI; i++) {
            #pragma unroll
            for (int r = 0; r < 4; r++) {
                int gr = rb + wr + i * 16 + quad * 4 + r;
                float bv = acc[i][0][r];
                int bp = cb + wc + m;
                #pragma unroll
                for (int j = 1; j < 4; j++) {
                    float v = acc[i][j][r];
                    int p = cb + wc + j * 16 + m;   // ascending; > keeps lowest p
                    if (v > bv) { bv = v; bp = p; }
                }
                #pragma unroll
                for (int off = 1; off < 16; off <<= 1) {
                    float ov = __shfl_xor(bv, off, 64);
                    int op = __shfl_xor(bp, off, 64);
                    if (ov > bv || (ov == bv && op < bp)) { bv = ov; bp = op; }
                }
                if (m == 0) {
                    unsigned u = __float_as_uint(bv);
                    u = (u & 0x80000000u) ? ~u : (u | 0x80000000u);
                    unsigned long long key =
                        ((unsigned long long)u << 32) | (unsigned)(0xFFFFFFFFu - (unsigned)bp);
                    atomicMax(&rowkey[gr], key);
                }
            }
        }
    }
}

// ---------------- K3: LayerNorm -> gelu -> L2 norm -> emit SPLIT bf16 -------
__global__ __launch_bounds__(256) void k_ln_gelu_norm(const float* __restrict__ Zin,
                                                      const float* __restrict__ g,
                                                      const float* __restrict__ b,
                                                      short* __restrict__ z_h,
                                                      short* __restrict__ z_l) {
    long row = blockIdx.x;
    int t = threadIdx.x;
    __shared__ float sm4[4];
    float x0 = Zin[row * P_DIM + t], x1 = Zin[row * P_DIM + t + 256];
    float mu = block_reduce_sum(x0 + x1, sm4) * (1.0f / P_DIM);
    float d0 = x0 - mu, d1 = x1 - mu;
    float var = block_reduce_sum(d0 * d0 + d1 * d1, sm4) * (1.0f / P_DIM);
    float rs = 1.0f / sqrtf(var + 1e-5f);
    float y0 = gelu_exact(d0 * rs * g[t] + b[t]);
    float y1 = gelu_exact(d1 * rs * g[t + 256] + b[t + 256]);
    float nn = block_reduce_sum(y0 * y0 + y1 * y1, sm4);
    float n = fmaxf(sqrtf(nn), 1e-12f);
    float v0 = y0 / n, v1 = y1 / n;
    short h0 = bf_hi(v0), h1 = bf_hi(v1);
    z_h[row * P_DIM + t]       = h0;
    z_h[row * P_DIM + t + 256] = h1;
    z_l[row * P_DIM + t]       = bf_hi(v0 - bf_f(h0));
    z_l[row * P_DIM + t + 256] = bf_hi(v1 - bf_f(h1));
}

// ---------------- K5: bitonic argsort (fused rowkey->pos gather) ------------
__global__ __launch_bounds__(256) void k_sort(const unsigned long long* __restrict__ rowkey,
                                              const float* __restrict__ spos,
                                              int* __restrict__ order,
                                              float* __restrict__ pos_srt) {
    int b = blockIdx.x, t = threadIdx.x;
    __shared__ unsigned long long key[2048];
    for (int u = 0; u < 8; u++) {
        int i = t + u * 256;
        unsigned p = 0xFFFFFFFFu - (unsigned)(rowkey[b * 2048 + i] & 0xFFFFFFFFull);
        float pv = spos[p];
        key[i] = (((unsigned long long)__float_as_uint(pv)) << 32) | (unsigned)i;
    }
    __syncthreads();
    for (int k = 2; k <= 2048; k <<= 1) {
        for (int j = k >> 1; j > 0; j >>= 1) {
            for (int u = 0; u < 8; u++) {
                int i = t + u * 256;
                int l = i ^ j;
                if (l > i) {
                    bool up = ((i & k) == 0);
                    unsigned long long a = key[i], c = key[l];
                    if ((a > c) == up) { key[i] = c; key[l] = a; }
                }
            }
            __syncthreads();
        }
    }
    for (int u = 0; u < 8; u++) {
        int r = t + u * 256;
        unsigned long long kk = key[r];
        order[b * 2048 + r]   = (int)(kk & 0xffffffffu);
        pos_srt[b * 2048 + r] = __uint_as_float((unsigned)(kk >> 32));
    }
}

// ---------------- K6: exact top-128, one WAVE per query ---------------------
__global__ __launch_bounds__(256) void k_routes(const float* __restrict__ pos_srt,
                                                const int* __restrict__ order,
                                                unsigned long long* __restrict__ bmG,
                                                uint2* __restrict__ bounds) {
    int blk = blockIdx.x;                 // 1024 blocks, 4 queries (waves) each
    int b = blk >> 9;
    int t = threadIdx.x;
    int lane = t & 63, wave = t >> 6;
    int r = (blk & 511) * 4 + wave;       // query rank in [0,2048)
    __shared__ float ps[2048];
    __shared__ unsigned short tk[2048];
    for (int u = 0; u < 8; u++) {
        int i = t + u * 256;
        ps[i] = pos_srt[b * 2048 + i];
        tk[i] = (unsigned short)order[b * 2048 + i];
    }
    __syncthreads();

    float pi = ps[r];
    float T = 3e38f;
    #pragma unroll
    for (int a2 = 0; a2 < 2; a2++) {
        int a = lane + a2 * 64;           // 0..127
        int jl = r - a, jr = r + 127 - a;
        if (jl >= 0 && jr <= 2047) {
            float dl = (a > 0)   ? (pi - ps[jl]) : 0.f;
            float dr = (a < 127) ? (ps[jr] - pi) : 0.f;
            T = fminf(T, fmaxf(dl, dr));
        }
    }
    #pragma unroll
    for (int off = 1; off < 64; off <<= 1) T = fminf(T, __shfl_xor(T, off, 64));

    int lo = 0, hi = r;
    while (lo < hi) { int mid = (lo + hi) >> 1; if (pi - ps[mid] <= T) hi = mid; else lo = mid + 1; }
    int mn = lo;
    lo = r; hi = 2047;
    while (lo < hi) { int mid = (lo + hi + 1) >> 1; if (ps[mid] - pi <= T) lo = mid; else hi = mid - 1; }
    int mx = lo;
    int Ls, Rs;
    if (T > 0.f) {
        lo = 0; hi = r;
        while (lo < hi) { int mid = (lo + hi) >> 1; if (pi - ps[mid] < T) hi = mid; else lo = mid + 1; }
        Ls = lo;
        lo = r; hi = 2047;
        while (lo < hi) { int mid = (lo + hi + 1) >> 1; if (ps[mid] - pi < T) lo = mid; else hi = mid - 1; }
        Rs = lo;
    } else { Ls = r + 1; Rs = r - 1; }

    int cnt_strict = (Rs >= Ls) ? (Rs - Ls + 1) : 0;
    int need = 128 - cnt_strict;
    int l0a, l0b, r0a, r0b;
    if (cnt_strict > 0) { l0a = mn; l0b = Ls - 1; r0a = Rs + 1; r0b = mx; }
    else                { l0a = mn; l0b = mx;     r0a = 1;      r0b = 0; }
    int nL = (l0b >= l0a) ? (l0b - l0a + 1) : 0;
    int nR = (r0b >= r0a) ? (r0b - r0a + 1) : 0;
    int tiecount = nL + nR;

    int X = 65535;
    if (need < tiecount) {
        int lo2 = 0, hi2 = 2047;
        while (lo2 < hi2) {
            int mid = (lo2 + hi2) >> 1;
            int cnt = 0;
            for (int e = lane; e < tiecount; e += 64) {
                int j = (e < nL) ? (l0a + e) : (r0a + e - nL);
                cnt += (tk[j] <= mid) ? 1 : 0;
            }
            #pragma unroll
            for (int off = 1; off < 64; off <<= 1) cnt += __shfl_xor(cnt, off, 64);
            if (cnt >= need) hi2 = mid; else lo2 = mid + 1;
        }
        X = lo2;
    }

    int qlo_loc = 1 << 30, qhi_loc = -1;
    if (lane < 32) {
        unsigned long long bits = 0;
        int j0 = lane << 6, j1 = j0 + 63;
        if (cnt_strict > 0) {
            int a0 = max(Ls, j0), a1 = min(Rs, j1);
            if (a0 <= a1) {
                int s = a0 - j0, e = a1 - j0;
                unsigned long long msk = (e - s == 63) ? ~0ull
                                       : (((1ull << (e - s + 1)) - 1) << s);
                bits |= msk;
            }
        }
        int a0 = max(l0a, j0), a1 = min(l0b, j1);
        for (int j = a0; j <= a1; j++) if (tk[j] <= X) bits |= 1ull << (j - j0);
        a0 = max(r0a, j0); a1 = min(r0b, j1);
        for (int j = a0; j <= a1; j++) if (tk[j] <= X) bits |= 1ull << (j - j0);
        if (bits) {
            qlo_loc = j0 + __builtin_ctzll(bits);
            qhi_loc = j0 + 63 - __builtin_clzll(bits);
        }
        bmG[((long)(b * 2048 + r)) * 32 + lane] = bits;
    }
    #pragma unroll
    for (int off = 1; off < 64; off <<= 1) {
        qlo_loc = min(qlo_loc, __shfl_xor(qlo_loc, off, 64));
        qhi_loc = max(qhi_loc, __shfl_xor(qhi_loc, off, 64));
    }
    if (lane == 0)
        bounds[b * 2048 + r] = make_uint2((unsigned)qlo_loc, (unsigned)qhi_loc);
}

// ---------------- K7: MFMA flash attention ----------------------------------
__global__ __launch_bounds__(256) void k_attn(const float* __restrict__ qkv,
                                              const int* __restrict__ order,
                                              const unsigned long long* __restrict__ bmG,
                                              const uint2* __restrict__ bounds,
                                              short* __restrict__ attn_h,
                                              short* __restrict__ attn_l) {
    __shared__ __align__(16) char smem[72320];
    short* Khi = (short*)smem;                              // 64 x 136 u16
    short* Klo = (short*)(smem + 17408);                    // 64 x 136
    short* Vt  = (short*)(smem + 34816);                    // 128 x 88
    short* Pt  = (short*)(smem + 57344);                    // 4 waves x 2 x 16x40
    unsigned short* cm = (unsigned short*)(smem + 67584);   // 128 x 16
    int* sh_tok = (int*)(smem + 71680);                     // 16
    int* sh_lohi = (int*)(smem + 71744);                    // 2
    float2* ml = (float2*)(smem + 71752);                   // [2][2][16]
    float* Opart = (float*)smem;                            // alias: [2][16][128]

    int gb = blockIdx.x;
    int b  = gb >> 9;
    int qg = (gb >> 2) & 127;
    int hp = gb & 3;
    int h0 = hp * 2;
    int r0 = qg * 16;
    int t = threadIdx.x;
    int lane = t & 63, wave = t >> 6;
    int rh = wave & 1, hs = wave >> 1;
    int key = lane & 15, quad = lane >> 4;

    const float4* qkvF4 = (const float4*)qkv;

    if (t < 16) sh_tok[t] = order[b * 2048 + r0 + t];
    if (t == 0) { sh_lohi[0] = 1 << 30; sh_lohi[1] = 0; }
    #pragma unroll
    for (int u = 0; u < 8; u++) {
        int e = t + u * 256;
        int c = e >> 4, q = e & 15;
        cm[c * 16 + q] = (unsigned short)(
            (bmG[((long)(b * 2048 + r0 + q)) * 32 + (c >> 2)] >> ((c & 3) * 16)) & 0xFFFF);
    }
    __syncthreads();
    if (t < 16) {
        uint2 bd = bounds[b * 2048 + r0 + t];
        atomicMin(&sh_lohi[0], (int)bd.x);
        atomicMax(&sh_lohi[1], (int)bd.y);
    }

    bf16x8 qh[2], ql[2];
    {
        long tq = (long)(b * 2048 + sh_tok[key]) * 384;
        #pragma unroll
        for (int ks = 0; ks < 2; ks++) {
            float4 v0 = qkvF4[tq + (h0 + hs) * 16 + ks * 8 + quad * 2];
            float4 v1 = qkvF4[tq + (h0 + hs) * 16 + ks * 8 + quad * 2 + 1];
            float vv[8] = {v0.x, v0.y, v0.z, v0.w, v1.x, v1.y, v1.z, v1.w};
            #pragma unroll
            for (int j = 0; j < 8; j++) {
                short hb = bf_hi(vv[j]);
                qh[ks][j] = hb;
                ql[ks][j] = bf_hi(vv[j] - bf_f(hb));
            }
        }
    }
    __syncthreads();
    int lo = sh_lohi[0] & ~63, hi = sh_lohi[1] + 1;

    float mrow[4], lrow[4];
    f32x4 Ont[4];
    #pragma unroll
    for (int r = 0; r < 4; r++) { mrow[r] = -1e30f; lrow[r] = 0.f; }
    #pragma unroll
    for (int nt = 0; nt < 4; nt++) Ont[nt] = (f32x4){0.f, 0.f, 0.f, 0.f};

    short* PtH = Pt + wave * 1280;
    short* PtL = PtH + 640;

    for (int c0 = lo; c0 < hi; c0 += 64) {
        __syncthreads();
        #pragma unroll
        for (int u = 0; u < 8; u++) {
            int idx = t + u * 256;
            int rl = idx >> 5, f4p = idx & 31;
            int rank = c0 + rl;
            int tok = order[b * 2048 + min(rank, 2047)];
            float4 v = qkvF4[(long)(b * 2048 + tok) * 384 + 128 + h0 * 16 + f4p];
            short h0s = bf_hi(v.x), h1s = bf_hi(v.y), h2s = bf_hi(v.z), h3s = bf_hi(v.w);
            *(short4*)(Khi + rl * 136 + f4p * 4) = make_short4(h0s, h1s, h2s, h3s);
            *(short4*)(Klo + rl * 136 + f4p * 4) =
                make_short4(bf_hi(v.x - bf_f(h0s)), bf_hi(v.y - bf_f(h1s)),
                            bf_hi(v.z - bf_f(h2s)), bf_hi(v.w - bf_f(h3s)));
        }
        {
            int rq = t & 15;
            int dp = t >> 4;
            float4 va[4][2];
            #pragma unroll
            for (int i = 0; i < 4; i++) {
                int rank = c0 + rq * 4 + i;
                int tok = order[b * 2048 + min(rank, 2047)];
                long base = (long)(b * 2048 + tok) * 384 + 256 + h0 * 16 + dp * 2;
                va[i][0] = qkvF4[base];
                va[i][1] = qkvF4[base + 1];
            }
            #pragma unroll
            for (int j2 = 0; j2 < 2; j2++)
                #pragma unroll
                for (int c = 0; c < 4; c++) {
                    const float* f0 = (const float*)&va[0][j2];
                    const float* f1 = (const float*)&va[1][j2];
                    const float* f2 = (const float*)&va[2][j2];
                    const float* f3 = (const float*)&va[3][j2];
                    *(short4*)(Vt + (dp * 8 + j2 * 4 + c) * 88 + rq * 4) =
                        make_short4(bf_hi(f0[c]), bf_hi(f1[c]), bf_hi(f2[c]), bf_hi(f3[c]));
                }
        }
        __syncthreads();

        int cb = c0 + rh * 32;
        if (cb >= hi) continue;                  // wave-uniform
        int ch0 = cb >> 4;
        unsigned long long m0 = *(const unsigned long long*)(cm + ch0 * 16 + quad * 4);
        unsigned long long m1 = (ch0 + 1 < 128)
            ? *(const unsigned long long*)(cm + (ch0 + 1) * 16 + quad * 4) : 0ull;
        if (!__any((m0 | m1) != 0ull)) continue; // wave-uniform skip

        f32x4 S0 = (f32x4){0.f,0.f,0.f,0.f}, S1 = (f32x4){0.f,0.f,0.f,0.f};
        #pragma unroll
        for (int ks = 0; ks < 2; ks++) {
            const short* kb0 = Khi + (rh * 32 + key) * 136 + hs * 64 + ks * 32 + quad * 8;
            const short* kl0 = Klo + (rh * 32 + key) * 136 + hs * 64 + ks * 32 + quad * 8;
            const short* kb1 = kb0 + 16 * 136;
            const short* kl1 = kl0 + 16 * 136;
            bf16x8 b0h = *(const bf16x8*)kb0, b0l = *(const bf16x8*)kl0;
            bf16x8 b1h = *(const bf16x8*)kb1, b1l = *(const bf16x8*)kl1;
            S0 = __builtin_amdgcn_mfma_f32_16x16x32_bf16(qh[ks], b0h, S0, 0, 0, 0);
            S0 = __builtin_amdgcn_mfma_f32_16x16x32_bf16(qh[ks], b0l, S0, 0, 0, 0);
            S0 = __builtin_amdgcn_mfma_f32_16x16x32_bf16(ql[ks], b0h, S0, 0, 0, 0);
            S1 = __builtin_amdgcn_mfma_f32_16x16x32_bf16(qh[ks], b1h, S1, 0, 0, 0);
            S1 = __builtin_amdgcn_mfma_f32_16x16x32_bf16(qh[ks], b1l, S1, 0, 0, 0);
            S1 = __builtin_amdgcn_mfma_f32_16x16x32_bf16(ql[ks], b1h, S1, 0, 0, 0);
        }
        float s0[4], s1[4], p0[4], p1[4];
        unsigned bit0[4], bit1[4];
        #pragma unroll
        for (int r = 0; r < 4; r++) {
            bit0[r] = (unsigned)((m0 >> (r * 16 + key)) & 1);
            bit1[r] = (unsigned)((m1 >> (r * 16 + key)) & 1);
            s0[r] = bit0[r] ? S0[r] * 0.125f : -1e30f;
            s1[r] = bit1[r] ? S1[r] * 0.125f : -1e30f;
        }
        #pragma unroll
        for (int r = 0; r < 4; r++) {
            float cmax = fmaxf(s0[r], s1[r]);
            cmax = fmaxf(cmax, __shfl_xor(cmax, 1, 64));
            cmax = fmaxf(cmax, __shfl_xor(cmax, 2, 64));
            cmax = fmaxf(cmax, __shfl_xor(cmax, 4, 64));
            cmax = fmaxf(cmax, __shfl_xor(cmax, 8, 64));
            float mn = fmaxf(mrow[r], cmax);
            float alpha = __expf(mrow[r] - mn);
            mrow[r] = mn;
            p0[r] = bit0[r] ? __expf(s0[r] - mn) : 0.f;
            p1[r] = bit1[r] ? __expf(s1[r] - mn) : 0.f;
            float rs = p0[r] + p1[r];
            rs += __shfl_xor(rs, 1, 64);
            rs += __shfl_xor(rs, 2, 64);
            rs += __shfl_xor(rs, 4, 64);
            rs += __shfl_xor(rs, 8, 64);
            lrow[r] = lrow[r] * alpha + rs;
            #pragma unroll
            for (int nt = 0; nt < 4; nt++) Ont[nt][r] *= alpha;
        }
        #pragma unroll
        for (int r = 0; r < 4; r++) {
            short ha = bf_hi(p0[r]);
            PtH[(quad * 4 + r) * 40 + key] = ha;
            PtL[(quad * 4 + r) * 40 + key] = bf_hi(p0[r] - bf_f(ha));
            short hb = bf_hi(p1[r]);
            PtH[(quad * 4 + r) * 40 + 16 + key] = hb;
            PtL[(quad * 4 + r) * 40 + 16 + key] = bf_hi(p1[r] - bf_f(hb));
        }
        bf16x8 pfh = *(const bf16x8*)(PtH + key * 40 + quad * 8);
        bf16x8 pfl = *(const bf16x8*)(PtL + key * 40 + quad * 8);
        #pragma unroll
        for (int nt = 0; nt < 4; nt++) {
            bf16x8 vf = *(const bf16x8*)(Vt + (hs * 64 + nt * 16 + key) * 88
                                         + rh * 32 + quad * 8);
            Ont[nt] = __builtin_amdgcn_mfma_f32_16x16x32_bf16(pfh, vf, Ont[nt], 0, 0, 0);
            Ont[nt] = __builtin_amdgcn_mfma_f32_16x16x32_bf16(pfl, vf, Ont[nt], 0, 0, 0);
        }
    }

    if (key == 0) {
        #pragma unroll
        for (int r = 0; r < 4; r++)
            ml[(rh * 2 + hs) * 16 + quad * 4 + r] = make_float2(mrow[r], lrow[r]);
    }
    __syncthreads();
    #pragma unroll
    for (int nt = 0; nt < 4; nt++)
        #pragma unroll
        for (int r = 0; r < 4; r++)
            Opart[rh * 2048 + (quad * 4 + r) * 128 + hs * 64 + nt * 16 + key] = Ont[nt][r];
    __syncthreads();

    {
        int q = t >> 4, hs2 = (t >> 3) & 1, ds = t & 7;
        float2 a = ml[(0 * 2 + hs2) * 16 + q];
        float2 c = ml[(1 * 2 + hs2) * 16 + q];
        float M = fmaxf(a.x, c.x);
        float w0 = __expf(a.x - M), w1 = __expf(c.x - M);
        float denom = a.y * w0 + c.y * w1;
        float inv = 1.0f / fmaxf(denom, 1e-37f);
        long off = (long)(b * 2048 + sh_tok[q]) * P_DIM + (h0 + hs2) * HD + ds * 8;
        short hsv[8], lsv[8];
        #pragma unroll
        for (int j = 0; j < 8; j++) {
            int d = hs2 * 64 + ds * 8 + j;
            float o = (Opart[q * 128 + d] * w0 + Opart[2048 + q * 128 + d] * w1) * inv;
            hsv[j] = bf_hi(o);
            lsv[j] = bf_hi(o - bf_f(hsv[j]));
        }
        *(short4*)(attn_h + off)     = make_short4(hsv[0], hsv[1], hsv[2], hsv[3]);
        *(short4*)(attn_h + off + 4) = make_short4(hsv[4], hsv[5], hsv[6], hsv[7]);
        *(short4*)(attn_l + off)     = make_short4(lsv[0], lsv[1], lsv[2], lsv[3]);
        *(short4*)(attn_l + off + 4) = make_short4(lsv[4], lsv[5], lsv[6], lsv[7]);
    }
}

// ---------------- K9: pooled partial sums (atomic) --------------------------
__global__ __launch_bounds__(256) void k_pool(const float* __restrict__ zatt,
                                              float* __restrict__ pooled) {
    int b = blockIdx.y, chunk = blockIdx.x, t = threadIdx.x;
    float a0 = 0.f, a1 = 0.f;
    for (int s = 0; s < 16; s++) {
        long row = ((long)b * S_LEN + chunk * 16 + s) * P_DIM;
        a0 += zatt[row + t];
        a1 += zatt[row + t + 256];
    }
    atomicAdd(&pooled[b * P_DIM + t], a0);
    atomicAdd(&pooled[b * P_DIM + t + 256], a1);
}

// ---------------- Expert stage 1: h = pooled/S @ w1 + b1 (all 3 experts) ----
__global__ __launch_bounds__(256) void k_exp_fc1(const float* __restrict__ pooled,
                                                 const float* __restrict__ w1_0, const float* __restrict__ b1_0,
                                                 const float* __restrict__ w1_1, const float* __restrict__ b1_1,
                                                 const float* __restrict__ w1_2, const float* __restrict__ b1_2,
                                                 float* __restrict__ h) {
    int t = threadIdx.x, b = blockIdx.y;
    int c = blockIdx.x * 256 + t;  // [0, 1792)
    __shared__ float pl[P_DIM];
    pl[t]       = pooled[b * P_DIM + t]       * (1.0f / S_LEN);
    pl[t + 256] = pooled[b * P_DIM + t + 256] * (1.0f / S_LEN);
    __syncthreads();

    const float* wp; const float* bp; int s2, j;
    if (c < 256)      { wp = w1_0; bp = b1_0; s2 = 256;  j = c; }
    else if (c < 768) { wp = w1_1; bp = b1_1; s2 = 512;  j = c - 256; }
    else              { wp = w1_2; bp = b1_2; s2 = 1024; j = c - 768; }

    const float* p = wp + j;
    float acc = 0.f;
    #pragma unroll 16
    for (int k = 0; k < P_DIM; k++) {
        acc = fmaf(pl[k], *p, acc);
        p += s2;
    }
    h[(long)b * 1792 + c] = acc + bp[j];
}

// ---------------- Expert stage 2: LN + gelu per (expert, batch) -------------
__global__ __launch_bounds__(256) void k_exp_ln(float* __restrict__ h,
                                                const float* __restrict__ g0, const float* __restrict__ bb0,
                                                const float* __restrict__ g1, const float* __restrict__ bb1,
                                                const float* __restrict__ g2, const float* __restrict__ bb2) {
    int e = blockIdx.x, b = blockIdx.y, t = threadIdx.x;
    __shared__ float sm4[4];
    const int offs[3] = {0, 256, 768};
    const int ns[3]   = {256, 512, 1024};
    const float* gs[3]  = {g0, g1, g2};
    const float* bbs[3] = {bb0, bb1, bb2};
    int n = ns[e];
    float* hp = h + (long)b * 1792 + offs[e];
    const float* g = gs[e]; const float* bb = bbs[e];

    float x[4];
    float loc = 0.f;
    for (int u = 0; u < 4; u++) {
        int j = t + u * 256;
        x[u] = (j < n) ? hp[j] : 0.f;
        loc += x[u];
    }
    float mu = block_reduce_sum(loc, sm4) / (float)n;
    loc = 0.f;
    for (int u = 0; u < 4; u++) {
        int j = t + u * 256;
        if (j < n) { float d = x[u] - mu; loc += d * d; }
    }
    float var = block_reduce_sum(loc, sm4) / (float)n;
    float rs = 1.0f / sqrtf(var + 1e-5f);
    for (int u = 0; u < 4; u++) {
        int j = t + u * 256;
        if (j < n) hp[j] = gelu_exact((x[u] - mu) * rs * g[j] + bb[j]);
    }
}

// ---------------- Expert stage 3: out = h @ w2 + b2 (all 3 experts) ---------
__global__ __launch_bounds__(256) void k_exp_fc2(const float* __restrict__ h,
                                                 const float* __restrict__ w2_0, const float* __restrict__ b2_0,
                                                 const float* __restrict__ w2_1, const float* __restrict__ b2_1,
                                                 const float* __restrict__ w2_2, const float* __restrict__ b2_2,
                                                 float* __restrict__ out) {
    int t = threadIdx.x, b = blockIdx.y;
    int c = blockIdx.x * 256 + t;  // [0, 1024), valid < 896
    __shared__ float hs[1792];
    for (int u = 0; u < 7; u++) hs[t + u * 256] = h[(long)b * 1792 + t + u * 256];
    __syncthreads();
    if (c >= 896) return;

    const float* wp; const float* bp; int s2, sN, j, off_h;
    if (c < 128)      { wp = w2_0; bp = b2_0; s2 = 256;  sN = 128; j = c;       off_h = 0; }
    else if (c < 384) { wp = w2_1; bp = b2_1; s2 = 512;  sN = 256; j = c - 128; off_h = 256; }
    else              { wp = w2_2; bp = b2_2; s2 = 1024; sN = 512; j = c - 384; off_h = 768; }

    const float* p = wp + j;
    const float* hh = hs + off_h;
    float acc = 0.f;
    #pragma unroll 16
    for (int k = 0; k < s2; k++) {
        acc = fmaf(hh[k], *p, acc);
        p += sN;
    }
    out[b * 896 + c] = acc + bp[j];
}

// ---------------------------------------------------------------------------
extern "C" void kernel_launch(void* const* d_in, const int* in_sizes, int n_in,
                              void* d_out, int out_size, void* d_ws, size_t ws_size,
                              hipStream_t stream) {
    const float* seq   = (const float*)d_in[0];
    const float* penta = (const float*)d_in[1];
    const float* spos  = (const float*)d_in[2];
    const float* projW = (const float*)d_in[3];
    const float* projb = (const float*)d_in[4];
    const float* lng   = (const float*)d_in[5];
    const float* lnb   = (const float*)d_in[6];
    const float* qkvW  = (const float*)d_in[7];
    const float* qkvb  = (const float*)d_in[8];
    const float* outW  = (const float*)d_in[9];
    const float* outb  = (const float*)d_in[10];

    float* ws      = (float*)d_ws;
    float* z_pre   = ws;                      // 2097152 floats (zatt alias)
    short* z_h     = (short*)(z_pre + 2097152); // 2097152 shorts (attn_h alias)
    short* z_l     = z_h + 2097152;           // 2097152 shorts (attn_l alias)
    float* qkv     = (float*)(z_l + 2097152); // 6291456 floats
    float* pos     = qkv + 6291456;           // 4096 (unused, layout keep)
    float* pooled  = pos + 4096;              // 1024
    float* hbuf    = pooled + 1024;           // 4096
    unsigned long long* rowkey = (unsigned long long*)(hbuf + 4096);  // 4096 ull
    float* pos_srt = (float*)(rowkey + 4096); // 4096
    int*   order   = (int*)(pos_srt + 4096);  // 4096
    uint2* bounds  = (uint2*)(order + 4096);  // 4096 uint2
    unsigned long long* bmG = (unsigned long long*)(bounds + 4096); // 131072 ull
    short* cent_h  = (short*)(bmG + 131072);  // 524288 shorts
    short* cent_l  = cent_h + 524288;
    short* pjWT_h  = cent_l + 524288;         // 512x1024
    short* pjWT_l  = pjWT_h + 524288;
    short* qkWT_h  = pjWT_l + 524288;         // 1536x512
    short* qkWT_l  = qkWT_h + 786432;
    short* owWT_h  = qkWT_l + 786432;         // 512x512
    short* owWT_l  = owWT_h + 262144;
    short* attn_h  = z_h;     // z_h/z_l dead after anchor+qkv GEMMs
    short* attn_l  = z_l;
    float* zatt    = z_pre;   // z_pre dead after ln_gelu

    // weight prep
    k_cent<<<1024, 256, 0, stream>>>(penta, cent_h, cent_l);
    { dim3 g(16, 8);  k_wt<IN_DIM, P_DIM><<<g, 256, 0, stream>>>(projW, pjWT_h, pjWT_l); }
    { dim3 g(8, 24);  k_wt<P_DIM, 3 * P_DIM><<<g, 256, 0, stream>>>(qkvW, qkWT_h, qkWT_l); }
    { dim3 g(8, 8);   k_wt<P_DIM, P_DIM><<<g, 256, 0, stream>>>(outW, owWT_h, owWT_l); }

    // proj -> ln/gelu/norm (emits pre-split z)
    { dim3 g(64, 4);  k_mm<64, IN_DIM, P_DIM, 0, false><<<g, 256, 0, stream>>>(
          seq, nullptr, nullptr, pjWT_h, pjWT_l, projb, z_pre, nullptr); }
    k_ln_gelu_norm<<<4096, 256, 0, stream>>>(z_pre, lng, lnb, z_h, z_l);

    // anchor argmax -> sort (fused position gather)
    hipMemsetAsync(rowkey, 0, 4096 * sizeof(unsigned long long), stream);
    { dim3 g(64, 8);  k_mm<64, P_DIM, 1024, 1, true><<<g, 256, 0, stream>>>(
          nullptr, z_h, z_l, cent_h, cent_l, nullptr, nullptr, rowkey); }
    k_sort<<<2, 256, 0, stream>>>(rowkey, spos, order, pos_srt);

    // qkv -> routes(bitmap) -> attention (emits pre-split) -> out-proj
    { dim3 g(64, 12); k_mm<64, P_DIM, 3 * P_DIM, 0, true><<<g, 256, 0, stream>>>(
          nullptr, z_h, z_l, qkWT_h, qkWT_l, qkvb, qkv, nullptr); }
    k_routes<<<1024, 256, 0, stream>>>(pos_srt, order, bmG, bounds);
    k_attn<<<1024, 256, 0, stream>>>(qkv, order, bmG, bounds, attn_h, attn_l);
    { dim3 g(64, 4);  k_mm<64, P_DIM, P_DIM, 0, true><<<g, 256, 0, stream>>>(
          nullptr, attn_h, attn_l, owWT_h, owWT_l, outb, zatt, nullptr); }

    // pool + experts
    hipMemsetAsync(pooled, 0, 1024 * sizeof(float), stream);
    { dim3 pg(128, 2); k_pool<<<pg, 256, 0, stream>>>(zatt, pooled); }

    dim3 g1(7, 2);
    k_exp_fc1<<<g1, 256, 0, stream>>>(pooled,
        (const float*)d_in[11], (const float*)d_in[12],
        (const float*)d_in[17], (const float*)d_in[18],
        (const float*)d_in[23], (const float*)d_in[24], hbuf);
    dim3 g2(3, 2);
    k_exp_ln<<<g2, 256, 0, stream>>>(hbuf,
        (const float*)d_in[13], (const float*)d_in[14],
        (const float*)d_in[19], (const float*)d_in[20],
        (const float*)d_in[25], (const float*)d_in[26]);
    dim3 g3(4, 2);
    k_exp_fc2<<<g3, 256, 0, stream>>>(hbuf,
        (const float*)d_in[15], (const float*)d_in[16],
        (const float*)d_in[21], (const float*)d_in[22],
        (const float*)d_in[27], (const float*)d_in[28], (float*)d_out);
}